// Round 8
// baseline (757.373 us; speedup 1.0000x reference)
//
#include <hip/hip_runtime.h>

#define LRELU(v) ((v) >= 0.f ? (v) : 0.2f * (v))
#define DLRELU(v) ((v) >= 0.f ? (v) : 0.04f * (v))

constexpr int Nn = 50000;
constexpr int Ee = 800000;
constexpr int Hh = 256;
constexpr int Gg = 128;
constexpr int Oo = 10;

typedef __attribute__((ext_vector_type(8))) short short8;
typedef __attribute__((ext_vector_type(4))) float f32x4;
typedef __attribute__((ext_vector_type(4))) float fv4;
typedef __attribute__((ext_vector_type(4))) unsigned short us4;

__device__ inline float bf2f(unsigned short u) {
  union { unsigned int i; float f; } v; v.i = ((unsigned int)u) << 16; return v.f;
}
__device__ inline unsigned short f2bf(float f) {
  union { float f; unsigned int i; } v; v.f = f;
  unsigned int i = v.i;
  return (unsigned short)((i + 0x7FFFu + ((i >> 16) & 1u)) >> 16);
}

// ---------------------------------------------------------------------------
// CSR build
// ---------------------------------------------------------------------------
__global__ __launch_bounds__(256) void hist_kernel(
    const int* __restrict__ dst, int* __restrict__ deg)
{
  const int e = blockIdx.x * 256 + threadIdx.x;
  if (e < Ee) atomicAdd(&deg[dst[e]], 1);
}

__global__ __launch_bounds__(1024) void scan1_kernel(
    const int* __restrict__ deg, int* __restrict__ bsum)
{
  const int i = blockIdx.x * 1024 + threadIdx.x;
  int v = (i < Nn) ? deg[i] : 0;
  #pragma unroll
  for (int o = 32; o; o >>= 1) v += __shfl_xor(v, o, 64);
  __shared__ int ws[16];
  const int wid = threadIdx.x >> 6, lane = threadIdx.x & 63;
  if (lane == 0) ws[wid] = v;
  __syncthreads();
  if (threadIdx.x == 0) {
    int s = 0;
    #pragma unroll
    for (int k = 0; k < 16; k++) s += ws[k];
    bsum[blockIdx.x] = s;
  }
}

__global__ __launch_bounds__(64) void scan2_kernel(
    const int* __restrict__ bsum, int* __restrict__ boff, int* __restrict__ row_ptr, int nb)
{
  if (threadIdx.x == 0) {
    int s = 0;
    for (int b = 0; b < nb; b++) { boff[b] = s; s += bsum[b]; }
    row_ptr[Nn] = s;
  }
}

__global__ __launch_bounds__(1024) void scan3_kernel(
    const int* __restrict__ deg, const int* __restrict__ boff,
    int* __restrict__ row_ptr, int* __restrict__ cursor)
{
  const int i = blockIdx.x * 1024 + threadIdx.x;
  const int wid = threadIdx.x >> 6, lane = threadIdx.x & 63;
  const int v = (i < Nn) ? deg[i] : 0;
  int inc = v;
  #pragma unroll
  for (int o = 1; o < 64; o <<= 1) {
    const int u = __shfl_up(inc, o, 64);
    if (lane >= o) inc += u;
  }
  __shared__ int ws[16];
  if (lane == 63) ws[wid] = inc;
  __syncthreads();
  if (wid == 0 && lane < 16) {
    int s = ws[lane];
    #pragma unroll
    for (int o = 1; o < 16; o <<= 1) {
      const int u = __shfl_up(s, o, 64);
      if (lane >= o) s += u;
    }
    ws[lane] = s;
  }
  __syncthreads();
  const int woff = (wid == 0) ? 0 : ws[wid - 1];
  const int excl = boff[blockIdx.x] + woff + inc - v;
  if (i < Nn) { row_ptr[i] = excl; cursor[i] = excl; }
}

// fill: packed 16B edge record {src, a0, a1, a2} in CSR order
__global__ __launch_bounds__(256) void fill_kernel(
    const int* __restrict__ src, const int* __restrict__ dst,
    const float* __restrict__ ea, int* __restrict__ cursor,
    fv4* __restrict__ edges)
{
  const int e = blockIdx.x * 256 + threadIdx.x;
  if (e >= Ee) return;
  const int pos = atomicAdd(&cursor[dst[e]], 1);
  fv4 r;
  r.x = __int_as_float(src[e]);
  r.y = ea[3 * e + 0];
  r.z = ea[3 * e + 1];
  r.w = ea[3 * e + 2];
  edges[pos] = r;
}

// ---------------------------------------------------------------------------
// Converters
// ---------------------------------------------------------------------------
__global__ __launch_bounds__(256) void f2bf_kernel(
    const float* __restrict__ in, unsigned short* __restrict__ out, int n4)
{
  const int i = blockIdx.x * 256 + threadIdx.x;
  if (i >= n4) return;
  const float4 v = *reinterpret_cast<const float4*>(in + (size_t)i * 4);
  us4 o; o.x = f2bf(v.x); o.y = f2bf(v.y); o.z = f2bf(v.z); o.w = f2bf(v.w);
  *reinterpret_cast<us4*>(out + (size_t)i * 4) = o;
}

// W [K,256] fp32 -> Bt [256,K] bf16 (transpose+convert)
__global__ __launch_bounds__(256) void wt_kernel(
    const float* __restrict__ W, unsigned short* __restrict__ Bt, int K)
{
  const int g = blockIdx.x * 256 + threadIdx.x;
  if (g >= 256 * K) return;
  const int c = g & 255, k = g >> 8;
  Bt[(size_t)c * K + k] = f2bf(W[(size_t)k * 256 + c]);
}

// head weights: W[K,M] fp32 -> Bt[256,Kpad] bf16 transposed, zero-padded
__global__ __launch_bounds__(256) void headwt_kernel(
    const float* __restrict__ W, unsigned short* __restrict__ Bt,
    int K, int M, int Kpad)
{
  const int g = blockIdx.x * 256 + threadIdx.x;
  if (g >= 256 * Kpad) return;
  const int c = g / Kpad, k = g % Kpad;
  Bt[(size_t)c * Kpad + k] = (c < M && k < K) ? f2bf(W[(size_t)k * M + c]) : (unsigned short)0;
}

// ---------------------------------------------------------------------------
// Fused layer: agg(gather) -> LDS S -> GEMM1+BN+leaky -> LDS Y -> GEMM2+leaky -> XB
// 64 nodes per block, 512 threads (8 waves). Waves: A: 8 nodes each; B/C: 32 cols each.
// ---------------------------------------------------------------------------
template<int DIN>
__global__ __launch_bounds__(512) void fused_layer(
    const unsigned short* __restrict__ xin, const fv4* __restrict__ edges,
    const float* __restrict__ We, const float* __restrict__ be,
    const int* __restrict__ row_ptr,
    const unsigned short* __restrict__ W1t, const float* __restrict__ b1,
    const float* __restrict__ gamma, const float* __restrict__ beta,
    const float* __restrict__ mu, const float* __restrict__ var,
    const unsigned short* __restrict__ W2t, const float* __restrict__ b2,
    unsigned short* __restrict__ XB)
{
  constexpr int FPL  = DIN / 64;            // 2 or 4 floats per lane
  constexpr int SH   = (DIN == 256) ? 8 : 7;
  constexpr int ROWB = DIN * 2;             // S row bytes
  constexpr int KS1  = DIN / 32;            // k-steps for GEMM1
  __shared__ __align__(16) unsigned short lS[64 * DIN];   // 16/32 KB
  __shared__ __align__(16) unsigned short lY[64 * 256];   // 32 KB

  const int t = threadIdx.x, lane = t & 63, wv = t >> 6;
  const int l15 = lane & 15, hi = lane >> 4;
  const int n0 = blockIdx.x * 64;

  // ---------------- phase A: gather 8 nodes/wave into swizzled lS ----------
  const int fo = lane * FPL;
  float w0[FPL], w1[FPL], w2[FPL], bb[FPL];
  #pragma unroll
  for (int j = 0; j < FPL; j++) {
    w0[j] = We[0 * DIN + fo + j];
    w1[j] = We[1 * DIN + fo + j];
    w2[j] = We[2 * DIN + fo + j];
    bb[j] = be[fo + j];
  }

  for (int i = 0; i < 8; i++) {
    const int r = wv * 8 + i;
    const int n = n0 + r;
    float acc[FPL];
    #pragma unroll
    for (int j = 0; j < FPL; j++) acc[j] = 0.f;

    if (n < Nn) {
      const int beg = row_ptr[n], end = row_ptr[n + 1];
      int e = beg;
      for (; e + 2 <= end; e += 2) {
        const fv4 e0 = __builtin_nontemporal_load(edges + e);
        const fv4 e1 = __builtin_nontemporal_load(edges + e + 1);
        const unsigned o0 = ((unsigned)__float_as_int(e0.x) << SH) + fo;
        const unsigned o1 = ((unsigned)__float_as_int(e1.x) << SH) + fo;
        float xv0[FPL], xv1[FPL];
        if constexpr (FPL == 4) {
          const us4 v0 = *reinterpret_cast<const us4*>(xin + o0);
          const us4 v1 = *reinterpret_cast<const us4*>(xin + o1);
          xv0[0] = bf2f(v0.x); xv0[1] = bf2f(v0.y); xv0[2] = bf2f(v0.z); xv0[3] = bf2f(v0.w);
          xv1[0] = bf2f(v1.x); xv1[1] = bf2f(v1.y); xv1[2] = bf2f(v1.z); xv1[3] = bf2f(v1.w);
        } else {
          const unsigned int u0 = *reinterpret_cast<const unsigned int*>(xin + o0);
          const unsigned int u1 = *reinterpret_cast<const unsigned int*>(xin + o1);
          xv0[0] = bf2f((unsigned short)(u0 & 0xFFFF)); xv0[1] = bf2f((unsigned short)(u0 >> 16));
          xv1[0] = bf2f((unsigned short)(u1 & 0xFFFF)); xv1[1] = bf2f((unsigned short)(u1 >> 16));
        }
        #pragma unroll
        for (int j = 0; j < FPL; j++) {
          acc[j] += fmaxf(xv0[j] + e0.y * w0[j] + e0.z * w1[j] + e0.w * w2[j] + bb[j], 0.f);
          acc[j] += fmaxf(xv1[j] + e1.y * w0[j] + e1.z * w1[j] + e1.w * w2[j] + bb[j], 0.f);
        }
      }
      if (e < end) {
        const fv4 e0 = __builtin_nontemporal_load(edges + e);
        const unsigned o0 = ((unsigned)__float_as_int(e0.x) << SH) + fo;
        float xv0[FPL];
        if constexpr (FPL == 4) {
          const us4 v0 = *reinterpret_cast<const us4*>(xin + o0);
          xv0[0] = bf2f(v0.x); xv0[1] = bf2f(v0.y); xv0[2] = bf2f(v0.z); xv0[3] = bf2f(v0.w);
        } else {
          const unsigned int u0 = *reinterpret_cast<const unsigned int*>(xin + o0);
          xv0[0] = bf2f((unsigned short)(u0 & 0xFFFF)); xv0[1] = bf2f((unsigned short)(u0 >> 16));
        }
        #pragma unroll
        for (int j = 0; j < FPL; j++)
          acc[j] += fmaxf(xv0[j] + e0.y * w0[j] + e0.z * w1[j] + e0.w * w2[j] + bb[j], 0.f);
      }
      // self term
      const unsigned on = ((unsigned)n << SH) + fo;
      if constexpr (FPL == 4) {
        const us4 v = *reinterpret_cast<const us4*>(xin + on);
        acc[0] += bf2f(v.x); acc[1] += bf2f(v.y); acc[2] += bf2f(v.z); acc[3] += bf2f(v.w);
      } else {
        const unsigned int u = *reinterpret_cast<const unsigned int*>(xin + on);
        acc[0] += bf2f((unsigned short)(u & 0xFFFF));
        acc[1] += bf2f((unsigned short)(u >> 16));
      }
    }

    // write S row r, XOR-swizzled on 16B slots
    if constexpr (FPL == 4) {
      const int slot = lane >> 1;
      char* p = (char*)lS + r * ROWB + ((slot ^ (r & 7)) << 4) + (lane & 1) * 8;
      us4 ov; ov.x = f2bf(acc[0]); ov.y = f2bf(acc[1]); ov.z = f2bf(acc[2]); ov.w = f2bf(acc[3]);
      *reinterpret_cast<us4*>(p) = ov;
    } else {
      const int slot = lane >> 2;
      char* p = (char*)lS + r * ROWB + ((slot ^ (r & 7)) << 4) + (lane & 3) * 4;
      *reinterpret_cast<unsigned int*>(p) =
          (unsigned int)f2bf(acc[0]) | ((unsigned int)f2bf(acc[1]) << 16);
    }
  }
  __syncthreads();

  // ---------------- phase B: Y = BN(leaky(S @ W1 + b1)) -> lY --------------
  f32x4 a1[4][2] = {};
  for (int ks = 0; ks < KS1; ks++) {
    short8 av[4], bv[2];
    #pragma unroll
    for (int rf = 0; rf < 4; rf++) {
      const int ar = rf * 16 + l15;
      av[rf] = *reinterpret_cast<const short8*>(
          (const char*)lS + ar * ROWB + (((ks * 4 + hi) ^ (ar & 7)) << 4));
    }
    #pragma unroll
    for (int cf = 0; cf < 2; cf++) {
      const int c = wv * 32 + cf * 16 + l15;
      bv[cf] = *reinterpret_cast<const short8*>(W1t + (size_t)c * DIN + ks * 32 + hi * 8);
    }
    #pragma unroll
    for (int rf = 0; rf < 4; rf++)
      #pragma unroll
      for (int cf = 0; cf < 2; cf++)
        a1[rf][cf] = __builtin_amdgcn_mfma_f32_16x16x32_bf16(av[rf], bv[cf], a1[rf][cf], 0, 0, 0);
  }
  #pragma unroll
  for (int cf = 0; cf < 2; cf++) {
    const int c = wv * 32 + cf * 16 + l15;
    const float bs = b1[c];
    const float gm = gamma[c], bt2 = beta[c], mm = mu[c];
    const float iv = rsqrtf(var[c] + 1e-5f);
    #pragma unroll
    for (int rf = 0; rf < 4; rf++)
      #pragma unroll
      for (int rg = 0; rg < 4; rg++) {
        const int r = rf * 16 + hi * 4 + rg;
        float v = a1[rf][cf][rg] + bs;
        v = gm * (v - mm) * iv + bt2;
        v = LRELU(v);
        *reinterpret_cast<unsigned short*>(
            (char*)lY + r * 512 + (((c >> 3) ^ (r & 7)) << 4) + (c & 7) * 2) = f2bf(v);
      }
  }
  __syncthreads();

  // ---------------- phase C: XB = leaky(Y @ W2 + b2) -----------------------
  f32x4 a2[4][2] = {};
  for (int ks = 0; ks < 8; ks++) {
    short8 av[4], bv[2];
    #pragma unroll
    for (int rf = 0; rf < 4; rf++) {
      const int ar = rf * 16 + l15;
      av[rf] = *reinterpret_cast<const short8*>(
          (const char*)lY + ar * 512 + (((ks * 4 + hi) ^ (ar & 7)) << 4));
    }
    #pragma unroll
    for (int cf = 0; cf < 2; cf++) {
      const int c = wv * 32 + cf * 16 + l15;
      bv[cf] = *reinterpret_cast<const short8*>(W2t + (size_t)c * 256 + ks * 32 + hi * 8);
    }
    #pragma unroll
    for (int rf = 0; rf < 4; rf++)
      #pragma unroll
      for (int cf = 0; cf < 2; cf++)
        a2[rf][cf] = __builtin_amdgcn_mfma_f32_16x16x32_bf16(av[rf], bv[cf], a2[rf][cf], 0, 0, 0);
  }
  #pragma unroll
  for (int cf = 0; cf < 2; cf++) {
    const int c = wv * 32 + cf * 16 + l15;
    const float bs = b2[c];
    #pragma unroll
    for (int rf = 0; rf < 4; rf++)
      #pragma unroll
      for (int rg = 0; rg < 4; rg++) {
        const int n = n0 + rf * 16 + hi * 4 + rg;
        if (n >= Nn) continue;
        const float v = LRELU(a2[rf][cf][rg] + bs);
        XB[(size_t)n * 256 + c] = f2bf(v);
      }
  }
}

// ---------------------------------------------------------------------------
// Pool: segment_sum (sorted batch) of bf16 features into pooled[G,768] fp32
// ---------------------------------------------------------------------------
__global__ __launch_bounds__(256) void pool_kernel(
    const unsigned short* __restrict__ xl, const int* __restrict__ batch,
    float* __restrict__ pooled, int layer)
{
  constexpr int NPB = 16;
  const int n0 = blockIdx.x * NPB;
  const int c  = threadIdx.x;
  if (n0 >= Nn) return;
  float acc = 0.f;
  int curb = batch[n0];
  for (int i = 0; i < NPB; i++) {
    const int n = n0 + i;
    if (n >= Nn) break;
    const int b = batch[n];
    if (b != curb) {
      atomicAdd(pooled + (size_t)curb * 768 + layer * 256 + c, acc);
      acc = 0.f;
      curb = b;
    }
    acc += bf2f(xl[(size_t)n * 256 + c]);
  }
  atomicAdd(pooled + (size_t)curb * 768 + layer * 256 + c, acc);
}

// ---------------------------------------------------------------------------
// Fused MFMA head: 4 blocks x 32 graphs, all 4 layers, act in swizzled LDS
// ---------------------------------------------------------------------------
__global__ __launch_bounds__(256) void head_fused(
    const unsigned short* __restrict__ P,   // [128][768] bf16
    const unsigned short* __restrict__ B1t, // [256][768]
    const unsigned short* __restrict__ B2t, // [256][256]
    const unsigned short* __restrict__ B3t, // [256][256]
    const unsigned short* __restrict__ B4t, // [256][256]
    const float* __restrict__ b1, const float* __restrict__ b2,
    const float* __restrict__ b3, const float* __restrict__ b4,
    float* __restrict__ out)                // [128][10]
{
  __shared__ __align__(16) unsigned short act[32 * 256];
  const int t = threadIdx.x, lane = t & 63, wid = t >> 6;
  const int l15 = lane & 15, hi = lane >> 4;
  const int r0 = blockIdx.x * 32;

  f32x4 acc[2][4];

  #pragma unroll
  for (int rf = 0; rf < 2; rf++)
    #pragma unroll
    for (int cf = 0; cf < 4; cf++) acc[rf][cf] = (f32x4){0.f, 0.f, 0.f, 0.f};
  #pragma unroll 2
  for (int ks = 0; ks < 24; ks++) {
    short8 bv[4], av[2];
    #pragma unroll
    for (int cf = 0; cf < 4; cf++) {
      const int c = wid * 64 + cf * 16 + l15;
      bv[cf] = *reinterpret_cast<const short8*>(B1t + (size_t)c * 768 + ks * 32 + hi * 8);
    }
    #pragma unroll
    for (int rf = 0; rf < 2; rf++)
      av[rf] = *reinterpret_cast<const short8*>(
          P + (size_t)(r0 + rf * 16 + l15) * 768 + ks * 32 + hi * 8);
    #pragma unroll
    for (int rf = 0; rf < 2; rf++)
      #pragma unroll
      for (int cf = 0; cf < 4; cf++)
        acc[rf][cf] = __builtin_amdgcn_mfma_f32_16x16x32_bf16(av[rf], bv[cf], acc[rf][cf], 0, 0, 0);
  }
  #pragma unroll
  for (int cf = 0; cf < 4; cf++) {
    const int c = wid * 64 + cf * 16 + l15;
    const float bs = (c < 200) ? b1[c] : 0.f;
    const int slot0 = c >> 3;
    #pragma unroll
    for (int rf = 0; rf < 2; rf++)
      #pragma unroll
      for (int rg = 0; rg < 4; rg++) {
        const int row = rf * 16 + hi * 4 + rg;
        const float v = DLRELU(acc[rf][cf][rg] + bs);
        act[row * 256 + ((slot0 ^ (row & 7)) << 3) + (c & 7)] = f2bf(v);
      }
  }
  __syncthreads();

  #pragma unroll
  for (int L = 0; L < 2; L++) {
    const unsigned short* B = (L == 0) ? B2t : B3t;
    const float* bias = (L == 0) ? b2 : b3;
    #pragma unroll
    for (int rf = 0; rf < 2; rf++)
      #pragma unroll
      for (int cf = 0; cf < 4; cf++) acc[rf][cf] = (f32x4){0.f, 0.f, 0.f, 0.f};
    #pragma unroll
    for (int ks = 0; ks < 8; ks++) {
      short8 bv[4], av[2];
      #pragma unroll
      for (int cf = 0; cf < 4; cf++) {
        const int c = wid * 64 + cf * 16 + l15;
        bv[cf] = *reinterpret_cast<const short8*>(B + (size_t)c * 256 + ks * 32 + hi * 8);
      }
      #pragma unroll
      for (int rf = 0; rf < 2; rf++) {
        const int row = rf * 16 + l15;
        const int slot = ks * 4 + hi;
        av[rf] = *reinterpret_cast<const short8*>(
            act + row * 256 + ((slot ^ (row & 7)) << 3));
      }
      #pragma unroll
      for (int rf = 0; rf < 2; rf++)
        #pragma unroll
        for (int cf = 0; cf < 4; cf++)
          acc[rf][cf] = __builtin_amdgcn_mfma_f32_16x16x32_bf16(av[rf], bv[cf], acc[rf][cf], 0, 0, 0);
    }
    __syncthreads();
    #pragma unroll
    for (int cf = 0; cf < 4; cf++) {
      const int c = wid * 64 + cf * 16 + l15;
      const float bs = (c < 200) ? bias[c] : 0.f;
      const int slot0 = c >> 3;
      #pragma unroll
      for (int rf = 0; rf < 2; rf++)
        #pragma unroll
        for (int rg = 0; rg < 4; rg++) {
          const int row = rf * 16 + hi * 4 + rg;
          const float v = DLRELU(acc[rf][cf][rg] + bs);
          act[row * 256 + ((slot0 ^ (row & 7)) << 3) + (c & 7)] = f2bf(v);
        }
    }
    __syncthreads();
  }

  if (wid == 0) {
    f32x4 a4[2] = {};
    #pragma unroll
    for (int ks = 0; ks < 8; ks++) {
      short8 av[2];
      const short8 bv = *reinterpret_cast<const short8*>(
          B4t + (size_t)l15 * 256 + ks * 32 + hi * 8);
      #pragma unroll
      for (int rf = 0; rf < 2; rf++) {
        const int row = rf * 16 + l15;
        const int slot = ks * 4 + hi;
        av[rf] = *reinterpret_cast<const short8*>(
            act + row * 256 + ((slot ^ (row & 7)) << 3));
      }
      #pragma unroll
      for (int rf = 0; rf < 2; rf++)
        a4[rf] = __builtin_amdgcn_mfma_f32_16x16x32_bf16(av[rf], bv, a4[rf], 0, 0, 0);
    }
    if (l15 < Oo) {
      const float bs = b4[l15];
      #pragma unroll
      for (int rf = 0; rf < 2; rf++)
        #pragma unroll
        for (int rg = 0; rg < 4; rg++) {
          const int row = r0 + rf * 16 + hi * 4 + rg;
          out[(size_t)row * Oo + l15] = a4[rf][rg] + bs;
        }
    }
  }
}

// ---------------------------------------------------------------------------
extern "C" void kernel_launch(void* const* d_in, const int* in_sizes, int n_in,
                              void* d_out, int out_size, void* d_ws, size_t ws_size,
                              hipStream_t stream)
{
  const float* x     = (const float*)d_in[0];
  const int*   ei    = (const int*)d_in[1];
  const float* ea    = (const float*)d_in[2];
  const int*   batch = (const int*)d_in[3];
  const int* src = ei;
  const int* dst = ei + Ee;

  const float *We[3], *be_[3], *W1[3], *b1[3], *g_[3], *bt_[3], *mu_[3], *var_[3], *W2[3], *b2[3];
  for (int l = 0; l < 3; l++) {
    const int base = 4 + l * 10;
    We[l]  = (const float*)d_in[base + 0];
    be_[l] = (const float*)d_in[base + 1];
    W1[l]  = (const float*)d_in[base + 2];
    b1[l]  = (const float*)d_in[base + 3];
    g_[l]  = (const float*)d_in[base + 4];
    bt_[l] = (const float*)d_in[base + 5];
    mu_[l] = (const float*)d_in[base + 6];
    var_[l]= (const float*)d_in[base + 7];
    W2[l]  = (const float*)d_in[base + 8];
    b2[l]  = (const float*)d_in[base + 9];
  }
  const float *Wm[4], *bm[4];
  for (int i = 0; i < 4; i++) {
    Wm[i] = (const float*)d_in[34 + 2 * i];
    bm[i] = (const float*)d_in[35 + 2 * i];
  }

  // ---- workspace layout ----
  int* deg     = (int*)d_ws;                        // Nn
  int* cursor  = deg + Nn;                          // Nn
  int* row_ptr = cursor + Nn;                       // Nn+4
  int* bsum    = row_ptr + Nn + 4;                  // 64
  int* boff    = bsum + 64;                         // 64
  fv4* edges   = (fv4*)(boff + 64);                 // byte 600528 (16B aligned)
  unsigned short* x0bf = (unsigned short*)(edges + Ee);  // Nn*128
  unsigned short* Wt11 = x0bf + (size_t)Nn * 128;   // 256x128
  unsigned short* Wt12 = Wt11 + 32768;              // 256x256 each
  unsigned short* Wt21 = Wt12 + 65536;
  unsigned short* Wt22 = Wt21 + 65536;
  unsigned short* Wt31 = Wt22 + 65536;
  unsigned short* Wt32 = Wt31 + 65536;
  unsigned short* HW1t = Wt32 + 65536;              // 256x768
  unsigned short* HW2t = HW1t + 256 * 768;          // 256x256
  unsigned short* HW3t = HW2t + 65536;
  unsigned short* HW4t = HW3t + 65536;
  unsigned short* XB0  = HW4t + 65536;              // Nn*256 each
  unsigned short* XB1  = XB0 + (size_t)Nn * Hh;
  unsigned short* XB2  = XB1 + (size_t)Nn * Hh;
  unsigned short* Pbf  = XB2 + (size_t)Nn * Hh;     // Gg*768
  float* pooled = (float*)(Pbf + (size_t)Gg * 768); // Gg*768
  float* outf  = (float*)d_out;

  const int  fuseGrid = (Nn + 63) / 64;
  const int  poolGrid = (Nn + 15) / 16;
  const int  eGrid    = (Ee + 255) / 256;
  const int  sGrid    = (Nn + 1023) / 1024;

  hipMemsetAsync(deg, 0, Nn * sizeof(int), stream);
  hipMemsetAsync(pooled, 0, (size_t)Gg * 768 * sizeof(float), stream);

  // CSR build (once)
  hist_kernel<<<eGrid, 256, 0, stream>>>(dst, deg);
  scan1_kernel<<<sGrid, 1024, 0, stream>>>(deg, bsum);
  scan2_kernel<<<1, 64, 0, stream>>>(bsum, boff, row_ptr, sGrid);
  scan3_kernel<<<sGrid, 1024, 0, stream>>>(deg, boff, row_ptr, cursor);
  fill_kernel<<<eGrid, 256, 0, stream>>>(src, dst, ea, cursor, edges);

  // converts
  f2bf_kernel<<<(Nn * 128 / 4 + 255) / 256, 256, 0, stream>>>(x, x0bf, Nn * 128 / 4);
  wt_kernel<<<(256 * 128 + 255) / 256, 256, 0, stream>>>(W1[0], Wt11, 128);
  wt_kernel<<<(256 * 256 + 255) / 256, 256, 0, stream>>>(W2[0], Wt12, 256);
  wt_kernel<<<(256 * 256 + 255) / 256, 256, 0, stream>>>(W1[1], Wt21, 256);
  wt_kernel<<<(256 * 256 + 255) / 256, 256, 0, stream>>>(W2[1], Wt22, 256);
  wt_kernel<<<(256 * 256 + 255) / 256, 256, 0, stream>>>(W1[2], Wt31, 256);
  wt_kernel<<<(256 * 256 + 255) / 256, 256, 0, stream>>>(W2[2], Wt32, 256);
  headwt_kernel<<<(256 * 768 + 255) / 256, 256, 0, stream>>>(Wm[0], HW1t, 768, 200, 768);
  headwt_kernel<<<(256 * 256 + 255) / 256, 256, 0, stream>>>(Wm[1], HW2t, 200, 200, 256);
  headwt_kernel<<<(256 * 256 + 255) / 256, 256, 0, stream>>>(Wm[2], HW3t, 200, 200, 256);
  headwt_kernel<<<(256 * 256 + 255) / 256, 256, 0, stream>>>(Wm[3], HW4t, 200, 10, 256);

  // ---- fused layers ----
  fused_layer<128><<<fuseGrid, 512, 0, stream>>>(
      x0bf, edges, We[0], be_[0], row_ptr, Wt11, b1[0],
      g_[0], bt_[0], mu_[0], var_[0], Wt12, b2[0], XB0);
  pool_kernel<<<poolGrid, 256, 0, stream>>>(XB0, batch, pooled, 0);

  fused_layer<256><<<fuseGrid, 512, 0, stream>>>(
      XB0, edges, We[1], be_[1], row_ptr, Wt21, b1[1],
      g_[1], bt_[1], mu_[1], var_[1], Wt22, b2[1], XB1);
  pool_kernel<<<poolGrid, 256, 0, stream>>>(XB1, batch, pooled, 1);

  fused_layer<256><<<fuseGrid, 512, 0, stream>>>(
      XB1, edges, We[2], be_[2], row_ptr, Wt31, b1[2],
      g_[2], bt_[2], mu_[2], var_[2], Wt32, b2[2], XB2);
  pool_kernel<<<poolGrid, 256, 0, stream>>>(XB2, batch, pooled, 2);

  // ---- fused MFMA head ----
  f2bf_kernel<<<(Gg * 768 / 4 + 255) / 256, 256, 0, stream>>>(pooled, Pbf, Gg * 768 / 4);
  head_fused<<<4, 256, 0, stream>>>(Pbf, HW1t, HW2t, HW3t, HW4t,
                                    bm[0], bm[1], bm[2], bm[3], outf);
}

// Round 11
// 683.689 us; speedup vs baseline: 1.1078x; 1.1078x over previous
//
#include <hip/hip_runtime.h>
#include <hip/hip_fp16.h>

#define LRELU(v) ((v) >= 0.f ? (v) : 0.2f * (v))
#define DLRELU(v) ((v) >= 0.f ? (v) : 0.04f * (v))

constexpr int Nn = 50000;
constexpr int Ee = 800000;
constexpr int Hh = 256;
constexpr int Gg = 128;
constexpr int Oo = 10;

typedef __attribute__((ext_vector_type(8))) short short8;
typedef __attribute__((ext_vector_type(4))) float f32x4;
typedef __attribute__((ext_vector_type(4))) unsigned int uv4;
typedef __attribute__((ext_vector_type(2))) unsigned int uv2;
typedef __attribute__((ext_vector_type(4))) unsigned short us4;

__device__ inline unsigned short f2h(float f) {
  __half h = __float2half_rn(f);
  return *reinterpret_cast<unsigned short*>(&h);
}
__device__ inline float h2f(unsigned short u) {
  __half h = *reinterpret_cast<__half*>(&u);
  return __half2float(h);
}
__device__ inline __half2 u2h2(unsigned int u) {
  return *reinterpret_cast<__half2*>(&u);
}
__device__ inline unsigned int h22u(__half2 h) {
  return *reinterpret_cast<unsigned int*>(&h);
}
__device__ inline __half2 hmax2(__half2 a, __half2 b) {
  __half2 r;
  asm volatile("v_pk_max_f16 %0, %1, %2" : "=v"(r) : "v"(a), "v"(b));
  return r;
}
// bf16 helpers (head path)
__device__ inline unsigned short f2bf(float f) {
  union { float f; unsigned int i; } v; v.f = f;
  unsigned int i = v.i;
  return (unsigned short)((i + 0x7FFFu + ((i >> 16) & 1u)) >> 16);
}

typedef __attribute__((address_space(1))) const unsigned int gu32;
typedef __attribute__((address_space(3))) unsigned int lu32;
__device__ inline void gload_lds16(const void* g, void* l) {
  __builtin_amdgcn_global_load_lds((gu32*)g, (lu32*)l, 16, 0, 0);
}

// ---------------------------------------------------------------------------
// CSR build
// ---------------------------------------------------------------------------
__global__ __launch_bounds__(256) void hist_kernel(
    const int* __restrict__ dst, int* __restrict__ deg)
{
  const int e = blockIdx.x * 256 + threadIdx.x;
  if (e < Ee) atomicAdd(&deg[dst[e]], 1);
}

__global__ __launch_bounds__(1024) void scan1_kernel(
    const int* __restrict__ deg, int* __restrict__ bsum)
{
  const int i = blockIdx.x * 1024 + threadIdx.x;
  int v = (i < Nn) ? deg[i] : 0;
  #pragma unroll
  for (int o = 32; o; o >>= 1) v += __shfl_xor(v, o, 64);
  __shared__ int ws[16];
  const int wid = threadIdx.x >> 6, lane = threadIdx.x & 63;
  if (lane == 0) ws[wid] = v;
  __syncthreads();
  if (threadIdx.x == 0) {
    int s = 0;
    #pragma unroll
    for (int k = 0; k < 16; k++) s += ws[k];
    bsum[blockIdx.x] = s;
  }
}

__global__ __launch_bounds__(64) void scan2_kernel(
    const int* __restrict__ bsum, int* __restrict__ boff, int* __restrict__ row_ptr, int nb)
{
  if (threadIdx.x == 0) {
    int s = 0;
    for (int b = 0; b < nb; b++) { boff[b] = s; s += bsum[b]; }
    row_ptr[Nn] = s;
  }
}

__global__ __launch_bounds__(1024) void scan3_kernel(
    const int* __restrict__ deg, const int* __restrict__ boff,
    int* __restrict__ row_ptr, int* __restrict__ cursor)
{
  const int i = blockIdx.x * 1024 + threadIdx.x;
  const int wid = threadIdx.x >> 6, lane = threadIdx.x & 63;
  const int v = (i < Nn) ? deg[i] : 0;
  int inc = v;
  #pragma unroll
  for (int o = 1; o < 64; o <<= 1) {
    const int u = __shfl_up(inc, o, 64);
    if (lane >= o) inc += u;
  }
  __shared__ int ws[16];
  if (lane == 63) ws[wid] = inc;
  __syncthreads();
  if (wid == 0 && lane < 16) {
    int s = ws[lane];
    #pragma unroll
    for (int o = 1; o < 16; o <<= 1) {
      const int u = __shfl_up(s, o, 64);
      if (lane >= o) s += u;
    }
    ws[lane] = s;
  }
  __syncthreads();
  const int woff = (wid == 0) ? 0 : ws[wid - 1];
  const int excl = boff[blockIdx.x] + woff + inc - v;
  if (i < Nn) { row_ptr[i] = excl; cursor[i] = excl; }
}

// fill: packed 16B edge record {src, half2(a0,a0), half2(a1,a1), half2(a2,a2)}
__global__ __launch_bounds__(256) void fill_kernel(
    const int* __restrict__ src, const int* __restrict__ dst,
    const float* __restrict__ ea, int* __restrict__ cursor,
    uv4* __restrict__ edges)
{
  const int e = blockIdx.x * 256 + threadIdx.x;
  if (e >= Ee) return;
  const int pos = atomicAdd(&cursor[dst[e]], 1);
  uv4 r;
  r.x = (unsigned)src[e];
  r.y = h22u(__float2half2_rn(ea[3 * e + 0]));
  r.z = h22u(__float2half2_rn(ea[3 * e + 1]));
  r.w = h22u(__float2half2_rn(ea[3 * e + 2]));
  edges[pos] = r;
}

// ---------------------------------------------------------------------------
// Converters
// ---------------------------------------------------------------------------
__global__ __launch_bounds__(256) void f2h_kernel(
    const float* __restrict__ in, unsigned short* __restrict__ out, int n4)
{
  const int i = blockIdx.x * 256 + threadIdx.x;
  if (i >= n4) return;
  const float4 v = *reinterpret_cast<const float4*>(in + (size_t)i * 4);
  us4 o; o.x = f2h(v.x); o.y = f2h(v.y); o.z = f2h(v.z); o.w = f2h(v.w);
  *reinterpret_cast<us4*>(out + (size_t)i * 4) = o;
}

__global__ __launch_bounds__(256) void f2bf_kernel(
    const float* __restrict__ in, unsigned short* __restrict__ out, int n4)
{
  const int i = blockIdx.x * 256 + threadIdx.x;
  if (i >= n4) return;
  const float4 v = *reinterpret_cast<const float4*>(in + (size_t)i * 4);
  us4 o; o.x = f2bf(v.x); o.y = f2bf(v.y); o.z = f2bf(v.z); o.w = f2bf(v.w);
  *reinterpret_cast<us4*>(out + (size_t)i * 4) = o;
}

// W [K,256] fp32 -> Bt [256,K] fp16 (transpose+convert)
__global__ __launch_bounds__(256) void wt_kernel(
    const float* __restrict__ W, unsigned short* __restrict__ Bt, int K)
{
  const int g = blockIdx.x * 256 + threadIdx.x;
  if (g >= 256 * K) return;
  const int c = g & 255, k = g >> 8;
  Bt[(size_t)c * K + k] = f2h(W[(size_t)k * 256 + c]);
}

// head weights: W[K,M] fp32 -> Bt[256,Kpad] BF16 transposed, zero-padded
__global__ __launch_bounds__(256) void headwt_kernel(
    const float* __restrict__ W, unsigned short* __restrict__ Bt,
    int K, int M, int Kpad)
{
  const int g = blockIdx.x * 256 + threadIdx.x;
  if (g >= 256 * Kpad) return;
  const int c = g / Kpad, k = g % Kpad;
  Bt[(size_t)c * Kpad + k] = (c < M && k < K) ? f2bf(W[(size_t)k * M + c]) : (unsigned short)0;
}

// ---------------------------------------------------------------------------
// Gather aggregation v3: fp16 packed math, pre-broadcast edge coeffs
// ---------------------------------------------------------------------------
template<int DIN>
__global__ __launch_bounds__(256) void agg_gather(
    const unsigned short* __restrict__ x, const uv4* __restrict__ edges,
    const float* __restrict__ We, const float* __restrict__ be,
    const int* __restrict__ row_ptr, unsigned short* __restrict__ S)
{
  constexpr int FPL = DIN / 64;
  constexpr int H2  = FPL / 2;
  constexpr int SH  = (DIN == 256) ? 8 : 7;
  const int wv   = threadIdx.x >> 6;
  const int lane = threadIdx.x & 63;
  const int n = blockIdx.x * 4 + wv;
  if (n >= Nn) return;
  const int fo = lane * FPL;

  const __half2 zero2 = __float2half2_rn(0.f);
  __half2 w0h[H2], w1h[H2], w2h[H2], bbh[H2], acc[H2];
  #pragma unroll
  for (int j = 0; j < H2; j++) {
    w0h[j] = __halves2half2(__float2half_rn(We[0 * DIN + fo + 2 * j]),
                            __float2half_rn(We[0 * DIN + fo + 2 * j + 1]));
    w1h[j] = __halves2half2(__float2half_rn(We[1 * DIN + fo + 2 * j]),
                            __float2half_rn(We[1 * DIN + fo + 2 * j + 1]));
    w2h[j] = __halves2half2(__float2half_rn(We[2 * DIN + fo + 2 * j]),
                            __float2half_rn(We[2 * DIN + fo + 2 * j + 1]));
    bbh[j] = __halves2half2(__float2half_rn(be[fo + 2 * j]),
                            __float2half_rn(be[fo + 2 * j + 1]));
    acc[j] = zero2;
  }

  const int beg = row_ptr[n], end = row_ptr[n + 1];
  int i = beg;
  for (; i + 2 <= end; i += 2) {
    const uv4 e0 = __builtin_nontemporal_load(edges + i);
    const uv4 e1 = __builtin_nontemporal_load(edges + i + 1);
    const unsigned o0 = (e0.x << SH) + fo;
    const unsigned o1 = (e1.x << SH) + fo;
    __half2 xv0[H2], xv1[H2];
    if constexpr (H2 == 2) {
      const uv2 r0 = *reinterpret_cast<const uv2*>(x + o0);
      const uv2 r1 = *reinterpret_cast<const uv2*>(x + o1);
      xv0[0] = u2h2(r0.x); xv0[1] = u2h2(r0.y);
      xv1[0] = u2h2(r1.x); xv1[1] = u2h2(r1.y);
    } else {
      xv0[0] = u2h2(*reinterpret_cast<const unsigned int*>(x + o0));
      xv1[0] = u2h2(*reinterpret_cast<const unsigned int*>(x + o1));
    }
    const __half2 a00 = u2h2(e0.y), a01 = u2h2(e0.z), a02 = u2h2(e0.w);
    const __half2 a10 = u2h2(e1.y), a11 = u2h2(e1.z), a12 = u2h2(e1.w);
    #pragma unroll
    for (int j = 0; j < H2; j++) {
      __half2 m0 = __hadd2(xv0[j], bbh[j]);
      m0 = __hfma2(a02, w2h[j], m0);
      m0 = __hfma2(a01, w1h[j], m0);
      m0 = __hfma2(a00, w0h[j], m0);
      acc[j] = __hadd2(acc[j], hmax2(m0, zero2));
      __half2 m1 = __hadd2(xv1[j], bbh[j]);
      m1 = __hfma2(a12, w2h[j], m1);
      m1 = __hfma2(a11, w1h[j], m1);
      m1 = __hfma2(a10, w0h[j], m1);
      acc[j] = __hadd2(acc[j], hmax2(m1, zero2));
    }
  }
  if (i < end) {
    const uv4 e0 = __builtin_nontemporal_load(edges + i);
    const unsigned o0 = (e0.x << SH) + fo;
    __half2 xv0[H2];
    if constexpr (H2 == 2) {
      const uv2 r0 = *reinterpret_cast<const uv2*>(x + o0);
      xv0[0] = u2h2(r0.x); xv0[1] = u2h2(r0.y);
    } else {
      xv0[0] = u2h2(*reinterpret_cast<const unsigned int*>(x + o0));
    }
    const __half2 a00 = u2h2(e0.y), a01 = u2h2(e0.z), a02 = u2h2(e0.w);
    #pragma unroll
    for (int j = 0; j < H2; j++) {
      __half2 m0 = __hadd2(xv0[j], bbh[j]);
      m0 = __hfma2(a02, w2h[j], m0);
      m0 = __hfma2(a01, w1h[j], m0);
      m0 = __hfma2(a00, w0h[j], m0);
      acc[j] = __hadd2(acc[j], hmax2(m0, zero2));
    }
  }

  // self term in fp32, emit fp16
  const unsigned on = ((unsigned)n << SH) + fo;
  if constexpr (H2 == 2) {
    const uv2 rs = *reinterpret_cast<const uv2*>(x + on);
    const float2 s0 = __half22float2(u2h2(rs.x)), s1 = __half22float2(u2h2(rs.y));
    const float2 f0 = __half22float2(acc[0]), f1 = __half22float2(acc[1]);
    uv2 o;
    o.x = (unsigned)f2h(s0.x + f0.x) | ((unsigned)f2h(s0.y + f0.y) << 16);
    o.y = (unsigned)f2h(s1.x + f1.x) | ((unsigned)f2h(s1.y + f1.y) << 16);
    __builtin_nontemporal_store(o, reinterpret_cast<uv2*>(S + on));
  } else {
    const float2 s0 = __half22float2(u2h2(*reinterpret_cast<const unsigned int*>(x + on)));
    const float2 f0 = __half22float2(acc[0]);
    const unsigned o = (unsigned)f2h(s0.x + f0.x) | ((unsigned)f2h(s0.y + f0.y) << 16);
    __builtin_nontemporal_store(o, reinterpret_cast<unsigned int*>(S + on));
  }
}

// ---------------------------------------------------------------------------
// MFMA GEMM (fp16): C[N,256] = epi( A[N,K] @ W[K,256] ), Bt=W^T [256][K]
// ---------------------------------------------------------------------------
template<int K, bool DOBN>
__global__ __launch_bounds__(256) void gemm_mfma(
    const unsigned short* __restrict__ A, const unsigned short* __restrict__ Bt,
    const float* __restrict__ bias,
    const float* __restrict__ gamma, const float* __restrict__ beta,
    const float* __restrict__ mu, const float* __restrict__ var,
    unsigned short* __restrict__ C)
{
  __shared__ __align__(16) unsigned short lA[128 * 64];
  __shared__ __align__(16) unsigned short lB[128 * 64];
  const int t = threadIdx.x;
  const int lane = t & 63, wid = t >> 6;
  const int wrow = wid >> 1, wcol = wid & 1;
  const int l15 = lane & 15, hi = lane >> 4;
  const int n0 = blockIdx.y * 128;
  const int c0 = blockIdx.x * 128;
  const int srow = lane >> 3;
  const int sslot = lane & 7;

  f32x4 acc[4][4] = {};

  for (int k0 = 0; k0 < K; k0 += 64) {
    #pragma unroll
    for (int c = 0; c < 4; c++) {
      const int chunk = wid * 4 + c;
      const int row = chunk * 8 + srow;
      const int scol = (sslot ^ (row & 7)) * 8;
      const int gr = min(n0 + row, Nn - 1);
      gload_lds16(A + (size_t)gr * K + k0 + scol, (char*)lA + chunk * 1024);
      const int cb = c0 + row;
      gload_lds16(Bt + (size_t)cb * K + k0 + scol, (char*)lB + chunk * 1024);
    }
    __syncthreads();
    #pragma unroll
    for (int kk = 0; kk < 2; kk++) {
      short8 av[4], bv[4];
      #pragma unroll
      for (int rf = 0; rf < 4; rf++) {
        const int ar = wrow * 64 + rf * 16 + l15;
        av[rf] = *reinterpret_cast<const short8*>(
            (const char*)lA + ar * 128 + (((kk * 4 + hi) ^ (ar & 7)) << 4));
      }
      #pragma unroll
      for (int cf = 0; cf < 4; cf++) {
        const int br = wcol * 64 + cf * 16 + l15;
        bv[cf] = *reinterpret_cast<const short8*>(
            (const char*)lB + br * 128 + (((kk * 4 + hi) ^ (br & 7)) << 4));
      }
      #pragma unroll
      for (int rf = 0; rf < 4; rf++)
        #pragma unroll
        for (int cf = 0; cf < 4; cf++)
          acc[rf][cf] = __builtin_amdgcn_mfma_f32_16x16x32_f16(av[rf], bv[cf], acc[rf][cf], 0, 0, 0);
    }
    __syncthreads();
  }

  #pragma unroll
  for (int cf = 0; cf < 4; cf++) {
    const int col = c0 + wcol * 64 + cf * 16 + l15;
    const float bs = bias[col];
    float gm = 0.f, bt2 = 0.f, mm = 0.f, iv = 0.f;
    if constexpr (DOBN) {
      gm = gamma[col]; bt2 = beta[col]; mm = mu[col];
      iv = rsqrtf(var[col] + 1e-5f);
    }
    #pragma unroll
    for (int rf = 0; rf < 4; rf++) {
      #pragma unroll
      for (int rg = 0; rg < 4; rg++) {
        const int row = n0 + wrow * 64 + rf * 16 + hi * 4 + rg;
        if (row >= Nn) continue;
        float v = acc[rf][cf][rg] + bs;
        if constexpr (DOBN) v = gm * (v - mm) * iv + bt2;
        v = LRELU(v);
        C[(size_t)row * 256 + col] = f2h(v);
      }
    }
  }
}

// ---------------------------------------------------------------------------
// Pool: segment_sum (sorted batch) of fp16 features into pooled[G,768] fp32
// ---------------------------------------------------------------------------
__global__ __launch_bounds__(256) void pool_kernel(
    const unsigned short* __restrict__ xl, const int* __restrict__ batch,
    float* __restrict__ pooled, int layer)
{
  constexpr int NPB = 16;
  const int n0 = blockIdx.x * NPB;
  const int c  = threadIdx.x;
  if (n0 >= Nn) return;
  float acc = 0.f;
  int curb = batch[n0];
  for (int i = 0; i < NPB; i++) {
    const int n = n0 + i;
    if (n >= Nn) break;
    const int b = batch[n];
    if (b != curb) {
      atomicAdd(pooled + (size_t)curb * 768 + layer * 256 + c, acc);
      acc = 0.f;
      curb = b;
    }
    acc += h2f(xl[(size_t)n * 256 + c]);
  }
  atomicAdd(pooled + (size_t)curb * 768 + layer * 256 + c, acc);
}

// ---------------------------------------------------------------------------
// Fused MFMA head (BF16 — fp16 overflows on pooled sums): 4 blocks x 32 graphs
// ---------------------------------------------------------------------------
__global__ __launch_bounds__(256) void head_fused(
    const unsigned short* __restrict__ P,   // [128][768] bf16
    const unsigned short* __restrict__ B1t, // [256][768] bf16
    const unsigned short* __restrict__ B2t, // [256][256]
    const unsigned short* __restrict__ B3t, // [256][256]
    const unsigned short* __restrict__ B4t, // [256][256]
    const float* __restrict__ b1, const float* __restrict__ b2,
    const float* __restrict__ b3, const float* __restrict__ b4,
    float* __restrict__ out)                // [128][10]
{
  __shared__ __align__(16) unsigned short act[32 * 256];
  const int t = threadIdx.x, lane = t & 63, wid = t >> 6;
  const int l15 = lane & 15, hi = lane >> 4;
  const int r0 = blockIdx.x * 32;

  f32x4 acc[2][4];

  #pragma unroll
  for (int rf = 0; rf < 2; rf++)
    #pragma unroll
    for (int cf = 0; cf < 4; cf++) acc[rf][cf] = (f32x4){0.f, 0.f, 0.f, 0.f};
  #pragma unroll 2
  for (int ks = 0; ks < 24; ks++) {
    short8 bv[4], av[2];
    #pragma unroll
    for (int cf = 0; cf < 4; cf++) {
      const int c = wid * 64 + cf * 16 + l15;
      bv[cf] = *reinterpret_cast<const short8*>(B1t + (size_t)c * 768 + ks * 32 + hi * 8);
    }
    #pragma unroll
    for (int rf = 0; rf < 2; rf++)
      av[rf] = *reinterpret_cast<const short8*>(
          P + (size_t)(r0 + rf * 16 + l15) * 768 + ks * 32 + hi * 8);
    #pragma unroll
    for (int rf = 0; rf < 2; rf++)
      #pragma unroll
      for (int cf = 0; cf < 4; cf++)
        acc[rf][cf] = __builtin_amdgcn_mfma_f32_16x16x32_bf16(av[rf], bv[cf], acc[rf][cf], 0, 0, 0);
  }
  #pragma unroll
  for (int cf = 0; cf < 4; cf++) {
    const int c = wid * 64 + cf * 16 + l15;
    const float bs = (c < 200) ? b1[c] : 0.f;
    const int slot0 = c >> 3;
    #pragma unroll
    for (int rf = 0; rf < 2; rf++)
      #pragma unroll
      for (int rg = 0; rg < 4; rg++) {
        const int row = rf * 16 + hi * 4 + rg;
        const float v = DLRELU(acc[rf][cf][rg] + bs);
        act[row * 256 + ((slot0 ^ (row & 7)) << 3) + (c & 7)] = f2bf(v);
      }
  }
  __syncthreads();

  #pragma unroll
  for (int L = 0; L < 2; L++) {
    const unsigned short* B = (L == 0) ? B2t : B3t;
    const float* bias = (L == 0) ? b2 : b3;
    #pragma unroll
    for (int rf = 0; rf < 2; rf++)
      #pragma unroll
      for (int cf = 0; cf < 4; cf++) acc[rf][cf] = (f32x4){0.f, 0.f, 0.f, 0.f};
    #pragma unroll
    for (int ks = 0; ks < 8; ks++) {
      short8 bv[4], av[2];
      #pragma unroll
      for (int cf = 0; cf < 4; cf++) {
        const int c = wid * 64 + cf * 16 + l15;
        bv[cf] = *reinterpret_cast<const short8*>(B + (size_t)c * 256 + ks * 32 + hi * 8);
      }
      #pragma unroll
      for (int rf = 0; rf < 2; rf++) {
        const int row = rf * 16 + l15;
        const int slot = ks * 4 + hi;
        av[rf] = *reinterpret_cast<const short8*>(
            act + row * 256 + ((slot ^ (row & 7)) << 3));
      }
      #pragma unroll
      for (int rf = 0; rf < 2; rf++)
        #pragma unroll
        for (int cf = 0; cf < 4; cf++)
          acc[rf][cf] = __builtin_amdgcn_mfma_f32_16x16x32_bf16(av[rf], bv[cf], acc[rf][cf], 0, 0, 0);
    }
    __syncthreads();
    #pragma unroll
    for (int cf = 0; cf < 4; cf++) {
      const int c = wid * 64 + cf * 16 + l15;
      const float bs = (c < 200) ? bias[c] : 0.f;
      const int slot0 = c >> 3;
      #pragma unroll
      for (int rf = 0; rf < 2; rf++)
        #pragma unroll
        for (int rg = 0; rg < 4; rg++) {
          const int row = rf * 16 + hi * 4 + rg;
          const float v = DLRELU(acc[rf][cf][rg] + bs);
          act[row * 256 + ((slot0 ^ (row & 7)) << 3) + (c & 7)] = f2bf(v);
        }
    }
    __syncthreads();
  }

  if (wid == 0) {
    f32x4 a4[2] = {};
    #pragma unroll
    for (int ks = 0; ks < 8; ks++) {
      short8 av[2];
      const short8 bv = *reinterpret_cast<const short8*>(
          B4t + (size_t)l15 * 256 + ks * 32 + hi * 8);
      #pragma unroll
      for (int rf = 0; rf < 2; rf++) {
        const int row = rf * 16 + l15;
        const int slot = ks * 4 + hi;
        av[rf] = *reinterpret_cast<const short8*>(
            act + row * 256 + ((slot ^ (row & 7)) << 3));
      }
      #pragma unroll
      for (int rf = 0; rf < 2; rf++)
        a4[rf] = __builtin_amdgcn_mfma_f32_16x16x32_bf16(av[rf], bv, a4[rf], 0, 0, 0);
    }
    if (l15 < Oo) {
      const float bs = b4[l15];
      #pragma unroll
      for (int rf = 0; rf < 2; rf++)
        #pragma unroll
        for (int rg = 0; rg < 4; rg++) {
          const int row = r0 + rf * 16 + hi * 4 + rg;
          out[(size_t)row * Oo + l15] = a4[rf][rg] + bs;
        }
    }
  }
}

// ---------------------------------------------------------------------------
extern "C" void kernel_launch(void* const* d_in, const int* in_sizes, int n_in,
                              void* d_out, int out_size, void* d_ws, size_t ws_size,
                              hipStream_t stream)
{
  const float* x     = (const float*)d_in[0];
  const int*   ei    = (const int*)d_in[1];
  const float* ea    = (const float*)d_in[2];
  const int*   batch = (const int*)d_in[3];
  const int* src = ei;
  const int* dst = ei + Ee;

  const float *We[3], *be_[3], *W1[3], *b1[3], *g_[3], *bt_[3], *mu_[3], *var_[3], *W2[3], *b2[3];
  for (int l = 0; l < 3; l++) {
    const int base = 4 + l * 10;
    We[l]  = (const float*)d_in[base + 0];
    be_[l] = (const float*)d_in[base + 1];
    W1[l]  = (const float*)d_in[base + 2];
    b1[l]  = (const float*)d_in[base + 3];
    g_[l]  = (const float*)d_in[base + 4];
    bt_[l] = (const float*)d_in[base + 5];
    mu_[l] = (const float*)d_in[base + 6];
    var_[l]= (const float*)d_in[base + 7];
    W2[l]  = (const float*)d_in[base + 8];
    b2[l]  = (const float*)d_in[base + 9];
  }
  const float *Wm[4], *bm[4];
  for (int i = 0; i < 4; i++) {
    Wm[i] = (const float*)d_in[34 + 2 * i];
    bm[i] = (const float*)d_in[35 + 2 * i];
  }

  // ---- workspace layout ----
  int* deg     = (int*)d_ws;                        // Nn
  int* cursor  = deg + Nn;                          // Nn
  int* row_ptr = cursor + Nn;                       // Nn+4
  int* bsum    = row_ptr + Nn + 4;                  // 64
  int* boff    = bsum + 64;                         // 64
  uv4* edges   = (uv4*)(boff + 64);                 // byte 600528 (16B aligned)
  unsigned short* x0h  = (unsigned short*)(edges + Ee);  // Nn*128
  unsigned short* Wt11 = x0h + (size_t)Nn * 128;    // 256x128
  unsigned short* Wt12 = Wt11 + 32768;              // 256x256 each
  unsigned short* Wt21 = Wt12 + 65536;
  unsigned short* Wt22 = Wt21 + 65536;
  unsigned short* Wt31 = Wt22 + 65536;
  unsigned short* Wt32 = Wt31 + 65536;
  unsigned short* HW1t = Wt32 + 65536;              // 256x768 (bf16)
  unsigned short* HW2t = HW1t + 256 * 768;          // 256x256
  unsigned short* HW3t = HW2t + 65536;
  unsigned short* HW4t = HW3t + 65536;
  unsigned short* S    = HW4t + 65536;              // Nn*256
  unsigned short* Y    = S  + (size_t)Nn * Hh;      // Nn*256
  unsigned short* XB0  = Y  + (size_t)Nn * Hh;      // Nn*256
  unsigned short* XB1  = XB0 + (size_t)Nn * Hh;     // Nn*256
  unsigned short* Pbf  = XB1 + (size_t)Nn * Hh;     // Gg*768 (bf16)
  float* pooled = (float*)(Pbf + (size_t)Gg * 768); // Gg*768
  float* outf  = (float*)d_out;

  const dim3 gemmGrid(2, (Nn + 127) / 128);
  const int  poolGrid = (Nn + 15) / 16;
  const int  aggGrid  = (Nn + 3) / 4;
  const int  eGrid    = (Ee + 255) / 256;
  const int  sGrid    = (Nn + 1023) / 1024;

  hipMemsetAsync(deg, 0, Nn * sizeof(int), stream);
  hipMemsetAsync(pooled, 0, (size_t)Gg * 768 * sizeof(float), stream);

  // CSR build (once)
  hist_kernel<<<eGrid, 256, 0, stream>>>(dst, deg);
  scan1_kernel<<<sGrid, 1024, 0, stream>>>(deg, bsum);
  scan2_kernel<<<1, 64, 0, stream>>>(bsum, boff, row_ptr, sGrid);
  scan3_kernel<<<sGrid, 1024, 0, stream>>>(deg, boff, row_ptr, cursor);
  fill_kernel<<<eGrid, 256, 0, stream>>>(src, dst, ea, cursor, edges);

  // converts
  f2h_kernel<<<(Nn * 128 / 4 + 255) / 256, 256, 0, stream>>>(x, x0h, Nn * 128 / 4);
  wt_kernel<<<(256 * 128 + 255) / 256, 256, 0, stream>>>(W1[0], Wt11, 128);
  wt_kernel<<<(256 * 256 + 255) / 256, 256, 0, stream>>>(W2[0], Wt12, 256);
  wt_kernel<<<(256 * 256 + 255) / 256, 256, 0, stream>>>(W1[1], Wt21, 256);
  wt_kernel<<<(256 * 256 + 255) / 256, 256, 0, stream>>>(W2[1], Wt22, 256);
  wt_kernel<<<(256 * 256 + 255) / 256, 256, 0, stream>>>(W1[2], Wt31, 256);
  wt_kernel<<<(256 * 256 + 255) / 256, 256, 0, stream>>>(W2[2], Wt32, 256);
  headwt_kernel<<<(256 * 768 + 255) / 256, 256, 0, stream>>>(Wm[0], HW1t, 768, 200, 768);
  headwt_kernel<<<(256 * 256 + 255) / 256, 256, 0, stream>>>(Wm[1], HW2t, 200, 200, 256);
  headwt_kernel<<<(256 * 256 + 255) / 256, 256, 0, stream>>>(Wm[2], HW3t, 200, 200, 256);
  headwt_kernel<<<(256 * 256 + 255) / 256, 256, 0, stream>>>(Wm[3], HW4t, 200, 10, 256);

  // ---- layer 1 (din = 128) ----
  agg_gather<128><<<aggGrid, 256, 0, stream>>>(x0h, edges, We[0], be_[0], row_ptr, S);
  gemm_mfma<128, true><<<gemmGrid, 256, 0, stream>>>(
      S, Wt11, b1[0], g_[0], bt_[0], mu_[0], var_[0], Y);
  gemm_mfma<256, false><<<gemmGrid, 256, 0, stream>>>(
      Y, Wt12, b2[0], nullptr, nullptr, nullptr, nullptr, XB0);
  pool_kernel<<<poolGrid, 256, 0, stream>>>(XB0, batch, pooled, 0);

  // ---- layer 2 (din = 256) ----
  agg_gather<256><<<aggGrid, 256, 0, stream>>>(XB0, edges, We[1], be_[1], row_ptr, S);
  gemm_mfma<256, true><<<gemmGrid, 256, 0, stream>>>(
      S, Wt21, b1[1], g_[1], bt_[1], mu_[1], var_[1], Y);
  gemm_mfma<256, false><<<gemmGrid, 256, 0, stream>>>(
      Y, Wt22, b2[1], nullptr, nullptr, nullptr, nullptr, XB1);
  pool_kernel<<<poolGrid, 256, 0, stream>>>(XB1, batch, pooled, 1);

  // ---- layer 3 (din = 256) ----
  agg_gather<256><<<aggGrid, 256, 0, stream>>>(XB1, edges, We[2], be_[2], row_ptr, S);
  gemm_mfma<256, true><<<gemmGrid, 256, 0, stream>>>(
      S, Wt31, b1[2], g_[2], bt_[2], mu_[2], var_[2], Y);
  gemm_mfma<256, false><<<gemmGrid, 256, 0, stream>>>(
      Y, Wt32, b2[2], nullptr, nullptr, nullptr, nullptr, XB0);
  pool_kernel<<<poolGrid, 256, 0, stream>>>(XB0, batch, pooled, 2);

  // ---- fused MFMA head (bf16) ----
  f2bf_kernel<<<(Gg * 768 / 4 + 255) / 256, 256, 0, stream>>>(pooled, Pbf, Gg * 768 / 4);
  head_fused<<<4, 256, 0, stream>>>(Pbf, HW1t, HW2t, HW3t, HW4t,
                                    bm[0], bm[1], bm[2], bm[3], outf);
}

// Round 12
// 653.209 us; speedup vs baseline: 1.1595x; 1.0467x over previous
//
#include <hip/hip_runtime.h>
#include <hip/hip_fp16.h>

#define LRELU(v) ((v) >= 0.f ? (v) : 0.2f * (v))
#define DLRELU(v) ((v) >= 0.f ? (v) : 0.04f * (v))

constexpr int Nn = 50000;
constexpr int Ee = 800000;
constexpr int Hh = 256;
constexpr int Gg = 128;
constexpr int Oo = 10;

typedef __attribute__((ext_vector_type(8))) short short8;
typedef __attribute__((ext_vector_type(4))) float f32x4;
typedef __attribute__((ext_vector_type(4))) unsigned int uv4;
typedef __attribute__((ext_vector_type(2))) unsigned int uv2;
typedef __attribute__((ext_vector_type(4))) unsigned short us4;

__device__ inline unsigned short f2h(float f) {
  __half h = __float2half_rn(f);
  return *reinterpret_cast<unsigned short*>(&h);
}
__device__ inline float h2f(unsigned short u) {
  __half h = *reinterpret_cast<__half*>(&u);
  return __half2float(h);
}
__device__ inline __half2 u2h2(unsigned int u) {
  return *reinterpret_cast<__half2*>(&u);
}
__device__ inline unsigned int h22u(__half2 h) {
  return *reinterpret_cast<unsigned int*>(&h);
}
__device__ inline __half2 hmax2(__half2 a, __half2 b) {
  __half2 r;
  asm volatile("v_pk_max_f16 %0, %1, %2" : "=v"(r) : "v"(a), "v"(b));
  return r;
}
__device__ inline unsigned short f2bf(float f) {
  union { float f; unsigned int i; } v; v.f = f;
  unsigned int i = v.i;
  return (unsigned short)((i + 0x7FFFu + ((i >> 16) & 1u)) >> 16);
}

typedef __attribute__((address_space(1))) const unsigned int gu32;
typedef __attribute__((address_space(3))) unsigned int lu32;
__device__ inline void gload_lds16(const void* g, void* l) {
  __builtin_amdgcn_global_load_lds((gu32*)g, (lu32*)l, 16, 0, 0);
}

// ---------------------------------------------------------------------------
// CSR build
// ---------------------------------------------------------------------------
__global__ __launch_bounds__(256) void hist_kernel(
    const int* __restrict__ dst, int* __restrict__ deg)
{
  const int e = blockIdx.x * 256 + threadIdx.x;
  if (e < Ee) atomicAdd(&deg[dst[e]], 1);
}

__global__ __launch_bounds__(1024) void scan1_kernel(
    const int* __restrict__ deg, int* __restrict__ bsum)
{
  const int i = blockIdx.x * 1024 + threadIdx.x;
  int v = (i < Nn) ? deg[i] : 0;
  #pragma unroll
  for (int o = 32; o; o >>= 1) v += __shfl_xor(v, o, 64);
  __shared__ int ws[16];
  const int wid = threadIdx.x >> 6, lane = threadIdx.x & 63;
  if (lane == 0) ws[wid] = v;
  __syncthreads();
  if (threadIdx.x == 0) {
    int s = 0;
    #pragma unroll
    for (int k = 0; k < 16; k++) s += ws[k];
    bsum[blockIdx.x] = s;
  }
}

__global__ __launch_bounds__(64) void scan2_kernel(
    const int* __restrict__ bsum, int* __restrict__ boff, int* __restrict__ row_ptr, int nb)
{
  if (threadIdx.x == 0) {
    int s = 0;
    for (int b = 0; b < nb; b++) { boff[b] = s; s += bsum[b]; }
    row_ptr[Nn] = s;
  }
}

__global__ __launch_bounds__(1024) void scan3_kernel(
    const int* __restrict__ deg, const int* __restrict__ boff,
    int* __restrict__ row_ptr, int* __restrict__ cursor)
{
  const int i = blockIdx.x * 1024 + threadIdx.x;
  const int wid = threadIdx.x >> 6, lane = threadIdx.x & 63;
  const int v = (i < Nn) ? deg[i] : 0;
  int inc = v;
  #pragma unroll
  for (int o = 1; o < 64; o <<= 1) {
    const int u = __shfl_up(inc, o, 64);
    if (lane >= o) inc += u;
  }
  __shared__ int ws[16];
  if (lane == 63) ws[wid] = inc;
  __syncthreads();
  if (wid == 0 && lane < 16) {
    int s = ws[lane];
    #pragma unroll
    for (int o = 1; o < 16; o <<= 1) {
      const int u = __shfl_up(s, o, 64);
      if (lane >= o) s += u;
    }
    ws[lane] = s;
  }
  __syncthreads();
  const int woff = (wid == 0) ? 0 : ws[wid - 1];
  const int excl = boff[blockIdx.x] + woff + inc - v;
  if (i < Nn) { row_ptr[i] = excl; cursor[i] = excl; }
}

// fill: packed 16B edge record {src, half2(a0,a0), half2(a1,a1), half2(a2,a2)}
__global__ __launch_bounds__(256) void fill_kernel(
    const int* __restrict__ src, const int* __restrict__ dst,
    const float* __restrict__ ea, int* __restrict__ cursor,
    uv4* __restrict__ edges)
{
  const int e = blockIdx.x * 256 + threadIdx.x;
  if (e >= Ee) return;
  const int pos = atomicAdd(&cursor[dst[e]], 1);
  uv4 r;
  r.x = (unsigned)src[e];
  r.y = h22u(__float2half2_rn(ea[3 * e + 0]));
  r.z = h22u(__float2half2_rn(ea[3 * e + 1]));
  r.w = h22u(__float2half2_rn(ea[3 * e + 2]));
  edges[pos] = r;
}

// ---------------------------------------------------------------------------
// Converters
// ---------------------------------------------------------------------------
__global__ __launch_bounds__(256) void f2h_kernel(
    const float* __restrict__ in, unsigned short* __restrict__ out, int n4)
{
  const int i = blockIdx.x * 256 + threadIdx.x;
  if (i >= n4) return;
  const float4 v = *reinterpret_cast<const float4*>(in + (size_t)i * 4);
  us4 o; o.x = f2h(v.x); o.y = f2h(v.y); o.z = f2h(v.z); o.w = f2h(v.w);
  *reinterpret_cast<us4*>(out + (size_t)i * 4) = o;
}

__global__ __launch_bounds__(256) void f2bf_kernel(
    const float* __restrict__ in, unsigned short* __restrict__ out, int n4)
{
  const int i = blockIdx.x * 256 + threadIdx.x;
  if (i >= n4) return;
  const float4 v = *reinterpret_cast<const float4*>(in + (size_t)i * 4);
  us4 o; o.x = f2bf(v.x); o.y = f2bf(v.y); o.z = f2bf(v.z); o.w = f2bf(v.w);
  *reinterpret_cast<us4*>(out + (size_t)i * 4) = o;
}

// W [K,256] fp32 -> Bt [256,K] fp16 (transpose+convert)
__global__ __launch_bounds__(256) void wt_kernel(
    const float* __restrict__ W, unsigned short* __restrict__ Bt, int K)
{
  const int g = blockIdx.x * 256 + threadIdx.x;
  if (g >= 256 * K) return;
  const int c = g & 255, k = g >> 8;
  Bt[(size_t)c * K + k] = f2h(W[(size_t)k * 256 + c]);
}

// head weights: W[K,M] fp32 -> Bt[256,Kpad] BF16 transposed, zero-padded
__global__ __launch_bounds__(256) void headwt_kernel(
    const float* __restrict__ W, unsigned short* __restrict__ Bt,
    int K, int M, int Kpad)
{
  const int g = blockIdx.x * 256 + threadIdx.x;
  if (g >= 256 * Kpad) return;
  const int c = g / Kpad, k = g % Kpad;
  Bt[(size_t)c * Kpad + k] = (c < M && k < K) ? f2bf(W[(size_t)k * M + c]) : (unsigned short)0;
}

// ---------------------------------------------------------------------------
// Gather aggregation v4: fp16 packed math, 4 independent chains in flight
// S[n] = fp16( x[n] + sum_e ReLU(x[src_e] + ea_e@We + be) )
// ---------------------------------------------------------------------------
template<int DIN>
__global__ __launch_bounds__(256) void agg_gather(
    const unsigned short* __restrict__ x, const uv4* __restrict__ edges,
    const float* __restrict__ We, const float* __restrict__ be,
    const int* __restrict__ row_ptr, unsigned short* __restrict__ S)
{
  constexpr int FPL = DIN / 64;
  constexpr int H2  = FPL / 2;
  constexpr int SH  = (DIN == 256) ? 8 : 7;
  const int wv   = threadIdx.x >> 6;
  const int lane = threadIdx.x & 63;
  const int n = blockIdx.x * 4 + wv;
  if (n >= Nn) return;
  const int fo = lane * FPL;

  const __half2 zero2 = __float2half2_rn(0.f);
  __half2 w0h[H2], w1h[H2], w2h[H2], bbh[H2], acc[H2];
  #pragma unroll
  for (int j = 0; j < H2; j++) {
    w0h[j] = __halves2half2(__float2half_rn(We[0 * DIN + fo + 2 * j]),
                            __float2half_rn(We[0 * DIN + fo + 2 * j + 1]));
    w1h[j] = __halves2half2(__float2half_rn(We[1 * DIN + fo + 2 * j]),
                            __float2half_rn(We[1 * DIN + fo + 2 * j + 1]));
    w2h[j] = __halves2half2(__float2half_rn(We[2 * DIN + fo + 2 * j]),
                            __float2half_rn(We[2 * DIN + fo + 2 * j + 1]));
    bbh[j] = __halves2half2(__float2half_rn(be[fo + 2 * j]),
                            __float2half_rn(be[fo + 2 * j + 1]));
    acc[j] = zero2;
  }

  const int beg = row_ptr[n], end = row_ptr[n + 1];
  int i = beg;

  // 4 chains in flight: load 4 edge records, issue 4 row gathers, then FMA
  for (; i + 4 <= end; i += 4) {
    uv4 e[4];
    #pragma unroll
    for (int q = 0; q < 4; q++) e[q] = __builtin_nontemporal_load(edges + i + q);
    __half2 xv[4][H2];
    #pragma unroll
    for (int q = 0; q < 4; q++) {
      const unsigned o = (e[q].x << SH) + fo;
      if constexpr (H2 == 2) {
        const uv2 r = *reinterpret_cast<const uv2*>(x + o);
        xv[q][0] = u2h2(r.x); xv[q][1] = u2h2(r.y);
      } else {
        xv[q][0] = u2h2(*reinterpret_cast<const unsigned int*>(x + o));
      }
    }
    #pragma unroll
    for (int q = 0; q < 4; q++) {
      const __half2 a0 = u2h2(e[q].y), a1 = u2h2(e[q].z), a2 = u2h2(e[q].w);
      #pragma unroll
      for (int j = 0; j < H2; j++) {
        __half2 m = __hadd2(xv[q][j], bbh[j]);
        m = __hfma2(a2, w2h[j], m);
        m = __hfma2(a1, w1h[j], m);
        m = __hfma2(a0, w0h[j], m);
        acc[j] = __hadd2(acc[j], hmax2(m, zero2));
      }
    }
  }
  // remainder
  for (; i < end; i++) {
    const uv4 e0 = __builtin_nontemporal_load(edges + i);
    const unsigned o0 = (e0.x << SH) + fo;
    __half2 xv0[H2];
    if constexpr (H2 == 2) {
      const uv2 r0 = *reinterpret_cast<const uv2*>(x + o0);
      xv0[0] = u2h2(r0.x); xv0[1] = u2h2(r0.y);
    } else {
      xv0[0] = u2h2(*reinterpret_cast<const unsigned int*>(x + o0));
    }
    const __half2 a00 = u2h2(e0.y), a01 = u2h2(e0.z), a02 = u2h2(e0.w);
    #pragma unroll
    for (int j = 0; j < H2; j++) {
      __half2 m0 = __hadd2(xv0[j], bbh[j]);
      m0 = __hfma2(a02, w2h[j], m0);
      m0 = __hfma2(a01, w1h[j], m0);
      m0 = __hfma2(a00, w0h[j], m0);
      acc[j] = __hadd2(acc[j], hmax2(m0, zero2));
    }
  }

  // self term in fp32, emit fp16
  const unsigned on = ((unsigned)n << SH) + fo;
  if constexpr (H2 == 2) {
    const uv2 rs = *reinterpret_cast<const uv2*>(x + on);
    const float2 s0 = __half22float2(u2h2(rs.x)), s1 = __half22float2(u2h2(rs.y));
    const float2 f0 = __half22float2(acc[0]), f1 = __half22float2(acc[1]);
    uv2 o;
    o.x = (unsigned)f2h(s0.x + f0.x) | ((unsigned)f2h(s0.y + f0.y) << 16);
    o.y = (unsigned)f2h(s1.x + f1.x) | ((unsigned)f2h(s1.y + f1.y) << 16);
    __builtin_nontemporal_store(o, reinterpret_cast<uv2*>(S + on));
  } else {
    const float2 s0 = __half22float2(u2h2(*reinterpret_cast<const unsigned int*>(x + on)));
    const float2 f0 = __half22float2(acc[0]);
    const unsigned o = (unsigned)f2h(s0.x + f0.x) | ((unsigned)f2h(s0.y + f0.y) << 16);
    __builtin_nontemporal_store(o, reinterpret_cast<unsigned int*>(S + on));
  }
}

// ---------------------------------------------------------------------------
// MFMA GEMM (fp16): C[N,256] = epi( A[N,K] @ W[K,256] ), Bt=W^T [256][K]
// ---------------------------------------------------------------------------
template<int K, bool DOBN>
__global__ __launch_bounds__(256) void gemm_mfma(
    const unsigned short* __restrict__ A, const unsigned short* __restrict__ Bt,
    const float* __restrict__ bias,
    const float* __restrict__ gamma, const float* __restrict__ beta,
    const float* __restrict__ mu, const float* __restrict__ var,
    unsigned short* __restrict__ C)
{
  __shared__ __align__(16) unsigned short lA[128 * 64];
  __shared__ __align__(16) unsigned short lB[128 * 64];
  const int t = threadIdx.x;
  const int lane = t & 63, wid = t >> 6;
  const int wrow = wid >> 1, wcol = wid & 1;
  const int l15 = lane & 15, hi = lane >> 4;
  const int n0 = blockIdx.y * 128;
  const int c0 = blockIdx.x * 128;
  const int srow = lane >> 3;
  const int sslot = lane & 7;

  f32x4 acc[4][4] = {};

  for (int k0 = 0; k0 < K; k0 += 64) {
    #pragma unroll
    for (int c = 0; c < 4; c++) {
      const int chunk = wid * 4 + c;
      const int row = chunk * 8 + srow;
      const int scol = (sslot ^ (row & 7)) * 8;
      const int gr = min(n0 + row, Nn - 1);
      gload_lds16(A + (size_t)gr * K + k0 + scol, (char*)lA + chunk * 1024);
      const int cb = c0 + row;
      gload_lds16(Bt + (size_t)cb * K + k0 + scol, (char*)lB + chunk * 1024);
    }
    __syncthreads();
    #pragma unroll
    for (int kk = 0; kk < 2; kk++) {
      short8 av[4], bv[4];
      #pragma unroll
      for (int rf = 0; rf < 4; rf++) {
        const int ar = wrow * 64 + rf * 16 + l15;
        av[rf] = *reinterpret_cast<const short8*>(
            (const char*)lA + ar * 128 + (((kk * 4 + hi) ^ (ar & 7)) << 4));
      }
      #pragma unroll
      for (int cf = 0; cf < 4; cf++) {
        const int br = wcol * 64 + cf * 16 + l15;
        bv[cf] = *reinterpret_cast<const short8*>(
            (const char*)lB + br * 128 + (((kk * 4 + hi) ^ (br & 7)) << 4));
      }
      #pragma unroll
      for (int rf = 0; rf < 4; rf++)
        #pragma unroll
        for (int cf = 0; cf < 4; cf++)
          acc[rf][cf] = __builtin_amdgcn_mfma_f32_16x16x32_f16(av[rf], bv[cf], acc[rf][cf], 0, 0, 0);
    }
    __syncthreads();
  }

  #pragma unroll
  for (int cf = 0; cf < 4; cf++) {
    const int col = c0 + wcol * 64 + cf * 16 + l15;
    const float bs = bias[col];
    float gm = 0.f, bt2 = 0.f, mm = 0.f, iv = 0.f;
    if constexpr (DOBN) {
      gm = gamma[col]; bt2 = beta[col]; mm = mu[col];
      iv = rsqrtf(var[col] + 1e-5f);
    }
    #pragma unroll
    for (int rf = 0; rf < 4; rf++) {
      #pragma unroll
      for (int rg = 0; rg < 4; rg++) {
        const int row = n0 + wrow * 64 + rf * 16 + hi * 4 + rg;
        if (row >= Nn) continue;
        float v = acc[rf][cf][rg] + bs;
        if constexpr (DOBN) v = gm * (v - mm) * iv + bt2;
        v = LRELU(v);
        C[(size_t)row * 256 + col] = f2h(v);
      }
    }
  }
}

// ---------------------------------------------------------------------------
// Pool: segment_sum (sorted batch) of fp16 features into pooled[G,768] fp32
// ---------------------------------------------------------------------------
__global__ __launch_bounds__(256) void pool_kernel(
    const unsigned short* __restrict__ xl, const int* __restrict__ batch,
    float* __restrict__ pooled, int layer)
{
  constexpr int NPB = 16;
  const int n0 = blockIdx.x * NPB;
  const int c  = threadIdx.x;
  if (n0 >= Nn) return;
  float acc = 0.f;
  int curb = batch[n0];
  for (int i = 0; i < NPB; i++) {
    const int n = n0 + i;
    if (n >= Nn) break;
    const int b = batch[n];
    if (b != curb) {
      atomicAdd(pooled + (size_t)curb * 768 + layer * 256 + c, acc);
      acc = 0.f;
      curb = b;
    }
    acc += h2f(xl[(size_t)n * 256 + c]);
  }
  atomicAdd(pooled + (size_t)curb * 768 + layer * 256 + c, acc);
}

// ---------------------------------------------------------------------------
// Fused MFMA head (BF16): 4 blocks x 32 graphs, all 4 layers
// ---------------------------------------------------------------------------
__global__ __launch_bounds__(256) void head_fused(
    const unsigned short* __restrict__ P,   // [128][768] bf16
    const unsigned short* __restrict__ B1t, // [256][768] bf16
    const unsigned short* __restrict__ B2t, // [256][256]
    const unsigned short* __restrict__ B3t, // [256][256]
    const unsigned short* __restrict__ B4t, // [256][256]
    const float* __restrict__ b1, const float* __restrict__ b2,
    const float* __restrict__ b3, const float* __restrict__ b4,
    float* __restrict__ out)                // [128][10]
{
  __shared__ __align__(16) unsigned short act[32 * 256];
  const int t = threadIdx.x, lane = t & 63, wid = t >> 6;
  const int l15 = lane & 15, hi = lane >> 4;
  const int r0 = blockIdx.x * 32;

  f32x4 acc[2][4];

  #pragma unroll
  for (int rf = 0; rf < 2; rf++)
    #pragma unroll
    for (int cf = 0; cf < 4; cf++) acc[rf][cf] = (f32x4){0.f, 0.f, 0.f, 0.f};
  #pragma unroll 2
  for (int ks = 0; ks < 24; ks++) {
    short8 bv[4], av[2];
    #pragma unroll
    for (int cf = 0; cf < 4; cf++) {
      const int c = wid * 64 + cf * 16 + l15;
      bv[cf] = *reinterpret_cast<const short8*>(B1t + (size_t)c * 768 + ks * 32 + hi * 8);
    }
    #pragma unroll
    for (int rf = 0; rf < 2; rf++)
      av[rf] = *reinterpret_cast<const short8*>(
          P + (size_t)(r0 + rf * 16 + l15) * 768 + ks * 32 + hi * 8);
    #pragma unroll
    for (int rf = 0; rf < 2; rf++)
      #pragma unroll
      for (int cf = 0; cf < 4; cf++)
        acc[rf][cf] = __builtin_amdgcn_mfma_f32_16x16x32_bf16(av[rf], bv[cf], acc[rf][cf], 0, 0, 0);
  }
  #pragma unroll
  for (int cf = 0; cf < 4; cf++) {
    const int c = wid * 64 + cf * 16 + l15;
    const float bs = (c < 200) ? b1[c] : 0.f;
    const int slot0 = c >> 3;
    #pragma unroll
    for (int rf = 0; rf < 2; rf++)
      #pragma unroll
      for (int rg = 0; rg < 4; rg++) {
        const int row = rf * 16 + hi * 4 + rg;
        const float v = DLRELU(acc[rf][cf][rg] + bs);
        act[row * 256 + ((slot0 ^ (row & 7)) << 3) + (c & 7)] = f2bf(v);
      }
  }
  __syncthreads();

  #pragma unroll
  for (int L = 0; L < 2; L++) {
    const unsigned short* B = (L == 0) ? B2t : B3t;
    const float* bias = (L == 0) ? b2 : b3;
    #pragma unroll
    for (int rf = 0; rf < 2; rf++)
      #pragma unroll
      for (int cf = 0; cf < 4; cf++) acc[rf][cf] = (f32x4){0.f, 0.f, 0.f, 0.f};
    #pragma unroll
    for (int ks = 0; ks < 8; ks++) {
      short8 bv[4], av[2];
      #pragma unroll
      for (int cf = 0; cf < 4; cf++) {
        const int c = wid * 64 + cf * 16 + l15;
        bv[cf] = *reinterpret_cast<const short8*>(B + (size_t)c * 256 + ks * 32 + hi * 8);
      }
      #pragma unroll
      for (int rf = 0; rf < 2; rf++) {
        const int row = rf * 16 + l15;
        const int slot = ks * 4 + hi;
        av[rf] = *reinterpret_cast<const short8*>(
            act + row * 256 + ((slot ^ (row & 7)) << 3));
      }
      #pragma unroll
      for (int rf = 0; rf < 2; rf++)
        #pragma unroll
        for (int cf = 0; cf < 4; cf++)
          acc[rf][cf] = __builtin_amdgcn_mfma_f32_16x16x32_bf16(av[rf], bv[cf], acc[rf][cf], 0, 0, 0);
    }
    __syncthreads();
    #pragma unroll
    for (int cf = 0; cf < 4; cf++) {
      const int c = wid * 64 + cf * 16 + l15;
      const float bs = (c < 200) ? bias[c] : 0.f;
      const int slot0 = c >> 3;
      #pragma unroll
      for (int rf = 0; rf < 2; rf++)
        #pragma unroll
        for (int rg = 0; rg < 4; rg++) {
          const int row = rf * 16 + hi * 4 + rg;
          const float v = DLRELU(acc[rf][cf][rg] + bs);
          act[row * 256 + ((slot0 ^ (row & 7)) << 3) + (c & 7)] = f2bf(v);
        }
    }
    __syncthreads();
  }

  if (wid == 0) {
    f32x4 a4[2] = {};
    #pragma unroll
    for (int ks = 0; ks < 8; ks++) {
      short8 av[2];
      const short8 bv = *reinterpret_cast<const short8*>(
          B4t + (size_t)l15 * 256 + ks * 32 + hi * 8);
      #pragma unroll
      for (int rf = 0; rf < 2; rf++) {
        const int row = rf * 16 + l15;
        const int slot = ks * 4 + hi;
        av[rf] = *reinterpret_cast<const short8*>(
            act + row * 256 + ((slot ^ (row & 7)) << 3));
      }
      #pragma unroll
      for (int rf = 0; rf < 2; rf++)
        a4[rf] = __builtin_amdgcn_mfma_f32_16x16x32_bf16(av[rf], bv, a4[rf], 0, 0, 0);
    }
    if (l15 < Oo) {
      const float bs = b4[l15];
      #pragma unroll
      for (int rf = 0; rf < 2; rf++)
        #pragma unroll
        for (int rg = 0; rg < 4; rg++) {
          const int row = r0 + rf * 16 + hi * 4 + rg;
          out[(size_t)row * Oo + l15] = a4[rf][rg] + bs;
        }
    }
  }
}

// ---------------------------------------------------------------------------
extern "C" void kernel_launch(void* const* d_in, const int* in_sizes, int n_in,
                              void* d_out, int out_size, void* d_ws, size_t ws_size,
                              hipStream_t stream)
{
  const float* x     = (const float*)d_in[0];
  const int*   ei    = (const int*)d_in[1];
  const float* ea    = (const float*)d_in[2];
  const int*   batch = (const int*)d_in[3];
  const int* src = ei;
  const int* dst = ei + Ee;

  const float *We[3], *be_[3], *W1[3], *b1[3], *g_[3], *bt_[3], *mu_[3], *var_[3], *W2[3], *b2[3];
  for (int l = 0; l < 3; l++) {
    const int base = 4 + l * 10;
    We[l]  = (const float*)d_in[base + 0];
    be_[l] = (const float*)d_in[base + 1];
    W1[l]  = (const float*)d_in[base + 2];
    b1[l]  = (const float*)d_in[base + 3];
    g_[l]  = (const float*)d_in[base + 4];
    bt_[l] = (const float*)d_in[base + 5];
    mu_[l] = (const float*)d_in[base + 6];
    var_[l]= (const float*)d_in[base + 7];
    W2[l]  = (const float*)d_in[base + 8];
    b2[l]  = (const float*)d_in[base + 9];
  }
  const float *Wm[4], *bm[4];
  for (int i = 0; i < 4; i++) {
    Wm[i] = (const float*)d_in[34 + 2 * i];
    bm[i] = (const float*)d_in[35 + 2 * i];
  }

  // ---- workspace layout ----
  int* deg     = (int*)d_ws;                        // Nn
  int* cursor  = deg + Nn;                          // Nn
  int* row_ptr = cursor + Nn;                       // Nn+4
  int* bsum    = row_ptr + Nn + 4;                  // 64
  int* boff    = bsum + 64;                         // 64
  uv4* edges   = (uv4*)(boff + 64);                 // 16B aligned
  unsigned short* x0h  = (unsigned short*)(edges + Ee);  // Nn*128
  unsigned short* Wt11 = x0h + (size_t)Nn * 128;    // 256x128
  unsigned short* Wt12 = Wt11 + 32768;              // 256x256 each
  unsigned short* Wt21 = Wt12 + 65536;
  unsigned short* Wt22 = Wt21 + 65536;
  unsigned short* Wt31 = Wt22 + 65536;
  unsigned short* Wt32 = Wt31 + 65536;
  unsigned short* HW1t = Wt32 + 65536;              // 256x768 (bf16)
  unsigned short* HW2t = HW1t + 256 * 768;          // 256x256
  unsigned short* HW3t = HW2t + 65536;
  unsigned short* HW4t = HW3t + 65536;
  unsigned short* S    = HW4t + 65536;              // Nn*256
  unsigned short* Y    = S  + (size_t)Nn * Hh;      // Nn*256
  unsigned short* XB0  = Y  + (size_t)Nn * Hh;      // Nn*256
  unsigned short* XB1  = XB0 + (size_t)Nn * Hh;     // Nn*256
  unsigned short* Pbf  = XB1 + (size_t)Nn * Hh;     // Gg*768 (bf16)
  float* pooled = (float*)(Pbf + (size_t)Gg * 768); // Gg*768
  float* outf  = (float*)d_out;

  const dim3 gemmGrid(2, (Nn + 127) / 128);
  const int  poolGrid = (Nn + 15) / 16;
  const int  aggGrid  = (Nn + 3) / 4;
  const int  eGrid    = (Ee + 255) / 256;
  const int  sGrid    = (Nn + 1023) / 1024;

  hipMemsetAsync(deg, 0, Nn * sizeof(int), stream);
  hipMemsetAsync(pooled, 0, (size_t)Gg * 768 * sizeof(float), stream);

  // CSR build (once)
  hist_kernel<<<eGrid, 256, 0, stream>>>(dst, deg);
  scan1_kernel<<<sGrid, 1024, 0, stream>>>(deg, bsum);
  scan2_kernel<<<1, 64, 0, stream>>>(bsum, boff, row_ptr, sGrid);
  scan3_kernel<<<sGrid, 1024, 0, stream>>>(deg, boff, row_ptr, cursor);
  fill_kernel<<<eGrid, 256, 0, stream>>>(src, dst, ea, cursor, edges);

  // converts
  f2h_kernel<<<(Nn * 128 / 4 + 255) / 256, 256, 0, stream>>>(x, x0h, Nn * 128 / 4);
  wt_kernel<<<(256 * 128 + 255) / 256, 256, 0, stream>>>(W1[0], Wt11, 128);
  wt_kernel<<<(256 * 256 + 255) / 256, 256, 0, stream>>>(W2[0], Wt12, 256);
  wt_kernel<<<(256 * 256 + 255) / 256, 256, 0, stream>>>(W1[1], Wt21, 256);
  wt_kernel<<<(256 * 256 + 255) / 256, 256, 0, stream>>>(W2[1], Wt22, 256);
  wt_kernel<<<(256 * 256 + 255) / 256, 256, 0, stream>>>(W1[2], Wt31, 256);
  wt_kernel<<<(256 * 256 + 255) / 256, 256, 0, stream>>>(W2[2], Wt32, 256);
  headwt_kernel<<<(256 * 768 + 255) / 256, 256, 0, stream>>>(Wm[0], HW1t, 768, 200, 768);
  headwt_kernel<<<(256 * 256 + 255) / 256, 256, 0, stream>>>(Wm[1], HW2t, 200, 200, 256);
  headwt_kernel<<<(256 * 256 + 255) / 256, 256, 0, stream>>>(Wm[2], HW3t, 200, 200, 256);
  headwt_kernel<<<(256 * 256 + 255) / 256, 256, 0, stream>>>(Wm[3], HW4t, 200, 10, 256);

  // ---- layer 1 (din = 128) ----
  agg_gather<128><<<aggGrid, 256, 0, stream>>>(x0h, edges, We[0], be_[0], row_ptr, S);
  gemm_mfma<128, true><<<gemmGrid, 256, 0, stream>>>(
      S, Wt11, b1[0], g_[0], bt_[0], mu_[0], var_[0], Y);
  gemm_mfma<256, false><<<gemmGrid, 256, 0, stream>>>(
      Y, Wt12, b2[0], nullptr, nullptr, nullptr, nullptr, XB0);
  pool_kernel<<<poolGrid, 256, 0, stream>>>(XB0, batch, pooled, 0);

  // ---- layer 2 (din = 256) ----
  agg_gather<256><<<aggGrid, 256, 0, stream>>>(XB0, edges, We[1], be_[1], row_ptr, S);
  gemm_mfma<256, true><<<gemmGrid, 256, 0, stream>>>(
      S, Wt21, b1[1], g_[1], bt_[1], mu_[1], var_[1], Y);
  gemm_mfma<256, false><<<gemmGrid, 256, 0, stream>>>(
      Y, Wt22, b2[1], nullptr, nullptr, nullptr, nullptr, XB1);
  pool_kernel<<<poolGrid, 256, 0, stream>>>(XB1, batch, pooled, 1);

  // ---- layer 3 (din = 256) ----
  agg_gather<256><<<aggGrid, 256, 0, stream>>>(XB1, edges, We[2], be_[2], row_ptr, S);
  gemm_mfma<256, true><<<gemmGrid, 256, 0, stream>>>(
      S, Wt31, b1[2], g_[2], bt_[2], mu_[2], var_[2], Y);
  gemm_mfma<256, false><<<gemmGrid, 256, 0, stream>>>(
      Y, Wt32, b2[2], nullptr, nullptr, nullptr, nullptr, XB0);
  pool_kernel<<<poolGrid, 256, 0, stream>>>(XB0, batch, pooled, 2);

  // ---- fused MFMA head (bf16) ----
  f2bf_kernel<<<(Gg * 768 / 4 + 255) / 256, 256, 0, stream>>>(pooled, Pbf, Gg * 768 / 4);
  head_fused<<<4, 256, 0, stream>>>(Pbf, HW1t, HW2t, HW3t, HW4t,
                                    bm[0], bm[1], bm[2], bm[3], outf);
}

// Round 13
// 621.409 us; speedup vs baseline: 1.2188x; 1.0512x over previous
//
#include <hip/hip_runtime.h>
#include <hip/hip_fp16.h>

#define LRELU(v) ((v) >= 0.f ? (v) : 0.2f * (v))
#define DLRELU(v) ((v) >= 0.f ? (v) : 0.04f * (v))

constexpr int Nn = 50000;
constexpr int Ee = 800000;
constexpr int Hh = 256;
constexpr int Gg = 128;
constexpr int Oo = 10;

typedef __attribute__((ext_vector_type(8))) short short8;
typedef __attribute__((ext_vector_type(4))) float f32x4;
typedef __attribute__((ext_vector_type(4))) unsigned int uv4;
typedef __attribute__((ext_vector_type(2))) unsigned int uv2;
typedef __attribute__((ext_vector_type(4))) unsigned short us4;

__device__ inline unsigned short f2h(float f) {
  __half h = __float2half_rn(f);
  return *reinterpret_cast<unsigned short*>(&h);
}
__device__ inline float h2f(unsigned short u) {
  __half h = *reinterpret_cast<__half*>(&u);
  return __half2float(h);
}
__device__ inline __half2 u2h2(unsigned int u) {
  return *reinterpret_cast<__half2*>(&u);
}
__device__ inline unsigned int h22u(__half2 h) {
  return *reinterpret_cast<unsigned int*>(&h);
}
__device__ inline __half2 hmax2(__half2 a, __half2 b) {
  __half2 r;
  asm volatile("v_pk_max_f16 %0, %1, %2" : "=v"(r) : "v"(a), "v"(b));
  return r;
}
__device__ inline unsigned short f2bf(float f) {
  union { float f; unsigned int i; } v; v.f = f;
  unsigned int i = v.i;
  return (unsigned short)((i + 0x7FFFu + ((i >> 16) & 1u)) >> 16);
}

typedef __attribute__((address_space(1))) const unsigned int gu32;
typedef __attribute__((address_space(3))) unsigned int lu32;
__device__ inline void gload_lds16(const void* g, void* l) {
  __builtin_amdgcn_global_load_lds((gu32*)g, (lu32*)l, 16, 0, 0);
}

// ---------------------------------------------------------------------------
// CSR build
// ---------------------------------------------------------------------------
__global__ __launch_bounds__(256) void hist_kernel(
    const int* __restrict__ dst, int* __restrict__ deg)
{
  const int e = blockIdx.x * 256 + threadIdx.x;
  if (e < Ee) atomicAdd(&deg[dst[e]], 1);
}

__global__ __launch_bounds__(1024) void scan1_kernel(
    const int* __restrict__ deg, int* __restrict__ bsum)
{
  const int i = blockIdx.x * 1024 + threadIdx.x;
  int v = (i < Nn) ? deg[i] : 0;
  #pragma unroll
  for (int o = 32; o; o >>= 1) v += __shfl_xor(v, o, 64);
  __shared__ int ws[16];
  const int wid = threadIdx.x >> 6, lane = threadIdx.x & 63;
  if (lane == 0) ws[wid] = v;
  __syncthreads();
  if (threadIdx.x == 0) {
    int s = 0;
    #pragma unroll
    for (int k = 0; k < 16; k++) s += ws[k];
    bsum[blockIdx.x] = s;
  }
}

__global__ __launch_bounds__(64) void scan2_kernel(
    const int* __restrict__ bsum, int* __restrict__ boff, int* __restrict__ row_ptr, int nb)
{
  if (threadIdx.x == 0) {
    int s = 0;
    for (int b = 0; b < nb; b++) { boff[b] = s; s += bsum[b]; }
    row_ptr[Nn] = s;
  }
}

__global__ __launch_bounds__(1024) void scan3_kernel(
    const int* __restrict__ deg, const int* __restrict__ boff,
    int* __restrict__ row_ptr, int* __restrict__ cursor)
{
  const int i = blockIdx.x * 1024 + threadIdx.x;
  const int wid = threadIdx.x >> 6, lane = threadIdx.x & 63;
  const int v = (i < Nn) ? deg[i] : 0;
  int inc = v;
  #pragma unroll
  for (int o = 1; o < 64; o <<= 1) {
    const int u = __shfl_up(inc, o, 64);
    if (lane >= o) inc += u;
  }
  __shared__ int ws[16];
  if (lane == 63) ws[wid] = inc;
  __syncthreads();
  if (wid == 0 && lane < 16) {
    int s = ws[lane];
    #pragma unroll
    for (int o = 1; o < 16; o <<= 1) {
      const int u = __shfl_up(s, o, 64);
      if (lane >= o) s += u;
    }
    ws[lane] = s;
  }
  __syncthreads();
  const int woff = (wid == 0) ? 0 : ws[wid - 1];
  const int excl = boff[blockIdx.x] + woff + inc - v;
  if (i < Nn) { row_ptr[i] = excl; cursor[i] = excl; }
}

// fill: packed 16B edge record {src, half2(a0,a0), half2(a1,a1), half2(a2,a2)}
__global__ __launch_bounds__(256) void fill_kernel(
    const int* __restrict__ src, const int* __restrict__ dst,
    const float* __restrict__ ea, int* __restrict__ cursor,
    uv4* __restrict__ edges)
{
  const int e = blockIdx.x * 256 + threadIdx.x;
  if (e >= Ee) return;
  const int pos = atomicAdd(&cursor[dst[e]], 1);
  uv4 r;
  r.x = (unsigned)src[e];
  r.y = h22u(__float2half2_rn(ea[3 * e + 0]));
  r.z = h22u(__float2half2_rn(ea[3 * e + 1]));
  r.w = h22u(__float2half2_rn(ea[3 * e + 2]));
  edges[pos] = r;
}

// ---------------------------------------------------------------------------
// Converters
// ---------------------------------------------------------------------------
__global__ __launch_bounds__(256) void f2h_kernel(
    const float* __restrict__ in, unsigned short* __restrict__ out, int n4)
{
  const int i = blockIdx.x * 256 + threadIdx.x;
  if (i >= n4) return;
  const float4 v = *reinterpret_cast<const float4*>(in + (size_t)i * 4);
  us4 o; o.x = f2h(v.x); o.y = f2h(v.y); o.z = f2h(v.z); o.w = f2h(v.w);
  *reinterpret_cast<us4*>(out + (size_t)i * 4) = o;
}

__global__ __launch_bounds__(256) void f2bf_kernel(
    const float* __restrict__ in, unsigned short* __restrict__ out, int n4)
{
  const int i = blockIdx.x * 256 + threadIdx.x;
  if (i >= n4) return;
  const float4 v = *reinterpret_cast<const float4*>(in + (size_t)i * 4);
  us4 o; o.x = f2bf(v.x); o.y = f2bf(v.y); o.z = f2bf(v.z); o.w = f2bf(v.w);
  *reinterpret_cast<us4*>(out + (size_t)i * 4) = o;
}

// Consolidated weight prep: 10 transpose jobs in one launch.
// job: dst[c*Kpad+k] = (c<M && k<K) ? cvt(src[k*M + c]) : 0 ; cvt = fp16|bf16
struct WtJobs {
  const float* src[10];
  unsigned short* dst[10];
  int K[10], M[10], Kpad[10], isbf[10], blk0[11];
};

__global__ __launch_bounds__(256) void wtall_kernel(WtJobs J)
{
  int j = 0;
  #pragma unroll
  for (int q = 1; q < 10; q++) if ((int)blockIdx.x >= J.blk0[q]) j = q;
  const int g = ((int)blockIdx.x - J.blk0[j]) * 256 + threadIdx.x;
  const int Kpad = J.Kpad[j];
  if (g >= 256 * Kpad) return;
  const int c = g / Kpad, k = g % Kpad;
  const int K = J.K[j], M = J.M[j];
  unsigned short o = 0;
  if (c < M && k < K) {
    const float w = J.src[j][(size_t)k * M + c];
    o = J.isbf[j] ? f2bf(w) : f2h(w);
  }
  J.dst[j][(size_t)c * Kpad + k] = o;
}

// ---------------------------------------------------------------------------
// Gather aggregation v4: fp16 packed math, 4 independent chains in flight
// ---------------------------------------------------------------------------
template<int DIN>
__global__ __launch_bounds__(256) void agg_gather(
    const unsigned short* __restrict__ x, const uv4* __restrict__ edges,
    const float* __restrict__ We, const float* __restrict__ be,
    const int* __restrict__ row_ptr, unsigned short* __restrict__ S)
{
  constexpr int FPL = DIN / 64;
  constexpr int H2  = FPL / 2;
  constexpr int SH  = (DIN == 256) ? 8 : 7;
  const int wv   = threadIdx.x >> 6;
  const int lane = threadIdx.x & 63;
  const int n = blockIdx.x * 4 + wv;
  if (n >= Nn) return;
  const int fo = lane * FPL;

  const __half2 zero2 = __float2half2_rn(0.f);
  __half2 w0h[H2], w1h[H2], w2h[H2], bbh[H2], acc[H2];
  #pragma unroll
  for (int j = 0; j < H2; j++) {
    w0h[j] = __halves2half2(__float2half_rn(We[0 * DIN + fo + 2 * j]),
                            __float2half_rn(We[0 * DIN + fo + 2 * j + 1]));
    w1h[j] = __halves2half2(__float2half_rn(We[1 * DIN + fo + 2 * j]),
                            __float2half_rn(We[1 * DIN + fo + 2 * j + 1]));
    w2h[j] = __halves2half2(__float2half_rn(We[2 * DIN + fo + 2 * j]),
                            __float2half_rn(We[2 * DIN + fo + 2 * j + 1]));
    bbh[j] = __halves2half2(__float2half_rn(be[fo + 2 * j]),
                            __float2half_rn(be[fo + 2 * j + 1]));
    acc[j] = zero2;
  }

  const int beg = row_ptr[n], end = row_ptr[n + 1];
  int i = beg;

  for (; i + 4 <= end; i += 4) {
    uv4 e[4];
    #pragma unroll
    for (int q = 0; q < 4; q++) e[q] = __builtin_nontemporal_load(edges + i + q);
    __half2 xv[4][H2];
    #pragma unroll
    for (int q = 0; q < 4; q++) {
      const unsigned o = (e[q].x << SH) + fo;
      if constexpr (H2 == 2) {
        const uv2 r = *reinterpret_cast<const uv2*>(x + o);
        xv[q][0] = u2h2(r.x); xv[q][1] = u2h2(r.y);
      } else {
        xv[q][0] = u2h2(*reinterpret_cast<const unsigned int*>(x + o));
      }
    }
    #pragma unroll
    for (int q = 0; q < 4; q++) {
      const __half2 a0 = u2h2(e[q].y), a1 = u2h2(e[q].z), a2 = u2h2(e[q].w);
      #pragma unroll
      for (int j = 0; j < H2; j++) {
        __half2 m = __hadd2(xv[q][j], bbh[j]);
        m = __hfma2(a2, w2h[j], m);
        m = __hfma2(a1, w1h[j], m);
        m = __hfma2(a0, w0h[j], m);
        acc[j] = __hadd2(acc[j], hmax2(m, zero2));
      }
    }
  }
  for (; i < end; i++) {
    const uv4 e0 = __builtin_nontemporal_load(edges + i);
    const unsigned o0 = (e0.x << SH) + fo;
    __half2 xv0[H2];
    if constexpr (H2 == 2) {
      const uv2 r0 = *reinterpret_cast<const uv2*>(x + o0);
      xv0[0] = u2h2(r0.x); xv0[1] = u2h2(r0.y);
    } else {
      xv0[0] = u2h2(*reinterpret_cast<const unsigned int*>(x + o0));
    }
    const __half2 a00 = u2h2(e0.y), a01 = u2h2(e0.z), a02 = u2h2(e0.w);
    #pragma unroll
    for (int j = 0; j < H2; j++) {
      __half2 m0 = __hadd2(xv0[j], bbh[j]);
      m0 = __hfma2(a02, w2h[j], m0);
      m0 = __hfma2(a01, w1h[j], m0);
      m0 = __hfma2(a00, w0h[j], m0);
      acc[j] = __hadd2(acc[j], hmax2(m0, zero2));
    }
  }

  const unsigned on = ((unsigned)n << SH) + fo;
  if constexpr (H2 == 2) {
    const uv2 rs = *reinterpret_cast<const uv2*>(x + on);
    const float2 s0 = __half22float2(u2h2(rs.x)), s1 = __half22float2(u2h2(rs.y));
    const float2 f0 = __half22float2(acc[0]), f1 = __half22float2(acc[1]);
    uv2 o;
    o.x = (unsigned)f2h(s0.x + f0.x) | ((unsigned)f2h(s0.y + f0.y) << 16);
    o.y = (unsigned)f2h(s1.x + f1.x) | ((unsigned)f2h(s1.y + f1.y) << 16);
    __builtin_nontemporal_store(o, reinterpret_cast<uv2*>(S + on));
  } else {
    const float2 s0 = __half22float2(u2h2(*reinterpret_cast<const unsigned int*>(x + on)));
    const float2 f0 = __half22float2(acc[0]);
    const unsigned o = (unsigned)f2h(s0.x + f0.x) | ((unsigned)f2h(s0.y + f0.y) << 16);
    __builtin_nontemporal_store(o, reinterpret_cast<unsigned int*>(S + on));
  }
}

// ---------------------------------------------------------------------------
// MFMA GEMM v2 (fp16): C[N,256] = epi( A[N,K] @ W[K,256] ), Bt=W^T [256][K]
// block tile 128x256, 8 waves (2x4, 64x64 each), BK=64, one block covers all cols
// LDS 48 KB: A 128x64 (16KB) + B 256x64 (32KB); gload_lds + XOR swizzle
// ---------------------------------------------------------------------------
template<int K, bool DOBN>
__global__ __launch_bounds__(512) void gemm_mfma(
    const unsigned short* __restrict__ A, const unsigned short* __restrict__ Bt,
    const float* __restrict__ bias,
    const float* __restrict__ gamma, const float* __restrict__ beta,
    const float* __restrict__ mu, const float* __restrict__ var,
    unsigned short* __restrict__ C)
{
  __shared__ __align__(16) unsigned short lA[128 * 64];
  __shared__ __align__(16) unsigned short lB[256 * 64];
  const int t = threadIdx.x;
  const int lane = t & 63, wid = t >> 6;         // 8 waves
  const int wrow = wid >> 2, wcol = wid & 3;     // 2 x 4
  const int l15 = lane & 15, hi = lane >> 4;
  const int n0 = blockIdx.y * 128;
  const int srow = lane >> 3;
  const int sslot = lane & 7;

  f32x4 acc[4][4] = {};

  for (int k0 = 0; k0 < K; k0 += 64) {
    #pragma unroll
    for (int c = 0; c < 6; c++) {
      const int chunk = wid * 6 + c;             // 0..47
      if (chunk < 16) {                          // A rows 0..127
        const int row = chunk * 8 + srow;
        const int scol = (sslot ^ (row & 7)) * 8;
        const int gr = min(n0 + row, Nn - 1);
        gload_lds16(A + (size_t)gr * K + k0 + scol, (char*)lA + chunk * 1024);
      } else {                                   // B rows 0..255
        const int bchunk = chunk - 16;
        const int row = bchunk * 8 + srow;
        const int scol = (sslot ^ (row & 7)) * 8;
        gload_lds16(Bt + (size_t)row * K + k0 + scol, (char*)lB + bchunk * 1024);
      }
    }
    __syncthreads();
    #pragma unroll
    for (int kk = 0; kk < 2; kk++) {
      short8 av[4], bv[4];
      #pragma unroll
      for (int rf = 0; rf < 4; rf++) {
        const int ar = wrow * 64 + rf * 16 + l15;
        av[rf] = *reinterpret_cast<const short8*>(
            (const char*)lA + ar * 128 + (((kk * 4 + hi) ^ (ar & 7)) << 4));
      }
      #pragma unroll
      for (int cf = 0; cf < 4; cf++) {
        const int br = wcol * 64 + cf * 16 + l15;
        bv[cf] = *reinterpret_cast<const short8*>(
            (const char*)lB + br * 128 + (((kk * 4 + hi) ^ (br & 7)) << 4));
      }
      #pragma unroll
      for (int rf = 0; rf < 4; rf++)
        #pragma unroll
        for (int cf = 0; cf < 4; cf++)
          acc[rf][cf] = __builtin_amdgcn_mfma_f32_16x16x32_f16(av[rf], bv[cf], acc[rf][cf], 0, 0, 0);
    }
    __syncthreads();
  }

  #pragma unroll
  for (int cf = 0; cf < 4; cf++) {
    const int col = wcol * 64 + cf * 16 + l15;
    const float bs = bias[col];
    float gm = 0.f, bt2 = 0.f, mm = 0.f, iv = 0.f;
    if constexpr (DOBN) {
      gm = gamma[col]; bt2 = beta[col]; mm = mu[col];
      iv = rsqrtf(var[col] + 1e-5f);
    }
    #pragma unroll
    for (int rf = 0; rf < 4; rf++) {
      #pragma unroll
      for (int rg = 0; rg < 4; rg++) {
        const int row = n0 + wrow * 64 + rf * 16 + hi * 4 + rg;
        if (row >= Nn) continue;
        float v = acc[rf][cf][rg] + bs;
        if constexpr (DOBN) v = gm * (v - mm) * iv + bt2;
        v = LRELU(v);
        C[(size_t)row * 256 + col] = f2h(v);
      }
    }
  }
}

// ---------------------------------------------------------------------------
// Pool: segment_sum (sorted batch) of fp16 features into pooled[G,768] fp32
// ---------------------------------------------------------------------------
__global__ __launch_bounds__(256) void pool_kernel(
    const unsigned short* __restrict__ xl, const int* __restrict__ batch,
    float* __restrict__ pooled, int layer)
{
  constexpr int NPB = 16;
  const int n0 = blockIdx.x * NPB;
  const int c  = threadIdx.x;
  if (n0 >= Nn) return;
  float acc = 0.f;
  int curb = batch[n0];
  for (int i = 0; i < NPB; i++) {
    const int n = n0 + i;
    if (n >= Nn) break;
    const int b = batch[n];
    if (b != curb) {
      atomicAdd(pooled + (size_t)curb * 768 + layer * 256 + c, acc);
      acc = 0.f;
      curb = b;
    }
    acc += h2f(xl[(size_t)n * 256 + c]);
  }
  atomicAdd(pooled + (size_t)curb * 768 + layer * 256 + c, acc);
}

// ---------------------------------------------------------------------------
// Fused MFMA head (BF16): 4 blocks x 32 graphs, all 4 layers
// ---------------------------------------------------------------------------
__global__ __launch_bounds__(256) void head_fused(
    const unsigned short* __restrict__ P,
    const unsigned short* __restrict__ B1t,
    const unsigned short* __restrict__ B2t,
    const unsigned short* __restrict__ B3t,
    const unsigned short* __restrict__ B4t,
    const float* __restrict__ b1, const float* __restrict__ b2,
    const float* __restrict__ b3, const float* __restrict__ b4,
    float* __restrict__ out)
{
  __shared__ __align__(16) unsigned short act[32 * 256];
  const int t = threadIdx.x, lane = t & 63, wid = t >> 6;
  const int l15 = lane & 15, hi = lane >> 4;
  const int r0 = blockIdx.x * 32;

  f32x4 acc[2][4];

  #pragma unroll
  for (int rf = 0; rf < 2; rf++)
    #pragma unroll
    for (int cf = 0; cf < 4; cf++) acc[rf][cf] = (f32x4){0.f, 0.f, 0.f, 0.f};
  #pragma unroll 2
  for (int ks = 0; ks < 24; ks++) {
    short8 bv[4], av[2];
    #pragma unroll
    for (int cf = 0; cf < 4; cf++) {
      const int c = wid * 64 + cf * 16 + l15;
      bv[cf] = *reinterpret_cast<const short8*>(B1t + (size_t)c * 768 + ks * 32 + hi * 8);
    }
    #pragma unroll
    for (int rf = 0; rf < 2; rf++)
      av[rf] = *reinterpret_cast<const short8*>(
          P + (size_t)(r0 + rf * 16 + l15) * 768 + ks * 32 + hi * 8);
    #pragma unroll
    for (int rf = 0; rf < 2; rf++)
      #pragma unroll
      for (int cf = 0; cf < 4; cf++)
        acc[rf][cf] = __builtin_amdgcn_mfma_f32_16x16x32_bf16(av[rf], bv[cf], acc[rf][cf], 0, 0, 0);
  }
  #pragma unroll
  for (int cf = 0; cf < 4; cf++) {
    const int c = wid * 64 + cf * 16 + l15;
    const float bs = (c < 200) ? b1[c] : 0.f;
    const int slot0 = c >> 3;
    #pragma unroll
    for (int rf = 0; rf < 2; rf++)
      #pragma unroll
      for (int rg = 0; rg < 4; rg++) {
        const int row = rf * 16 + hi * 4 + rg;
        const float v = DLRELU(acc[rf][cf][rg] + bs);
        act[row * 256 + ((slot0 ^ (row & 7)) << 3) + (c & 7)] = f2bf(v);
      }
  }
  __syncthreads();

  #pragma unroll
  for (int L = 0; L < 2; L++) {
    const unsigned short* B = (L == 0) ? B2t : B3t;
    const float* bias = (L == 0) ? b2 : b3;
    #pragma unroll
    for (int rf = 0; rf < 2; rf++)
      #pragma unroll
      for (int cf = 0; cf < 4; cf++) acc[rf][cf] = (f32x4){0.f, 0.f, 0.f, 0.f};
    #pragma unroll
    for (int ks = 0; ks < 8; ks++) {
      short8 bv[4], av[2];
      #pragma unroll
      for (int cf = 0; cf < 4; cf++) {
        const int c = wid * 64 + cf * 16 + l15;
        bv[cf] = *reinterpret_cast<const short8*>(B + (size_t)c * 256 + ks * 32 + hi * 8);
      }
      #pragma unroll
      for (int rf = 0; rf < 2; rf++) {
        const int row = rf * 16 + l15;
        const int slot = ks * 4 + hi;
        av[rf] = *reinterpret_cast<const short8*>(
            act + row * 256 + ((slot ^ (row & 7)) << 3));
      }
      #pragma unroll
      for (int rf = 0; rf < 2; rf++)
        #pragma unroll
        for (int cf = 0; cf < 4; cf++)
          acc[rf][cf] = __builtin_amdgcn_mfma_f32_16x16x32_bf16(av[rf], bv[cf], acc[rf][cf], 0, 0, 0);
    }
    __syncthreads();
    #pragma unroll
    for (int cf = 0; cf < 4; cf++) {
      const int c = wid * 64 + cf * 16 + l15;
      const float bs = (c < 200) ? bias[c] : 0.f;
      const int slot0 = c >> 3;
      #pragma unroll
      for (int rf = 0; rf < 2; rf++)
        #pragma unroll
        for (int rg = 0; rg < 4; rg++) {
          const int row = rf * 16 + hi * 4 + rg;
          const float v = DLRELU(acc[rf][cf][rg] + bs);
          act[row * 256 + ((slot0 ^ (row & 7)) << 3) + (c & 7)] = f2bf(v);
        }
    }
    __syncthreads();
  }

  if (wid == 0) {
    f32x4 a4[2] = {};
    #pragma unroll
    for (int ks = 0; ks < 8; ks++) {
      short8 av[2];
      const short8 bv = *reinterpret_cast<const short8*>(
          B4t + (size_t)l15 * 256 + ks * 32 + hi * 8);
      #pragma unroll
      for (int rf = 0; rf < 2; rf++) {
        const int row = rf * 16 + l15;
        const int slot = ks * 4 + hi;
        av[rf] = *reinterpret_cast<const short8*>(
            act + row * 256 + ((slot ^ (row & 7)) << 3));
      }
      #pragma unroll
      for (int rf = 0; rf < 2; rf++)
        a4[rf] = __builtin_amdgcn_mfma_f32_16x16x32_bf16(av[rf], bv, a4[rf], 0, 0, 0);
    }
    if (l15 < Oo) {
      const float bs = b4[l15];
      #pragma unroll
      for (int rf = 0; rf < 2; rf++)
        #pragma unroll
        for (int rg = 0; rg < 4; rg++) {
          const int row = r0 + rf * 16 + hi * 4 + rg;
          out[(size_t)row * Oo + l15] = a4[rf][rg] + bs;
        }
    }
  }
}

// ---------------------------------------------------------------------------
extern "C" void kernel_launch(void* const* d_in, const int* in_sizes, int n_in,
                              void* d_out, int out_size, void* d_ws, size_t ws_size,
                              hipStream_t stream)
{
  const float* x     = (const float*)d_in[0];
  const int*   ei    = (const int*)d_in[1];
  const float* ea    = (const float*)d_in[2];
  const int*   batch = (const int*)d_in[3];
  const int* src = ei;
  const int* dst = ei + Ee;

  const float *We[3], *be_[3], *W1[3], *b1[3], *g_[3], *bt_[3], *mu_[3], *var_[3], *W2[3], *b2[3];
  for (int l = 0; l < 3; l++) {
    const int base = 4 + l * 10;
    We[l]  = (const float*)d_in[base + 0];
    be_[l] = (const float*)d_in[base + 1];
    W1[l]  = (const float*)d_in[base + 2];
    b1[l]  = (const float*)d_in[base + 3];
    g_[l]  = (const float*)d_in[base + 4];
    bt_[l] = (const float*)d_in[base + 5];
    mu_[l] = (const float*)d_in[base + 6];
    var_[l]= (const float*)d_in[base + 7];
    W2[l]  = (const float*)d_in[base + 8];
    b2[l]  = (const float*)d_in[base + 9];
  }
  const float *Wm[4], *bm[4];
  for (int i = 0; i < 4; i++) {
    Wm[i] = (const float*)d_in[34 + 2 * i];
    bm[i] = (const float*)d_in[35 + 2 * i];
  }

  // ---- workspace layout ----
  int* deg     = (int*)d_ws;                        // Nn
  int* cursor  = deg + Nn;                          // Nn
  int* row_ptr = cursor + Nn;                       // Nn+4
  int* bsum    = row_ptr + Nn + 4;                  // 64
  int* boff    = bsum + 64;                         // 64
  uv4* edges   = (uv4*)(boff + 64);                 // 16B aligned
  unsigned short* x0h  = (unsigned short*)(edges + Ee);  // Nn*128
  unsigned short* Wt11 = x0h + (size_t)Nn * 128;    // 256x128
  unsigned short* Wt12 = Wt11 + 32768;              // 256x256 each
  unsigned short* Wt21 = Wt12 + 65536;
  unsigned short* Wt22 = Wt21 + 65536;
  unsigned short* Wt31 = Wt22 + 65536;
  unsigned short* Wt32 = Wt31 + 65536;
  unsigned short* HW1t = Wt32 + 65536;              // 256x768 (bf16)
  unsigned short* HW2t = HW1t + 256 * 768;          // 256x256
  unsigned short* HW3t = HW2t + 65536;
  unsigned short* HW4t = HW3t + 65536;
  unsigned short* S    = HW4t + 65536;              // Nn*256
  unsigned short* Y    = S  + (size_t)Nn * Hh;      // Nn*256
  unsigned short* XB0  = Y  + (size_t)Nn * Hh;      // Nn*256
  unsigned short* XB1  = XB0 + (size_t)Nn * Hh;     // Nn*256
  unsigned short* Pbf  = XB1 + (size_t)Nn * Hh;     // Gg*768 (bf16)
  float* pooled = (float*)(Pbf + (size_t)Gg * 768); // Gg*768
  float* outf  = (float*)d_out;

  const dim3 gemmGrid(1, (Nn + 127) / 128);
  const int  poolGrid = (Nn + 15) / 16;
  const int  aggGrid  = (Nn + 3) / 4;
  const int  eGrid    = (Ee + 255) / 256;
  const int  sGrid    = (Nn + 1023) / 1024;

  hipMemsetAsync(deg, 0, Nn * sizeof(int), stream);
  hipMemsetAsync(pooled, 0, (size_t)Gg * 768 * sizeof(float), stream);

  // CSR build (once)
  hist_kernel<<<eGrid, 256, 0, stream>>>(dst, deg);
  scan1_kernel<<<sGrid, 1024, 0, stream>>>(deg, bsum);
  scan2_kernel<<<1, 64, 0, stream>>>(bsum, boff, row_ptr, sGrid);
  scan3_kernel<<<sGrid, 1024, 0, stream>>>(deg, boff, row_ptr, cursor);
  fill_kernel<<<eGrid, 256, 0, stream>>>(src, dst, ea, cursor, edges);

  // converts: x -> fp16, all 10 weight transposes in one launch
  f2h_kernel<<<(Nn * 128 / 4 + 255) / 256, 256, 0, stream>>>(x, x0h, Nn * 128 / 4);
  {
    WtJobs J;
    const float* s[10] = {W1[0], W2[0], W1[1], W2[1], W1[2], W2[2], Wm[0], Wm[1], Wm[2], Wm[3]};
    unsigned short* d[10] = {Wt11, Wt12, Wt21, Wt22, Wt31, Wt32, HW1t, HW2t, HW3t, HW4t};
    const int Ks[10]   = {128, 256, 256, 256, 256, 256, 768, 200, 200, 200};
    const int Ms[10]   = {256, 256, 256, 256, 256, 256, 200, 200, 200, 10};
    const int Kp[10]   = {128, 256, 256, 256, 256, 256, 768, 256, 256, 256};
    const int bf[10]   = {0, 0, 0, 0, 0, 0, 1, 1, 1, 1};
    int blk = 0;
    for (int q = 0; q < 10; q++) {
      J.src[q] = s[q]; J.dst[q] = d[q];
      J.K[q] = Ks[q]; J.M[q] = Ms[q]; J.Kpad[q] = Kp[q]; J.isbf[q] = bf[q];
      J.blk0[q] = blk;
      blk += (256 * Kp[q] + 255) / 256;
    }
    J.blk0[10] = blk;
    wtall_kernel<<<blk, 256, 0, stream>>>(J);
  }

  // ---- layer 1 (din = 128) ----
  agg_gather<128><<<aggGrid, 256, 0, stream>>>(x0h, edges, We[0], be_[0], row_ptr, S);
  gemm_mfma<128, true><<<gemmGrid, 512, 0, stream>>>(
      S, Wt11, b1[0], g_[0], bt_[0], mu_[0], var_[0], Y);
  gemm_mfma<256, false><<<gemmGrid, 512, 0, stream>>>(
      Y, Wt12, b2[0], nullptr, nullptr, nullptr, nullptr, XB0);
  pool_kernel<<<poolGrid, 256, 0, stream>>>(XB0, batch, pooled, 0);

  // ---- layer 2 (din = 256) ----
  agg_gather<256><<<aggGrid, 256, 0, stream>>>(XB0, edges, We[1], be_[1], row_ptr, S);
  gemm_mfma<256, true><<<gemmGrid, 512, 0, stream>>>(
      S, Wt21, b1[1], g_[1], bt_[1], mu_[1], var_[1], Y);
  gemm_mfma<256, false><<<gemmGrid, 512, 0, stream>>>(
      Y, Wt22, b2[1], nullptr, nullptr, nullptr, nullptr, XB1);
  pool_kernel<<<poolGrid, 256, 0, stream>>>(XB1, batch, pooled, 1);

  // ---- layer 3 (din = 256) ----
  agg_gather<256><<<aggGrid, 256, 0, stream>>>(XB1, edges, We[2], be_[2], row_ptr, S);
  gemm_mfma<256, true><<<gemmGrid, 512, 0, stream>>>(
      S, Wt31, b1[2], g_[2], bt_[2], mu_[2], var_[2], Y);
  gemm_mfma<256, false><<<gemmGrid, 512, 0, stream>>>(
      Y, Wt32, b2[2], nullptr, nullptr, nullptr, nullptr, XB0);
  pool_kernel<<<poolGrid, 256, 0, stream>>>(XB0, batch, pooled, 2);

  // ---- fused MFMA head (bf16) ----
  f2bf_kernel<<<(Gg * 768 / 4 + 255) / 256, 256, 0, stream>>>(pooled, Pbf, Gg * 768 / 4);
  head_fused<<<4, 256, 0, stream>>>(Pbf, HW1t, HW2t, HW3t, HW4t,
                                    bm[0], bm[1], bm[2], bm[3], outf);
}

// Round 14
// 583.194 us; speedup vs baseline: 1.2987x; 1.0655x over previous
//
#include <hip/hip_runtime.h>
#include <hip/hip_fp16.h>

#define LRELU(v) ((v) >= 0.f ? (v) : 0.2f * (v))
#define DLRELU(v) ((v) >= 0.f ? (v) : 0.04f * (v))

constexpr int Nn = 50000;
constexpr int Ee = 800000;
constexpr int Hh = 256;
constexpr int Gg = 128;
constexpr int Oo = 10;

typedef __attribute__((ext_vector_type(8))) short short8;
typedef __attribute__((ext_vector_type(4))) float f32x4;
typedef __attribute__((ext_vector_type(4))) unsigned int uv4;
typedef __attribute__((ext_vector_type(2))) unsigned int uv2;
typedef __attribute__((ext_vector_type(4))) unsigned short us4;

__device__ inline unsigned short f2h(float f) {
  __half h = __float2half_rn(f);
  return *reinterpret_cast<unsigned short*>(&h);
}
__device__ inline float h2f(unsigned short u) {
  __half h = *reinterpret_cast<__half*>(&u);
  return __half2float(h);
}
__device__ inline __half2 u2h2(unsigned int u) {
  return *reinterpret_cast<__half2*>(&u);
}
__device__ inline unsigned int h22u(__half2 h) {
  return *reinterpret_cast<unsigned int*>(&h);
}
__device__ inline __half2 hmax2(__half2 a, __half2 b) {
  __half2 r;
  asm volatile("v_pk_max_f16 %0, %1, %2" : "=v"(r) : "v"(a), "v"(b));
  return r;
}
__device__ inline unsigned short f2bf(float f) {
  union { float f; unsigned int i; } v; v.f = f;
  unsigned int i = v.i;
  return (unsigned short)((i + 0x7FFFu + ((i >> 16) & 1u)) >> 16);
}

typedef __attribute__((address_space(1))) const unsigned int gu32;
typedef __attribute__((address_space(3))) unsigned int lu32;
__device__ inline void gload_lds16(const void* g, void* l) {
  __builtin_amdgcn_global_load_lds((gu32*)g, (lu32*)l, 16, 0, 0);
}

// ---------------------------------------------------------------------------
// CSR build
// ---------------------------------------------------------------------------
__global__ __launch_bounds__(256) void hist_kernel(
    const int* __restrict__ dst, int* __restrict__ deg)
{
  const int e = blockIdx.x * 256 + threadIdx.x;
  if (e < Ee) atomicAdd(&deg[dst[e]], 1);
}

__global__ __launch_bounds__(1024) void scan1_kernel(
    const int* __restrict__ deg, int* __restrict__ bsum)
{
  const int i = blockIdx.x * 1024 + threadIdx.x;
  int v = (i < Nn) ? deg[i] : 0;
  #pragma unroll
  for (int o = 32; o; o >>= 1) v += __shfl_xor(v, o, 64);
  __shared__ int ws[16];
  const int wid = threadIdx.x >> 6, lane = threadIdx.x & 63;
  if (lane == 0) ws[wid] = v;
  __syncthreads();
  if (threadIdx.x == 0) {
    int s = 0;
    #pragma unroll
    for (int k = 0; k < 16; k++) s += ws[k];
    bsum[blockIdx.x] = s;
  }
}

__global__ __launch_bounds__(64) void scan2_kernel(
    const int* __restrict__ bsum, int* __restrict__ boff, int* __restrict__ row_ptr, int nb)
{
  if (threadIdx.x == 0) {
    int s = 0;
    for (int b = 0; b < nb; b++) { boff[b] = s; s += bsum[b]; }
    row_ptr[Nn] = s;
  }
}

__global__ __launch_bounds__(1024) void scan3_kernel(
    const int* __restrict__ deg, const int* __restrict__ boff,
    int* __restrict__ row_ptr, int* __restrict__ cursor)
{
  const int i = blockIdx.x * 1024 + threadIdx.x;
  const int wid = threadIdx.x >> 6, lane = threadIdx.x & 63;
  const int v = (i < Nn) ? deg[i] : 0;
  int inc = v;
  #pragma unroll
  for (int o = 1; o < 64; o <<= 1) {
    const int u = __shfl_up(inc, o, 64);
    if (lane >= o) inc += u;
  }
  __shared__ int ws[16];
  if (lane == 63) ws[wid] = inc;
  __syncthreads();
  if (wid == 0 && lane < 16) {
    int s = ws[lane];
    #pragma unroll
    for (int o = 1; o < 16; o <<= 1) {
      const int u = __shfl_up(s, o, 64);
      if (lane >= o) s += u;
    }
    ws[lane] = s;
  }
  __syncthreads();
  const int woff = (wid == 0) ? 0 : ws[wid - 1];
  const int excl = boff[blockIdx.x] + woff + inc - v;
  if (i < Nn) { row_ptr[i] = excl; cursor[i] = excl; }
}

// fill: packed 16B edge record {src, half2(a0,a0), half2(a1,a1), half2(a2,a2)}
__global__ __launch_bounds__(256) void fill_kernel(
    const int* __restrict__ src, const int* __restrict__ dst,
    const float* __restrict__ ea, int* __restrict__ cursor,
    uv4* __restrict__ edges)
{
  const int e = blockIdx.x * 256 + threadIdx.x;
  if (e >= Ee) return;
  const int pos = atomicAdd(&cursor[dst[e]], 1);
  uv4 r;
  r.x = (unsigned)src[e];
  r.y = h22u(__float2half2_rn(ea[3 * e + 0]));
  r.z = h22u(__float2half2_rn(ea[3 * e + 1]));
  r.w = h22u(__float2half2_rn(ea[3 * e + 2]));
  edges[pos] = r;
}

// ---------------------------------------------------------------------------
// Converters
// ---------------------------------------------------------------------------
__global__ __launch_bounds__(256) void f2h_kernel(
    const float* __restrict__ in, unsigned short* __restrict__ out, int n4)
{
  const int i = blockIdx.x * 256 + threadIdx.x;
  if (i >= n4) return;
  const float4 v = *reinterpret_cast<const float4*>(in + (size_t)i * 4);
  us4 o; o.x = f2h(v.x); o.y = f2h(v.y); o.z = f2h(v.z); o.w = f2h(v.w);
  *reinterpret_cast<us4*>(out + (size_t)i * 4) = o;
}

__global__ __launch_bounds__(256) void f2bf_kernel(
    const float* __restrict__ in, unsigned short* __restrict__ out, int n4)
{
  const int i = blockIdx.x * 256 + threadIdx.x;
  if (i >= n4) return;
  const float4 v = *reinterpret_cast<const float4*>(in + (size_t)i * 4);
  us4 o; o.x = f2bf(v.x); o.y = f2bf(v.y); o.z = f2bf(v.z); o.w = f2bf(v.w);
  *reinterpret_cast<us4*>(out + (size_t)i * 4) = o;
}

// Consolidated weight prep: 10 transpose jobs in one launch.
struct WtJobs {
  const float* src[10];
  unsigned short* dst[10];
  int K[10], M[10], Kpad[10], isbf[10], blk0[11];
};

__global__ __launch_bounds__(256) void wtall_kernel(WtJobs J)
{
  int j = 0;
  #pragma unroll
  for (int q = 1; q < 10; q++) if ((int)blockIdx.x >= J.blk0[q]) j = q;
  const int g = ((int)blockIdx.x - J.blk0[j]) * 256 + threadIdx.x;
  const int Kpad = J.Kpad[j];
  if (g >= 256 * Kpad) return;
  const int c = g / Kpad, k = g % Kpad;
  const int K = J.K[j], M = J.M[j];
  unsigned short o = 0;
  if (c < M && k < K) {
    const float w = J.src[j][(size_t)k * M + c];
    o = J.isbf[j] ? f2bf(w) : f2h(w);
  }
  J.dst[j][(size_t)c * Kpad + k] = o;
}

// ---------------------------------------------------------------------------
// Gather aggregation v4: fp16 packed math, 4 independent chains in flight
// ---------------------------------------------------------------------------
template<int DIN>
__global__ __launch_bounds__(256) void agg_gather(
    const unsigned short* __restrict__ x, const uv4* __restrict__ edges,
    const float* __restrict__ We, const float* __restrict__ be,
    const int* __restrict__ row_ptr, unsigned short* __restrict__ S)
{
  constexpr int FPL = DIN / 64;
  constexpr int H2  = FPL / 2;
  constexpr int SH  = (DIN == 256) ? 8 : 7;
  const int wv   = threadIdx.x >> 6;
  const int lane = threadIdx.x & 63;
  const int n = blockIdx.x * 4 + wv;
  if (n >= Nn) return;
  const int fo = lane * FPL;

  const __half2 zero2 = __float2half2_rn(0.f);
  __half2 w0h[H2], w1h[H2], w2h[H2], bbh[H2], acc[H2];
  #pragma unroll
  for (int j = 0; j < H2; j++) {
    w0h[j] = __halves2half2(__float2half_rn(We[0 * DIN + fo + 2 * j]),
                            __float2half_rn(We[0 * DIN + fo + 2 * j + 1]));
    w1h[j] = __halves2half2(__float2half_rn(We[1 * DIN + fo + 2 * j]),
                            __float2half_rn(We[1 * DIN + fo + 2 * j + 1]));
    w2h[j] = __halves2half2(__float2half_rn(We[2 * DIN + fo + 2 * j]),
                            __float2half_rn(We[2 * DIN + fo + 2 * j + 1]));
    bbh[j] = __halves2half2(__float2half_rn(be[fo + 2 * j]),
                            __float2half_rn(be[fo + 2 * j + 1]));
    acc[j] = zero2;
  }

  const int beg = row_ptr[n], end = row_ptr[n + 1];
  int i = beg;

  for (; i + 4 <= end; i += 4) {
    uv4 e[4];
    #pragma unroll
    for (int q = 0; q < 4; q++) e[q] = __builtin_nontemporal_load(edges + i + q);
    __half2 xv[4][H2];
    #pragma unroll
    for (int q = 0; q < 4; q++) {
      const unsigned o = (e[q].x << SH) + fo;
      if constexpr (H2 == 2) {
        const uv2 r = *reinterpret_cast<const uv2*>(x + o);
        xv[q][0] = u2h2(r.x); xv[q][1] = u2h2(r.y);
      } else {
        xv[q][0] = u2h2(*reinterpret_cast<const unsigned int*>(x + o));
      }
    }
    #pragma unroll
    for (int q = 0; q < 4; q++) {
      const __half2 a0 = u2h2(e[q].y), a1 = u2h2(e[q].z), a2 = u2h2(e[q].w);
      #pragma unroll
      for (int j = 0; j < H2; j++) {
        __half2 m = __hadd2(xv[q][j], bbh[j]);
        m = __hfma2(a2, w2h[j], m);
        m = __hfma2(a1, w1h[j], m);
        m = __hfma2(a0, w0h[j], m);
        acc[j] = __hadd2(acc[j], hmax2(m, zero2));
      }
    }
  }
  for (; i < end; i++) {
    const uv4 e0 = __builtin_nontemporal_load(edges + i);
    const unsigned o0 = (e0.x << SH) + fo;
    __half2 xv0[H2];
    if constexpr (H2 == 2) {
      const uv2 r0 = *reinterpret_cast<const uv2*>(x + o0);
      xv0[0] = u2h2(r0.x); xv0[1] = u2h2(r0.y);
    } else {
      xv0[0] = u2h2(*reinterpret_cast<const unsigned int*>(x + o0));
    }
    const __half2 a00 = u2h2(e0.y), a01 = u2h2(e0.z), a02 = u2h2(e0.w);
    #pragma unroll
    for (int j = 0; j < H2; j++) {
      __half2 m0 = __hadd2(xv0[j], bbh[j]);
      m0 = __hfma2(a02, w2h[j], m0);
      m0 = __hfma2(a01, w1h[j], m0);
      m0 = __hfma2(a00, w0h[j], m0);
      acc[j] = __hadd2(acc[j], hmax2(m0, zero2));
    }
  }

  const unsigned on = ((unsigned)n << SH) + fo;
  if constexpr (H2 == 2) {
    const uv2 rs = *reinterpret_cast<const uv2*>(x + on);
    const float2 s0 = __half22float2(u2h2(rs.x)), s1 = __half22float2(u2h2(rs.y));
    const float2 f0 = __half22float2(acc[0]), f1 = __half22float2(acc[1]);
    uv2 o;
    o.x = (unsigned)f2h(s0.x + f0.x) | ((unsigned)f2h(s0.y + f0.y) << 16);
    o.y = (unsigned)f2h(s1.x + f1.x) | ((unsigned)f2h(s1.y + f1.y) << 16);
    __builtin_nontemporal_store(o, reinterpret_cast<uv2*>(S + on));
  } else {
    const float2 s0 = __half22float2(u2h2(*reinterpret_cast<const unsigned int*>(x + on)));
    const float2 f0 = __half22float2(acc[0]);
    const unsigned o = (unsigned)f2h(s0.x + f0.x) | ((unsigned)f2h(s0.y + f0.y) << 16);
    __builtin_nontemporal_store(o, reinterpret_cast<unsigned int*>(S + on));
  }
}

// ---------------------------------------------------------------------------
// Fused dual GEMM (fp16): XB = leaky( BNleaky(A@W1) @ W2 )
// block = 128 rows x 256 cols, 8 waves (2x4). 3 barriers total.
// LDS 64KB union: phase1 lA[128][K1]; phase2 lY[128][256] (same buffer).
// B1/B2 fragments read directly from L2 (weights 128KB, L2-resident).
// ---------------------------------------------------------------------------
template<int K1>
__global__ __launch_bounds__(512) void gemm12(
    const unsigned short* __restrict__ A,
    const unsigned short* __restrict__ B1t, const float* __restrict__ b1,
    const float* __restrict__ gamma, const float* __restrict__ beta,
    const float* __restrict__ mu, const float* __restrict__ var,
    const unsigned short* __restrict__ B2t, const float* __restrict__ b2,
    unsigned short* __restrict__ XB)
{
  __shared__ __align__(16) unsigned short smem[128 * 256];  // 64 KB
  unsigned short* lA = smem;   // [128][K1], row stride K1*2 B (phase 1)
  unsigned short* lY = smem;   // [128][256], row stride 512 B (phase 2)

  const int t = threadIdx.x;
  const int lane = t & 63, wid = t >> 6;         // 8 waves
  const int wrow = wid >> 2, wcol = wid & 3;     // 2 x 4
  const int l15 = lane & 15, hi = lane >> 4;
  const int n0 = blockIdx.x * 128;

  // ---- stage full A tile [128][K1] (linear LDS dest, pre-swizzled source) ----
  constexpr int SPR = K1 / 8;        // 16B slots per row (16 or 32)
  constexpr int NCH = 128 * K1 * 2 / 1024;  // 1KB chunks (32 or 64)
  constexpr int CPW = NCH / 8;       // chunks per wave
  #pragma unroll
  for (int c = 0; c < CPW; c++) {
    const int ch = wid * CPW + c;
    const int row = ch * (512 / K1) + lane / SPR;
    const int slot = lane % SPR;
    const int scol = (slot ^ (row & 7)) * 8;
    const int gr = min(n0 + row, Nn - 1);
    gload_lds16(A + (size_t)gr * K1 + scol, (char*)lA + ch * 1024);
  }
  __syncthreads();

  // ---- phase 1: acc = A @ W1 (A from LDS, B1 from L2), no barriers ----
  f32x4 acc[4][4] = {};
  #pragma unroll
  for (int ks = 0; ks < K1 / 32; ks++) {
    short8 av[4], bv[4];
    #pragma unroll
    for (int rf = 0; rf < 4; rf++) {
      const int ar = wrow * 64 + rf * 16 + l15;
      av[rf] = *reinterpret_cast<const short8*>(
          (const char*)lA + ar * (K1 * 2) + (((ks * 4 + hi) ^ (ar & 7)) << 4));
    }
    #pragma unroll
    for (int cf = 0; cf < 4; cf++) {
      const int c = wcol * 64 + cf * 16 + l15;
      bv[cf] = *reinterpret_cast<const short8*>(B1t + (size_t)c * K1 + ks * 32 + hi * 8);
    }
    #pragma unroll
    for (int rf = 0; rf < 4; rf++)
      #pragma unroll
      for (int cf = 0; cf < 4; cf++)
        acc[rf][cf] = __builtin_amdgcn_mfma_f32_16x16x32_f16(av[rf], bv[cf], acc[rf][cf], 0, 0, 0);
  }
  __syncthreads();  // all lA reads done -> safe to overwrite with lY

  // ---- epilogue 1: BN + leaky -> lY (swizzled) ----
  #pragma unroll
  for (int cf = 0; cf < 4; cf++) {
    const int c = wcol * 64 + cf * 16 + l15;
    const float bs = b1[c];
    const float gm = gamma[c], bt2 = beta[c], mm = mu[c];
    const float iv = rsqrtf(var[c] + 1e-5f);
    const int slot0 = c >> 3;
    #pragma unroll
    for (int rf = 0; rf < 4; rf++)
      #pragma unroll
      for (int rg = 0; rg < 4; rg++) {
        const int row = wrow * 64 + rf * 16 + hi * 4 + rg;
        float v = acc[rf][cf][rg] + bs;
        v = gm * (v - mm) * iv + bt2;
        v = LRELU(v);
        *reinterpret_cast<unsigned short*>(
            (char*)lY + row * 512 + (((slot0 ^ (row & 7)) << 4)) + (c & 7) * 2) = f2h(v);
      }
  }
  __syncthreads();

  // ---- phase 2: acc = Y @ W2 (Y from LDS, B2 from L2), no barriers ----
  #pragma unroll
  for (int rf = 0; rf < 4; rf++)
    #pragma unroll
    for (int cf = 0; cf < 4; cf++) acc[rf][cf] = (f32x4){0.f, 0.f, 0.f, 0.f};
  #pragma unroll
  for (int ks = 0; ks < 8; ks++) {
    short8 av[4], bv[4];
    #pragma unroll
    for (int rf = 0; rf < 4; rf++) {
      const int ar = wrow * 64 + rf * 16 + l15;
      av[rf] = *reinterpret_cast<const short8*>(
          (const char*)lY + ar * 512 + (((ks * 4 + hi) ^ (ar & 7)) << 4));
    }
    #pragma unroll
    for (int cf = 0; cf < 4; cf++) {
      const int c = wcol * 64 + cf * 16 + l15;
      bv[cf] = *reinterpret_cast<const short8*>(B2t + (size_t)c * 256 + ks * 32 + hi * 8);
    }
    #pragma unroll
    for (int rf = 0; rf < 4; rf++)
      #pragma unroll
      for (int cf = 0; cf < 4; cf++)
        acc[rf][cf] = __builtin_amdgcn_mfma_f32_16x16x32_f16(av[rf], bv[cf], acc[rf][cf], 0, 0, 0);
  }

  // ---- epilogue 2: bias + leaky -> XB ----
  #pragma unroll
  for (int cf = 0; cf < 4; cf++) {
    const int col = wcol * 64 + cf * 16 + l15;
    const float bs = b2[col];
    #pragma unroll
    for (int rf = 0; rf < 4; rf++)
      #pragma unroll
      for (int rg = 0; rg < 4; rg++) {
        const int row = n0 + wrow * 64 + rf * 16 + hi * 4 + rg;
        if (row >= Nn) continue;
        const float v = LRELU(acc[rf][cf][rg] + bs);
        XB[(size_t)row * 256 + col] = f2h(v);
      }
  }
}

// ---------------------------------------------------------------------------
// Pool: segment_sum (sorted batch) of fp16 features into pooled[G,768] fp32
// ---------------------------------------------------------------------------
__global__ __launch_bounds__(256) void pool_kernel(
    const unsigned short* __restrict__ xl, const int* __restrict__ batch,
    float* __restrict__ pooled, int layer)
{
  constexpr int NPB = 16;
  const int n0 = blockIdx.x * NPB;
  const int c  = threadIdx.x;
  if (n0 >= Nn) return;
  float acc = 0.f;
  int curb = batch[n0];
  for (int i = 0; i < NPB; i++) {
    const int n = n0 + i;
    if (n >= Nn) break;
    const int b = batch[n];
    if (b != curb) {
      atomicAdd(pooled + (size_t)curb * 768 + layer * 256 + c, acc);
      acc = 0.f;
      curb = b;
    }
    acc += h2f(xl[(size_t)n * 256 + c]);
  }
  atomicAdd(pooled + (size_t)curb * 768 + layer * 256 + c, acc);
}

// ---------------------------------------------------------------------------
// Fused MFMA head (BF16): 4 blocks x 32 graphs, all 4 layers
// ---------------------------------------------------------------------------
__global__ __launch_bounds__(256) void head_fused(
    const unsigned short* __restrict__ P,
    const unsigned short* __restrict__ B1t,
    const unsigned short* __restrict__ B2t,
    const unsigned short* __restrict__ B3t,
    const unsigned short* __restrict__ B4t,
    const float* __restrict__ b1, const float* __restrict__ b2,
    const float* __restrict__ b3, const float* __restrict__ b4,
    float* __restrict__ out)
{
  __shared__ __align__(16) unsigned short act[32 * 256];
  const int t = threadIdx.x, lane = t & 63, wid = t >> 6;
  const int l15 = lane & 15, hi = lane >> 4;
  const int r0 = blockIdx.x * 32;

  f32x4 acc[2][4];

  #pragma unroll
  for (int rf = 0; rf < 2; rf++)
    #pragma unroll
    for (int cf = 0; cf < 4; cf++) acc[rf][cf] = (f32x4){0.f, 0.f, 0.f, 0.f};
  #pragma unroll 2
  for (int ks = 0; ks < 24; ks++) {
    short8 bv[4], av[2];
    #pragma unroll
    for (int cf = 0; cf < 4; cf++) {
      const int c = wid * 64 + cf * 16 + l15;
      bv[cf] = *reinterpret_cast<const short8*>(B1t + (size_t)c * 768 + ks * 32 + hi * 8);
    }
    #pragma unroll
    for (int rf = 0; rf < 2; rf++)
      av[rf] = *reinterpret_cast<const short8*>(
          P + (size_t)(r0 + rf * 16 + l15) * 768 + ks * 32 + hi * 8);
    #pragma unroll
    for (int rf = 0; rf < 2; rf++)
      #pragma unroll
      for (int cf = 0; cf < 4; cf++)
        acc[rf][cf] = __builtin_amdgcn_mfma_f32_16x16x32_bf16(av[rf], bv[cf], acc[rf][cf], 0, 0, 0);
  }
  #pragma unroll
  for (int cf = 0; cf < 4; cf++) {
    const int c = wid * 64 + cf * 16 + l15;
    const float bs = (c < 200) ? b1[c] : 0.f;
    const int slot0 = c >> 3;
    #pragma unroll
    for (int rf = 0; rf < 2; rf++)
      #pragma unroll
      for (int rg = 0; rg < 4; rg++) {
        const int row = rf * 16 + hi * 4 + rg;
        const float v = DLRELU(acc[rf][cf][rg] + bs);
        act[row * 256 + ((slot0 ^ (row & 7)) << 3) + (c & 7)] = f2bf(v);
      }
  }
  __syncthreads();

  #pragma unroll
  for (int L = 0; L < 2; L++) {
    const unsigned short* B = (L == 0) ? B2t : B3t;
    const float* bias = (L == 0) ? b2 : b3;
    #pragma unroll
    for (int rf = 0; rf < 2; rf++)
      #pragma unroll
      for (int cf = 0; cf < 4; cf++) acc[rf][cf] = (f32x4){0.f, 0.f, 0.f, 0.f};
    #pragma unroll
    for (int ks = 0; ks < 8; ks++) {
      short8 bv[4], av[2];
      #pragma unroll
      for (int cf = 0; cf < 4; cf++) {
        const int c = wid * 64 + cf * 16 + l15;
        bv[cf] = *reinterpret_cast<const short8*>(B + (size_t)c * 256 + ks * 32 + hi * 8);
      }
      #pragma unroll
      for (int rf = 0; rf < 2; rf++) {
        const int row = rf * 16 + l15;
        const int slot = ks * 4 + hi;
        av[rf] = *reinterpret_cast<const short8*>(
            act + row * 256 + ((slot ^ (row & 7)) << 3));
      }
      #pragma unroll
      for (int rf = 0; rf < 2; rf++)
        #pragma unroll
        for (int cf = 0; cf < 4; cf++)
          acc[rf][cf] = __builtin_amdgcn_mfma_f32_16x16x32_bf16(av[rf], bv[cf], acc[rf][cf], 0, 0, 0);
    }
    __syncthreads();
    #pragma unroll
    for (int cf = 0; cf < 4; cf++) {
      const int c = wid * 64 + cf * 16 + l15;
      const float bs = (c < 200) ? bias[c] : 0.f;
      const int slot0 = c >> 3;
      #pragma unroll
      for (int rf = 0; rf < 2; rf++)
        #pragma unroll
        for (int rg = 0; rg < 4; rg++) {
          const int row = rf * 16 + hi * 4 + rg;
          const float v = DLRELU(acc[rf][cf][rg] + bs);
          act[row * 256 + ((slot0 ^ (row & 7)) << 3) + (c & 7)] = f2bf(v);
        }
    }
    __syncthreads();
  }

  if (wid == 0) {
    f32x4 a4[2] = {};
    #pragma unroll
    for (int ks = 0; ks < 8; ks++) {
      short8 av[2];
      const short8 bv = *reinterpret_cast<const short8*>(
          B4t + (size_t)l15 * 256 + ks * 32 + hi * 8);
      #pragma unroll
      for (int rf = 0; rf < 2; rf++) {
        const int row = rf * 16 + l15;
        const int slot = ks * 4 + hi;
        av[rf] = *reinterpret_cast<const short8*>(
            act + row * 256 + ((slot ^ (row & 7)) << 3));
      }
      #pragma unroll
      for (int rf = 0; rf < 2; rf++)
        a4[rf] = __builtin_amdgcn_mfma_f32_16x16x32_bf16(av[rf], bv, a4[rf], 0, 0, 0);
    }
    if (l15 < Oo) {
      const float bs = b4[l15];
      #pragma unroll
      for (int rf = 0; rf < 2; rf++)
        #pragma unroll
        for (int rg = 0; rg < 4; rg++) {
          const int row = r0 + rf * 16 + hi * 4 + rg;
          out[(size_t)row * Oo + l15] = a4[rf][rg] + bs;
        }
    }
  }
}

// ---------------------------------------------------------------------------
extern "C" void kernel_launch(void* const* d_in, const int* in_sizes, int n_in,
                              void* d_out, int out_size, void* d_ws, size_t ws_size,
                              hipStream_t stream)
{
  const float* x     = (const float*)d_in[0];
  const int*   ei    = (const int*)d_in[1];
  const float* ea    = (const float*)d_in[2];
  const int*   batch = (const int*)d_in[3];
  const int* src = ei;
  const int* dst = ei + Ee;

  const float *We[3], *be_[3], *W1[3], *b1[3], *g_[3], *bt_[3], *mu_[3], *var_[3], *W2[3], *b2[3];
  for (int l = 0; l < 3; l++) {
    const int base = 4 + l * 10;
    We[l]  = (const float*)d_in[base + 0];
    be_[l] = (const float*)d_in[base + 1];
    W1[l]  = (const float*)d_in[base + 2];
    b1[l]  = (const float*)d_in[base + 3];
    g_[l]  = (const float*)d_in[base + 4];
    bt_[l] = (const float*)d_in[base + 5];
    mu_[l] = (const float*)d_in[base + 6];
    var_[l]= (const float*)d_in[base + 7];
    W2[l]  = (const float*)d_in[base + 8];
    b2[l]  = (const float*)d_in[base + 9];
  }
  const float *Wm[4], *bm[4];
  for (int i = 0; i < 4; i++) {
    Wm[i] = (const float*)d_in[34 + 2 * i];
    bm[i] = (const float*)d_in[35 + 2 * i];
  }

  // ---- workspace layout ----
  int* deg     = (int*)d_ws;                        // Nn
  int* cursor  = deg + Nn;                          // Nn
  int* row_ptr = cursor + Nn;                       // Nn+4
  int* bsum    = row_ptr + Nn + 4;                  // 64
  int* boff    = bsum + 64;                         // 64
  uv4* edges   = (uv4*)(boff + 64);                 // 16B aligned
  unsigned short* x0h  = (unsigned short*)(edges + Ee);  // Nn*128
  unsigned short* Wt11 = x0h + (size_t)Nn * 128;    // 256x128
  unsigned short* Wt12 = Wt11 + 32768;              // 256x256 each
  unsigned short* Wt21 = Wt12 + 65536;
  unsigned short* Wt22 = Wt21 + 65536;
  unsigned short* Wt31 = Wt22 + 65536;
  unsigned short* Wt32 = Wt31 + 65536;
  unsigned short* HW1t = Wt32 + 65536;              // 256x768 (bf16)
  unsigned short* HW2t = HW1t + 256 * 768;          // 256x256
  unsigned short* HW3t = HW2t + 65536;
  unsigned short* HW4t = HW3t + 65536;
  unsigned short* S    = HW4t + 65536;              // Nn*256
  unsigned short* XB0  = S  + (size_t)Nn * Hh;      // Nn*256
  unsigned short* XB1  = XB0 + (size_t)Nn * Hh;     // Nn*256
  unsigned short* Pbf  = XB1 + (size_t)Nn * Hh;     // Gg*768 (bf16)
  float* pooled = (float*)(Pbf + (size_t)Gg * 768); // Gg*768
  float* outf  = (float*)d_out;

  const int  gemmGrid = (Nn + 127) / 128;
  const int  poolGrid = (Nn + 15) / 16;
  const int  aggGrid  = (Nn + 3) / 4;
  const int  eGrid    = (Ee + 255) / 256;
  const int  sGrid    = (Nn + 1023) / 1024;

  hipMemsetAsync(deg, 0, Nn * sizeof(int), stream);
  hipMemsetAsync(pooled, 0, (size_t)Gg * 768 * sizeof(float), stream);

  // CSR build (once)
  hist_kernel<<<eGrid, 256, 0, stream>>>(dst, deg);
  scan1_kernel<<<sGrid, 1024, 0, stream>>>(deg, bsum);
  scan2_kernel<<<1, 64, 0, stream>>>(bsum, boff, row_ptr, sGrid);
  scan3_kernel<<<sGrid, 1024, 0, stream>>>(deg, boff, row_ptr, cursor);
  fill_kernel<<<eGrid, 256, 0, stream>>>(src, dst, ea, cursor, edges);

  // converts: x -> fp16, all 10 weight transposes in one launch
  f2h_kernel<<<(Nn * 128 / 4 + 255) / 256, 256, 0, stream>>>(x, x0h, Nn * 128 / 4);
  {
    WtJobs J;
    const float* s[10] = {W1[0], W2[0], W1[1], W2[1], W1[2], W2[2], Wm[0], Wm[1], Wm[2], Wm[3]};
    unsigned short* d[10] = {Wt11, Wt12, Wt21, Wt22, Wt31, Wt32, HW1t, HW2t, HW3t, HW4t};
    const int Ks[10]   = {128, 256, 256, 256, 256, 256, 768, 200, 200, 200};
    const int Ms[10]   = {256, 256, 256, 256, 256, 256, 200, 200, 200, 10};
    const int Kp[10]   = {128, 256, 256, 256, 256, 256, 768, 256, 256, 256};
    const int bf[10]   = {0, 0, 0, 0, 0, 0, 1, 1, 1, 1};
    int blk = 0;
    for (int q = 0; q < 10; q++) {
      J.src[q] = s[q]; J.dst[q] = d[q];
      J.K[q] = Ks[q]; J.M[q] = Ms[q]; J.Kpad[q] = Kp[q]; J.isbf[q] = bf[q];
      J.blk0[q] = blk;
      blk += (256 * Kp[q] + 255) / 256;
    }
    J.blk0[10] = blk;
    wtall_kernel<<<blk, 256, 0, stream>>>(J);
  }

  // ---- layer 1 (din = 128) ----
  agg_gather<128><<<aggGrid, 256, 0, stream>>>(x0h, edges, We[0], be_[0], row_ptr, S);
  gemm12<128><<<gemmGrid, 512, 0, stream>>>(
      S, Wt11, b1[0], g_[0], bt_[0], mu_[0], var_[0], Wt12, b2[0], XB0);
  pool_kernel<<<poolGrid, 256, 0, stream>>>(XB0, batch, pooled, 0);

  // ---- layer 2 (din = 256) ----
  agg_gather<256><<<aggGrid, 256, 0, stream>>>(XB0, edges, We[1], be_[1], row_ptr, S);
  gemm12<256><<<gemmGrid, 512, 0, stream>>>(
      S, Wt21, b1[1], g_[1], bt_[1], mu_[1], var_[1], Wt22, b2[1], XB1);
  pool_kernel<<<poolGrid, 256, 0, stream>>>(XB1, batch, pooled, 1);

  // ---- layer 3 (din = 256) ----
  agg_gather<256><<<aggGrid, 256, 0, stream>>>(XB1, edges, We[2], be_[2], row_ptr, S);
  gemm12<256><<<gemmGrid, 512, 0, stream>>>(
      S, Wt31, b1[2], g_[2], bt_[2], mu_[2], var_[2], Wt32, b2[2], XB0);
  pool_kernel<<<poolGrid, 256, 0, stream>>>(XB0, batch, pooled, 2);

  // ---- fused MFMA head (bf16) ----
  f2bf_kernel<<<(Gg * 768 / 4 + 255) / 256, 256, 0, stream>>>(pooled, Pbf, Gg * 768 / 4);
  head_fused<<<4, 256, 0, stream>>>(Pbf, HW1t, HW2t, HW3t, HW4t,
                                    bm[0], bm[1], bm[2], bm[3], outf);
}

// Round 15
// 552.690 us; speedup vs baseline: 1.3703x; 1.0552x over previous
//
#include <hip/hip_runtime.h>
#include <hip/hip_fp16.h>

#define LRELU(v) ((v) >= 0.f ? (v) : 0.2f * (v))
#define DLRELU(v) ((v) >= 0.f ? (v) : 0.04f * (v))

constexpr int Nn = 50000;
constexpr int Ee = 800000;
constexpr int Hh = 256;
constexpr int Gg = 128;
constexpr int Oo = 10;

typedef __attribute__((ext_vector_type(8))) short short8;
typedef __attribute__((ext_vector_type(4))) float f32x4;
typedef __attribute__((ext_vector_type(4))) unsigned int uv4;
typedef __attribute__((ext_vector_type(2))) unsigned int uv2;
typedef __attribute__((ext_vector_type(4))) unsigned short us4;

__device__ inline unsigned short f2h(float f) {
  __half h = __float2half_rn(f);
  return *reinterpret_cast<unsigned short*>(&h);
}
__device__ inline float h2f(unsigned short u) {
  __half h = *reinterpret_cast<__half*>(&u);
  return __half2float(h);
}
__device__ inline __half2 u2h2(unsigned int u) {
  return *reinterpret_cast<__half2*>(&u);
}
__device__ inline unsigned int h22u(__half2 h) {
  return *reinterpret_cast<unsigned int*>(&h);
}
__device__ inline __half2 hmax2(__half2 a, __half2 b) {
  __half2 r;
  asm volatile("v_pk_max_f16 %0, %1, %2" : "=v"(r) : "v"(a), "v"(b));
  return r;
}
__device__ inline unsigned short f2bf(float f) {
  union { float f; unsigned int i; } v; v.f = f;
  unsigned int i = v.i;
  return (unsigned short)((i + 0x7FFFu + ((i >> 16) & 1u)) >> 16);
}

typedef __attribute__((address_space(1))) const unsigned int gu32;
typedef __attribute__((address_space(3))) unsigned int lu32;
__device__ inline void gload_lds16(const void* g, void* l) {
  __builtin_amdgcn_global_load_lds((gu32*)g, (lu32*)l, 16, 0, 0);
}

// ---------------------------------------------------------------------------
// CSR build
// ---------------------------------------------------------------------------
__global__ __launch_bounds__(256) void hist_kernel(
    const int* __restrict__ dst, int* __restrict__ deg)
{
  const int e = blockIdx.x * 256 + threadIdx.x;
  if (e < Ee) atomicAdd(&deg[dst[e]], 1);
}

__global__ __launch_bounds__(1024) void scan1_kernel(
    const int* __restrict__ deg, int* __restrict__ bsum)
{
  const int i = blockIdx.x * 1024 + threadIdx.x;
  int v = (i < Nn) ? deg[i] : 0;
  #pragma unroll
  for (int o = 32; o; o >>= 1) v += __shfl_xor(v, o, 64);
  __shared__ int ws[16];
  const int wid = threadIdx.x >> 6, lane = threadIdx.x & 63;
  if (lane == 0) ws[wid] = v;
  __syncthreads();
  if (threadIdx.x == 0) {
    int s = 0;
    #pragma unroll
    for (int k = 0; k < 16; k++) s += ws[k];
    bsum[blockIdx.x] = s;
  }
}

__global__ __launch_bounds__(64) void scan2_kernel(
    const int* __restrict__ bsum, int* __restrict__ boff, int* __restrict__ row_ptr, int nb)
{
  if (threadIdx.x == 0) {
    int s = 0;
    for (int b = 0; b < nb; b++) { boff[b] = s; s += bsum[b]; }
    row_ptr[Nn] = s;
  }
}

__global__ __launch_bounds__(1024) void scan3_kernel(
    const int* __restrict__ deg, const int* __restrict__ boff,
    int* __restrict__ row_ptr, int* __restrict__ cursor)
{
  const int i = blockIdx.x * 1024 + threadIdx.x;
  const int wid = threadIdx.x >> 6, lane = threadIdx.x & 63;
  const int v = (i < Nn) ? deg[i] : 0;
  int inc = v;
  #pragma unroll
  for (int o = 1; o < 64; o <<= 1) {
    const int u = __shfl_up(inc, o, 64);
    if (lane >= o) inc += u;
  }
  __shared__ int ws[16];
  if (lane == 63) ws[wid] = inc;
  __syncthreads();
  if (wid == 0 && lane < 16) {
    int s = ws[lane];
    #pragma unroll
    for (int o = 1; o < 16; o <<= 1) {
      const int u = __shfl_up(s, o, 64);
      if (lane >= o) s += u;
    }
    ws[lane] = s;
  }
  __syncthreads();
  const int woff = (wid == 0) ? 0 : ws[wid - 1];
  const int excl = boff[blockIdx.x] + woff + inc - v;
  if (i < Nn) { row_ptr[i] = excl; cursor[i] = excl; }
}

// fill: packed 16B edge record {src, half2(a0,a0), half2(a1,a1), half2(a2,a2)}
__global__ __launch_bounds__(256) void fill_kernel(
    const int* __restrict__ src, const int* __restrict__ dst,
    const float* __restrict__ ea, int* __restrict__ cursor,
    uv4* __restrict__ edges)
{
  const int e = blockIdx.x * 256 + threadIdx.x;
  if (e >= Ee) return;
  const int pos = atomicAdd(&cursor[dst[e]], 1);
  uv4 r;
  r.x = (unsigned)src[e];
  r.y = h22u(__float2half2_rn(ea[3 * e + 0]));
  r.z = h22u(__float2half2_rn(ea[3 * e + 1]));
  r.w = h22u(__float2half2_rn(ea[3 * e + 2]));
  edges[pos] = r;
}

// ---------------------------------------------------------------------------
// Converters
// ---------------------------------------------------------------------------
__global__ __launch_bounds__(256) void f2h_kernel(
    const float* __restrict__ in, unsigned short* __restrict__ out, int n4)
{
  const int i = blockIdx.x * 256 + threadIdx.x;
  if (i >= n4) return;
  const float4 v = *reinterpret_cast<const float4*>(in + (size_t)i * 4);
  us4 o; o.x = f2h(v.x); o.y = f2h(v.y); o.z = f2h(v.z); o.w = f2h(v.w);
  *reinterpret_cast<us4*>(out + (size_t)i * 4) = o;
}

// Consolidated weight prep: 10 transpose jobs in one launch.
struct WtJobs {
  const float* src[10];
  unsigned short* dst[10];
  int K[10], M[10], Kpad[10], isbf[10], blk0[11];
};

__global__ __launch_bounds__(256) void wtall_kernel(WtJobs J)
{
  int j = 0;
  #pragma unroll
  for (int q = 1; q < 10; q++) if ((int)blockIdx.x >= J.blk0[q]) j = q;
  const int g = ((int)blockIdx.x - J.blk0[j]) * 256 + threadIdx.x;
  const int Kpad = J.Kpad[j];
  if (g >= 256 * Kpad) return;
  const int c = g / Kpad, k = g % Kpad;
  const int K = J.K[j], M = J.M[j];
  unsigned short o = 0;
  if (c < M && k < K) {
    const float w = J.src[j][(size_t)k * M + c];
    o = J.isbf[j] ? f2bf(w) : f2h(w);
  }
  J.dst[j][(size_t)c * Kpad + k] = o;
}

// ---------------------------------------------------------------------------
// Gather aggregation v5: fp16 packed math, 8 independent chains in flight
// ---------------------------------------------------------------------------
template<int DIN>
__global__ __launch_bounds__(256) void agg_gather(
    const unsigned short* __restrict__ x, const uv4* __restrict__ edges,
    const float* __restrict__ We, const float* __restrict__ be,
    const int* __restrict__ row_ptr, unsigned short* __restrict__ S)
{
  constexpr int FPL = DIN / 64;
  constexpr int H2  = FPL / 2;
  constexpr int SH  = (DIN == 256) ? 8 : 7;
  const int wv   = threadIdx.x >> 6;
  const int lane = threadIdx.x & 63;
  const int n = blockIdx.x * 4 + wv;
  if (n >= Nn) return;
  const int fo = lane * FPL;

  const __half2 zero2 = __float2half2_rn(0.f);
  __half2 w0h[H2], w1h[H2], w2h[H2], bbh[H2], acc[H2];
  #pragma unroll
  for (int j = 0; j < H2; j++) {
    w0h[j] = __halves2half2(__float2half_rn(We[0 * DIN + fo + 2 * j]),
                            __float2half_rn(We[0 * DIN + fo + 2 * j + 1]));
    w1h[j] = __halves2half2(__float2half_rn(We[1 * DIN + fo + 2 * j]),
                            __float2half_rn(We[1 * DIN + fo + 2 * j + 1]));
    w2h[j] = __halves2half2(__float2half_rn(We[2 * DIN + fo + 2 * j]),
                            __float2half_rn(We[2 * DIN + fo + 2 * j + 1]));
    bbh[j] = __halves2half2(__float2half_rn(be[fo + 2 * j]),
                            __float2half_rn(be[fo + 2 * j + 1]));
    acc[j] = zero2;
  }

  const int beg = row_ptr[n], end = row_ptr[n + 1];
  int i = beg;

  // 8 chains in flight
  for (; i + 8 <= end; i += 8) {
    uv4 e[8];
    #pragma unroll
    for (int q = 0; q < 8; q++) e[q] = __builtin_nontemporal_load(edges + i + q);
    __half2 xv[8][H2];
    #pragma unroll
    for (int q = 0; q < 8; q++) {
      const unsigned o = (e[q].x << SH) + fo;
      if constexpr (H2 == 2) {
        const uv2 r = *reinterpret_cast<const uv2*>(x + o);
        xv[q][0] = u2h2(r.x); xv[q][1] = u2h2(r.y);
      } else {
        xv[q][0] = u2h2(*reinterpret_cast<const unsigned int*>(x + o));
      }
    }
    #pragma unroll
    for (int q = 0; q < 8; q++) {
      const __half2 a0 = u2h2(e[q].y), a1 = u2h2(e[q].z), a2 = u2h2(e[q].w);
      #pragma unroll
      for (int j = 0; j < H2; j++) {
        __half2 m = __hadd2(xv[q][j], bbh[j]);
        m = __hfma2(a2, w2h[j], m);
        m = __hfma2(a1, w1h[j], m);
        m = __hfma2(a0, w0h[j], m);
        acc[j] = __hadd2(acc[j], hmax2(m, zero2));
      }
    }
  }
  for (; i < end; i++) {
    const uv4 e0 = __builtin_nontemporal_load(edges + i);
    const unsigned o0 = (e0.x << SH) + fo;
    __half2 xv0[H2];
    if constexpr (H2 == 2) {
      const uv2 r0 = *reinterpret_cast<const uv2*>(x + o0);
      xv0[0] = u2h2(r0.x); xv0[1] = u2h2(r0.y);
    } else {
      xv0[0] = u2h2(*reinterpret_cast<const unsigned int*>(x + o0));
    }
    const __half2 a00 = u2h2(e0.y), a01 = u2h2(e0.z), a02 = u2h2(e0.w);
    #pragma unroll
    for (int j = 0; j < H2; j++) {
      __half2 m0 = __hadd2(xv0[j], bbh[j]);
      m0 = __hfma2(a02, w2h[j], m0);
      m0 = __hfma2(a01, w1h[j], m0);
      m0 = __hfma2(a00, w0h[j], m0);
      acc[j] = __hadd2(acc[j], hmax2(m0, zero2));
    }
  }

  const unsigned on = ((unsigned)n << SH) + fo;
  if constexpr (H2 == 2) {
    const uv2 rs = *reinterpret_cast<const uv2*>(x + on);
    const float2 s0 = __half22float2(u2h2(rs.x)), s1 = __half22float2(u2h2(rs.y));
    const float2 f0 = __half22float2(acc[0]), f1 = __half22float2(acc[1]);
    uv2 o;
    o.x = (unsigned)f2h(s0.x + f0.x) | ((unsigned)f2h(s0.y + f0.y) << 16);
    o.y = (unsigned)f2h(s1.x + f1.x) | ((unsigned)f2h(s1.y + f1.y) << 16);
    __builtin_nontemporal_store(o, reinterpret_cast<uv2*>(S + on));
  } else {
    const float2 s0 = __half22float2(u2h2(*reinterpret_cast<const unsigned int*>(x + on)));
    const float2 f0 = __half22float2(acc[0]);
    const unsigned o = (unsigned)f2h(s0.x + f0.x) | ((unsigned)f2h(s0.y + f0.y) << 16);
    __builtin_nontemporal_store(o, reinterpret_cast<unsigned int*>(S + on));
  }
}

// ---------------------------------------------------------------------------
// Fused dual GEMM + pooling (fp16): XB = leaky( BNleaky(A@W1) @ W2 ); pooled += seg_sum
// block = 128 rows x 256 cols, 8 waves (2x4). LDS 64KB union (lA / lY / pool partial).
// Sorted batch, min graph ~330 >> 128 rows => block spans <= 2 graphs; 4 slots safe.
// ---------------------------------------------------------------------------
template<int K1, bool WRITE_XB>
__global__ __launch_bounds__(512) void gemm12(
    const unsigned short* __restrict__ A,
    const unsigned short* __restrict__ B1t, const float* __restrict__ b1,
    const float* __restrict__ gamma, const float* __restrict__ beta,
    const float* __restrict__ mu, const float* __restrict__ var,
    const unsigned short* __restrict__ B2t, const float* __restrict__ b2,
    unsigned short* __restrict__ XB,
    const int* __restrict__ batch, float* __restrict__ pooled, int layer)
{
  __shared__ __align__(16) unsigned short smem[128 * 256];  // 64 KB
  unsigned short* lA = smem;
  unsigned short* lY = smem;
  float* part = (float*)smem;   // [4][256] fp32 partial pool (16 KB region reuse)

  const int t = threadIdx.x;
  const int lane = t & 63, wid = t >> 6;
  const int wrow = wid >> 2, wcol = wid & 3;
  const int l15 = lane & 15, hi = lane >> 4;
  const int n0 = blockIdx.x * 128;

  // ---- stage full A tile [128][K1] ----
  constexpr int SPR = K1 / 8;
  constexpr int NCH = 128 * K1 * 2 / 1024;
  constexpr int CPW = NCH / 8;
  #pragma unroll
  for (int c = 0; c < CPW; c++) {
    const int ch = wid * CPW + c;
    const int row = ch * (512 / K1) + lane / SPR;
    const int slot = lane % SPR;
    const int scol = (slot ^ (row & 7)) * 8;
    const int gr = min(n0 + row, Nn - 1);
    gload_lds16(A + (size_t)gr * K1 + scol, (char*)lA + ch * 1024);
  }
  __syncthreads();

  // ---- phase 1: acc = A @ W1 ----
  f32x4 acc[4][4] = {};
  #pragma unroll
  for (int ks = 0; ks < K1 / 32; ks++) {
    short8 av[4], bv[4];
    #pragma unroll
    for (int rf = 0; rf < 4; rf++) {
      const int ar = wrow * 64 + rf * 16 + l15;
      av[rf] = *reinterpret_cast<const short8*>(
          (const char*)lA + ar * (K1 * 2) + (((ks * 4 + hi) ^ (ar & 7)) << 4));
    }
    #pragma unroll
    for (int cf = 0; cf < 4; cf++) {
      const int c = wcol * 64 + cf * 16 + l15;
      bv[cf] = *reinterpret_cast<const short8*>(B1t + (size_t)c * K1 + ks * 32 + hi * 8);
    }
    #pragma unroll
    for (int rf = 0; rf < 4; rf++)
      #pragma unroll
      for (int cf = 0; cf < 4; cf++)
        acc[rf][cf] = __builtin_amdgcn_mfma_f32_16x16x32_f16(av[rf], bv[cf], acc[rf][cf], 0, 0, 0);
  }
  __syncthreads();

  // ---- epilogue 1: BN + leaky -> lY ----
  #pragma unroll
  for (int cf = 0; cf < 4; cf++) {
    const int c = wcol * 64 + cf * 16 + l15;
    const float bs = b1[c];
    const float gm = gamma[c], bt2 = beta[c], mm = mu[c];
    const float iv = rsqrtf(var[c] + 1e-5f);
    const int slot0 = c >> 3;
    #pragma unroll
    for (int rf = 0; rf < 4; rf++)
      #pragma unroll
      for (int rg = 0; rg < 4; rg++) {
        const int row = wrow * 64 + rf * 16 + hi * 4 + rg;
        float v = acc[rf][cf][rg] + bs;
        v = gm * (v - mm) * iv + bt2;
        v = LRELU(v);
        *reinterpret_cast<unsigned short*>(
            (char*)lY + row * 512 + (((slot0 ^ (row & 7)) << 4)) + (c & 7) * 2) = f2h(v);
      }
  }
  __syncthreads();

  // ---- phase 2: acc = Y @ W2 ----
  #pragma unroll
  for (int rf = 0; rf < 4; rf++)
    #pragma unroll
    for (int cf = 0; cf < 4; cf++) acc[rf][cf] = (f32x4){0.f, 0.f, 0.f, 0.f};
  #pragma unroll
  for (int ks = 0; ks < 8; ks++) {
    short8 av[4], bv[4];
    #pragma unroll
    for (int rf = 0; rf < 4; rf++) {
      const int ar = wrow * 64 + rf * 16 + l15;
      av[rf] = *reinterpret_cast<const short8*>(
          (const char*)lY + ar * 512 + (((ks * 4 + hi) ^ (ar & 7)) << 4));
    }
    #pragma unroll
    for (int cf = 0; cf < 4; cf++) {
      const int c = wcol * 64 + cf * 16 + l15;
      bv[cf] = *reinterpret_cast<const short8*>(B2t + (size_t)c * 256 + ks * 32 + hi * 8);
    }
    #pragma unroll
    for (int rf = 0; rf < 4; rf++)
      #pragma unroll
      for (int cf = 0; cf < 4; cf++)
        acc[rf][cf] = __builtin_amdgcn_mfma_f32_16x16x32_f16(av[rf], bv[cf], acc[rf][cf], 0, 0, 0);
  }
  __syncthreads();  // all lY reads done -> reuse smem as pool partial

  // zero pool partial [4][256]
  for (int z = t; z < 1024; z += 512) part[z] = 0.f;
  __syncthreads();

  const int base = batch[min(n0, Nn - 1)];
  // graph slot per owned row (same 16 rows for all cf)
  int slotArr[4][4];
  #pragma unroll
  for (int rf = 0; rf < 4; rf++)
    #pragma unroll
    for (int rg = 0; rg < 4; rg++) {
      const int row = n0 + wrow * 64 + rf * 16 + hi * 4 + rg;
      slotArr[rf][rg] = (row < Nn) ? (batch[row] - base) : -1;
    }

  // ---- epilogue 2: bias + leaky -> XB (optional) + LDS pool partial ----
  #pragma unroll
  for (int cf = 0; cf < 4; cf++) {
    const int col = wcol * 64 + cf * 16 + l15;
    const float bs = b2[col];
    float psum[4] = {0.f, 0.f, 0.f, 0.f};
    #pragma unroll
    for (int rf = 0; rf < 4; rf++)
      #pragma unroll
      for (int rg = 0; rg < 4; rg++) {
        const int sl = slotArr[rf][rg];
        if (sl < 0) continue;
        const float v = LRELU(acc[rf][cf][rg] + bs);
        if (WRITE_XB) {
          const int row = n0 + wrow * 64 + rf * 16 + hi * 4 + rg;
          XB[(size_t)row * 256 + col] = f2h(v);
        }
        psum[sl] += v;
      }
    #pragma unroll
    for (int k = 0; k < 4; k++)
      if (psum[k] != 0.f) atomicAdd(&part[k * 256 + col], psum[k]);
  }
  __syncthreads();

  // flush partial -> global pooled
  for (int z = t; z < 1024; z += 512) {
    const float v = part[z];
    if (v != 0.f) {
      const int g = base + (z >> 8);
      if (g < Gg)
        atomicAdd(&pooled[(size_t)g * 768 + layer * 256 + (z & 255)], v);
    }
  }
}

// ---------------------------------------------------------------------------
// Fused MFMA head (BF16, reads fp32 pooled directly): 4 blocks x 32 graphs
// ---------------------------------------------------------------------------
__global__ __launch_bounds__(256) void head_fused(
    const float* __restrict__ P,            // [128][768] fp32
    const unsigned short* __restrict__ B1t,
    const unsigned short* __restrict__ B2t,
    const unsigned short* __restrict__ B3t,
    const unsigned short* __restrict__ B4t,
    const float* __restrict__ b1, const float* __restrict__ b2,
    const float* __restrict__ b3, const float* __restrict__ b4,
    float* __restrict__ out)
{
  __shared__ __align__(16) unsigned short act[32 * 256];
  const int t = threadIdx.x, lane = t & 63, wid = t >> 6;
  const int l15 = lane & 15, hi = lane >> 4;
  const int r0 = blockIdx.x * 32;

  f32x4 acc[2][4];

  #pragma unroll
  for (int rf = 0; rf < 2; rf++)
    #pragma unroll
    for (int cf = 0; cf < 4; cf++) acc[rf][cf] = (f32x4){0.f, 0.f, 0.f, 0.f};
  for (int ks = 0; ks < 24; ks++) {
    short8 bv[4], av[2];
    #pragma unroll
    for (int cf = 0; cf < 4; cf++) {
      const int c = wid * 64 + cf * 16 + l15;
      bv[cf] = *reinterpret_cast<const short8*>(B1t + (size_t)c * 768 + ks * 32 + hi * 8);
    }
    #pragma unroll
    for (int rf = 0; rf < 2; rf++) {
      const float* p = P + (size_t)(r0 + rf * 16 + l15) * 768 + ks * 32 + hi * 8;
      const float4 p0 = *reinterpret_cast<const float4*>(p);
      const float4 p1 = *reinterpret_cast<const float4*>(p + 4);
      short8 a;
      a[0] = (short)f2bf(p0.x); a[1] = (short)f2bf(p0.y);
      a[2] = (short)f2bf(p0.z); a[3] = (short)f2bf(p0.w);
      a[4] = (short)f2bf(p1.x); a[5] = (short)f2bf(p1.y);
      a[6] = (short)f2bf(p1.z); a[7] = (short)f2bf(p1.w);
      av[rf] = a;
    }
    #pragma unroll
    for (int rf = 0; rf < 2; rf++)
      #pragma unroll
      for (int cf = 0; cf < 4; cf++)
        acc[rf][cf] = __builtin_amdgcn_mfma_f32_16x16x32_bf16(av[rf], bv[cf], acc[rf][cf], 0, 0, 0);
  }
  #pragma unroll
  for (int cf = 0; cf < 4; cf++) {
    const int c = wid * 64 + cf * 16 + l15;
    const float bs = (c < 200) ? b1[c] : 0.f;
    const int slot0 = c >> 3;
    #pragma unroll
    for (int rf = 0; rf < 2; rf++)
      #pragma unroll
      for (int rg = 0; rg < 4; rg++) {
        const int row = rf * 16 + hi * 4 + rg;
        const float v = DLRELU(acc[rf][cf][rg] + bs);
        act[row * 256 + ((slot0 ^ (row & 7)) << 3) + (c & 7)] = f2bf(v);
      }
  }
  __syncthreads();

  #pragma unroll
  for (int L = 0; L < 2; L++) {
    const unsigned short* B = (L == 0) ? B2t : B3t;
    const float* bias = (L == 0) ? b2 : b3;
    #pragma unroll
    for (int rf = 0; rf < 2; rf++)
      #pragma unroll
      for (int cf = 0; cf < 4; cf++) acc[rf][cf] = (f32x4){0.f, 0.f, 0.f, 0.f};
    #pragma unroll
    for (int ks = 0; ks < 8; ks++) {
      short8 bv[4], av[2];
      #pragma unroll
      for (int cf = 0; cf < 4; cf++) {
        const int c = wid * 64 + cf * 16 + l15;
        bv[cf] = *reinterpret_cast<const short8*>(B + (size_t)c * 256 + ks * 32 + hi * 8);
      }
      #pragma unroll
      for (int rf = 0; rf < 2; rf++) {
        const int row = rf * 16 + l15;
        const int slot = ks * 4 + hi;
        av[rf] = *reinterpret_cast<const short8*>(
            act + row * 256 + ((slot ^ (row & 7)) << 3));
      }
      #pragma unroll
      for (int rf = 0; rf < 2; rf++)
        #pragma unroll
        for (int cf = 0; cf < 4; cf++)
          acc[rf][cf] = __builtin_amdgcn_mfma_f32_16x16x32_bf16(av[rf], bv[cf], acc[rf][cf], 0, 0, 0);
    }
    __syncthreads();
    #pragma unroll
    for (int cf = 0; cf < 4; cf++) {
      const int c = wid * 64 + cf * 16 + l15;
      const float bs = (c < 200) ? bias[c] : 0.f;
      const int slot0 = c >> 3;
      #pragma unroll
      for (int rf = 0; rf < 2; rf++)
        #pragma unroll
        for (int rg = 0; rg < 4; rg++) {
          const int row = rf * 16 + hi * 4 + rg;
          const float v = DLRELU(acc[rf][cf][rg] + bs);
          act[row * 256 + ((slot0 ^ (row & 7)) << 3) + (c & 7)] = f2bf(v);
        }
    }
    __syncthreads();
  }

  if (wid == 0) {
    f32x4 a4[2] = {};
    #pragma unroll
    for (int ks = 0; ks < 8; ks++) {
      short8 av[2];
      const short8 bv = *reinterpret_cast<const short8*>(
          B4t + (size_t)l15 * 256 + ks * 32 + hi * 8);
      #pragma unroll
      for (int rf = 0; rf < 2; rf++) {
        const int row = rf * 16 + l15;
        const int slot = ks * 4 + hi;
        av[rf] = *reinterpret_cast<const short8*>(
            act + row * 256 + ((slot ^ (row & 7)) << 3));
      }
      #pragma unroll
      for (int rf = 0; rf < 2; rf++)
        a4[rf] = __builtin_amdgcn_mfma_f32_16x16x32_bf16(av[rf], bv, a4[rf], 0, 0, 0);
    }
    if (l15 < Oo) {
      const float bs = b4[l15];
      #pragma unroll
      for (int rf = 0; rf < 2; rf++)
        #pragma unroll
        for (int rg = 0; rg < 4; rg++) {
          const int row = r0 + rf * 16 + hi * 4 + rg;
          out[(size_t)row * Oo + l15] = a4[rf][rg] + bs;
        }
    }
  }
}

// ---------------------------------------------------------------------------
extern "C" void kernel_launch(void* const* d_in, const int* in_sizes, int n_in,
                              void* d_out, int out_size, void* d_ws, size_t ws_size,
                              hipStream_t stream)
{
  const float* x     = (const float*)d_in[0];
  const int*   ei    = (const int*)d_in[1];
  const float* ea    = (const float*)d_in[2];
  const int*   batch = (const int*)d_in[3];
  const int* src = ei;
  const int* dst = ei + Ee;

  const float *We[3], *be_[3], *W1[3], *b1[3], *g_[3], *bt_[3], *mu_[3], *var_[3], *W2[3], *b2[3];
  for (int l = 0; l < 3; l++) {
    const int base = 4 + l * 10;
    We[l]  = (const float*)d_in[base + 0];
    be_[l] = (const float*)d_in[base + 1];
    W1[l]  = (const float*)d_in[base + 2];
    b1[l]  = (const float*)d_in[base + 3];
    g_[l]  = (const float*)d_in[base + 4];
    bt_[l] = (const float*)d_in[base + 5];
    mu_[l] = (const float*)d_in[base + 6];
    var_[l]= (const float*)d_in[base + 7];
    W2[l]  = (const float*)d_in[base + 8];
    b2[l]  = (const float*)d_in[base + 9];
  }
  const float *Wm[4], *bm[4];
  for (int i = 0; i < 4; i++) {
    Wm[i] = (const float*)d_in[34 + 2 * i];
    bm[i] = (const float*)d_in[35 + 2 * i];
  }

  // ---- workspace layout ----
  int* deg     = (int*)d_ws;                        // Nn
  int* cursor  = deg + Nn;                          // Nn
  int* row_ptr = cursor + Nn;                       // Nn+4
  int* bsum    = row_ptr + Nn + 4;                  // 64
  int* boff    = bsum + 64;                         // 64
  uv4* edges   = (uv4*)(boff + 64);                 // 16B aligned
  unsigned short* x0h  = (unsigned short*)(edges + Ee);  // Nn*128
  unsigned short* Wt11 = x0h + (size_t)Nn * 128;    // 256x128
  unsigned short* Wt12 = Wt11 + 32768;              // 256x256 each
  unsigned short* Wt21 = Wt12 + 65536;
  unsigned short* Wt22 = Wt21 + 65536;
  unsigned short* Wt31 = Wt22 + 65536;
  unsigned short* Wt32 = Wt31 + 65536;
  unsigned short* HW1t = Wt32 + 65536;              // 256x768 (bf16)
  unsigned short* HW2t = HW1t + 256 * 768;          // 256x256
  unsigned short* HW3t = HW2t + 65536;
  unsigned short* HW4t = HW3t + 65536;
  unsigned short* S    = HW4t + 65536;              // Nn*256
  unsigned short* XB0  = S  + (size_t)Nn * Hh;      // Nn*256
  unsigned short* XB1  = XB0 + (size_t)Nn * Hh;     // Nn*256
  float* pooled = (float*)(XB1 + (size_t)Nn * Hh);  // Gg*768
  float* outf  = (float*)d_out;

  const int  gemmGrid = (Nn + 127) / 128;
  const int  aggGrid  = (Nn + 3) / 4;
  const int  eGrid    = (Ee + 255) / 256;
  const int  sGrid    = (Nn + 1023) / 1024;

  hipMemsetAsync(deg, 0, Nn * sizeof(int), stream);
  hipMemsetAsync(pooled, 0, (size_t)Gg * 768 * sizeof(float), stream);

  // CSR build (once)
  hist_kernel<<<eGrid, 256, 0, stream>>>(dst, deg);
  scan1_kernel<<<sGrid, 1024, 0, stream>>>(deg, bsum);
  scan2_kernel<<<1, 64, 0, stream>>>(bsum, boff, row_ptr, sGrid);
  scan3_kernel<<<sGrid, 1024, 0, stream>>>(deg, boff, row_ptr, cursor);
  fill_kernel<<<eGrid, 256, 0, stream>>>(src, dst, ea, cursor, edges);

  // converts
  f2h_kernel<<<(Nn * 128 / 4 + 255) / 256, 256, 0, stream>>>(x, x0h, Nn * 128 / 4);
  {
    WtJobs J;
    const float* s[10] = {W1[0], W2[0], W1[1], W2[1], W1[2], W2[2], Wm[0], Wm[1], Wm[2], Wm[3]};
    unsigned short* d[10] = {Wt11, Wt12, Wt21, Wt22, Wt31, Wt32, HW1t, HW2t, HW3t, HW4t};
    const int Ks[10]   = {128, 256, 256, 256, 256, 256, 768, 200, 200, 200};
    const int Ms[10]   = {256, 256, 256, 256, 256, 256, 200, 200, 200, 10};
    const int Kp[10]   = {128, 256, 256, 256, 256, 256, 768, 256, 256, 256};
    const int bf[10]   = {0, 0, 0, 0, 0, 0, 1, 1, 1, 1};
    int blk = 0;
    for (int q = 0; q < 10; q++) {
      J.src[q] = s[q]; J.dst[q] = d[q];
      J.K[q] = Ks[q]; J.M[q] = Ms[q]; J.Kpad[q] = Kp[q]; J.isbf[q] = bf[q];
      J.blk0[q] = blk;
      blk += (256 * Kp[q] + 255) / 256;
    }
    J.blk0[10] = blk;
    wtall_kernel<<<blk, 256, 0, stream>>>(J);
  }

  // ---- layer 1 (din = 128) ----
  agg_gather<128><<<aggGrid, 256, 0, stream>>>(x0h, edges, We[0], be_[0], row_ptr, S);
  gemm12<128, true><<<gemmGrid, 512, 0, stream>>>(
      S, Wt11, b1[0], g_[0], bt_[0], mu_[0], var_[0], Wt12, b2[0], XB0,
      batch, pooled, 0);

  // ---- layer 2 (din = 256) ----
  agg_gather<256><<<aggGrid, 256, 0, stream>>>(XB0, edges, We[1], be_[1], row_ptr, S);
  gemm12<256, true><<<gemmGrid, 512, 0, stream>>>(
      S, Wt21, b1[1], g_[1], bt_[1], mu_[1], var_[1], Wt22, b2[1], XB1,
      batch, pooled, 1);

  // ---- layer 3 (din = 256) ----
  agg_gather<256><<<aggGrid, 256, 0, stream>>>(XB1, edges, We[2], be_[2], row_ptr, S);
  gemm12<256, false><<<gemmGrid, 512, 0, stream>>>(
      S, Wt31, b1[2], g_[2], bt_[2], mu_[2], var_[2], Wt32, b2[2], nullptr,
      batch, pooled, 2);

  // ---- fused MFMA head (reads fp32 pooled) ----
  head_fused<<<4, 256, 0, stream>>>(pooled, HW1t, HW2t, HW3t, HW4t,
                                    bm[0], bm[1], bm[2], bm[3], outf);
}

// Round 16
// 537.153 us; speedup vs baseline: 1.4100x; 1.0289x over previous
//
#include <hip/hip_runtime.h>
#include <hip/hip_fp16.h>

#define LRELU(v) ((v) >= 0.f ? (v) : 0.2f * (v))
#define DLRELU(v) ((v) >= 0.f ? (v) : 0.04f * (v))

constexpr int Nn = 50000;
constexpr int Ee = 800000;
constexpr int Hh = 256;
constexpr int Gg = 128;
constexpr int Oo = 10;

typedef __attribute__((ext_vector_type(8))) short short8;
typedef __attribute__((ext_vector_type(4))) float f32x4;
typedef __attribute__((ext_vector_type(4))) unsigned int uv4;
typedef __attribute__((ext_vector_type(2))) unsigned int uv2;
typedef __attribute__((ext_vector_type(4))) unsigned short us4;

__device__ inline unsigned short f2h(float f) {
  __half h = __float2half_rn(f);
  return *reinterpret_cast<unsigned short*>(&h);
}
__device__ inline float h2f(unsigned short u) {
  __half h = *reinterpret_cast<__half*>(&u);
  return __half2float(h);
}
__device__ inline __half2 u2h2(unsigned int u) {
  return *reinterpret_cast<__half2*>(&u);
}
__device__ inline unsigned int h22u(__half2 h) {
  return *reinterpret_cast<unsigned int*>(&h);
}
__device__ inline __half2 hmax2(__half2 a, __half2 b) {
  __half2 r;
  asm volatile("v_pk_max_f16 %0, %1, %2" : "=v"(r) : "v"(a), "v"(b));
  return r;
}
__device__ inline unsigned short f2bf(float f) {
  union { float f; unsigned int i; } v; v.f = f;
  unsigned int i = v.i;
  return (unsigned short)((i + 0x7FFFu + ((i >> 16) & 1u)) >> 16);
}

typedef __attribute__((address_space(1))) const unsigned int gu32;
typedef __attribute__((address_space(3))) unsigned int lu32;
__device__ inline void gload_lds16(const void* g, void* l) {
  __builtin_amdgcn_global_load_lds((gu32*)g, (lu32*)l, 16, 0, 0);
}

// ---------------------------------------------------------------------------
// Consolidated prep: f2h(x) + hist + 10 weight transposes in ONE launch
// ---------------------------------------------------------------------------
struct PrepArgs {
  const float* x; unsigned short* x0h;            // job A: 6250 blocks
  const int* dst; int* deg;                        // job B: 3125 blocks
  const float* wsrc[10];
  unsigned short* wdst[10];
  int K[10], M[10], Kpad[10], isbf[10], blk0[11];  // job C ranges (abs block ids)
};
constexpr int PREP_A = (Nn * 128 / 4 + 255) / 256;   // 6250
constexpr int PREP_B = (Ee + 255) / 256;             // 3125

__global__ __launch_bounds__(256) void prep_kernel(PrepArgs P)
{
  const int bid = blockIdx.x;
  if (bid < PREP_A) {
    const int i = bid * 256 + threadIdx.x;
    if (i >= Nn * 128 / 4) return;
    const float4 v = *reinterpret_cast<const float4*>(P.x + (size_t)i * 4);
    us4 o; o.x = f2h(v.x); o.y = f2h(v.y); o.z = f2h(v.z); o.w = f2h(v.w);
    *reinterpret_cast<us4*>(P.x0h + (size_t)i * 4) = o;
    return;
  }
  if (bid < PREP_A + PREP_B) {
    const int e = (bid - PREP_A) * 256 + threadIdx.x;
    if (e < Ee) atomicAdd(&P.deg[P.dst[e]], 1);
    return;
  }
  int j = 0;
  #pragma unroll
  for (int q = 1; q < 10; q++) if (bid >= P.blk0[q]) j = q;
  const int g = (bid - P.blk0[j]) * 256 + threadIdx.x;
  const int Kpad = P.Kpad[j];
  if (g >= 256 * Kpad) return;
  const int c = g / Kpad, k = g % Kpad;
  unsigned short o = 0;
  if (c < P.M[j] && k < P.K[j]) {
    const float w = P.wsrc[j][(size_t)k * P.M[j] + c];
    o = P.isbf[j] ? f2bf(w) : f2h(w);
  }
  P.wdst[j][(size_t)c * Kpad + k] = o;
}

// ---------------------------------------------------------------------------
// CSR scan + fill
// ---------------------------------------------------------------------------
__global__ __launch_bounds__(1024) void scan1_kernel(
    const int* __restrict__ deg, int* __restrict__ bsum)
{
  const int i = blockIdx.x * 1024 + threadIdx.x;
  int v = (i < Nn) ? deg[i] : 0;
  #pragma unroll
  for (int o = 32; o; o >>= 1) v += __shfl_xor(v, o, 64);
  __shared__ int ws[16];
  const int wid = threadIdx.x >> 6, lane = threadIdx.x & 63;
  if (lane == 0) ws[wid] = v;
  __syncthreads();
  if (threadIdx.x == 0) {
    int s = 0;
    #pragma unroll
    for (int k = 0; k < 16; k++) s += ws[k];
    bsum[blockIdx.x] = s;
  }
}

__global__ __launch_bounds__(64) void scan2_kernel(
    const int* __restrict__ bsum, int* __restrict__ boff, int* __restrict__ row_ptr, int nb)
{
  if (threadIdx.x == 0) {
    int s = 0;
    for (int b = 0; b < nb; b++) { boff[b] = s; s += bsum[b]; }
    row_ptr[Nn] = s;
  }
}

__global__ __launch_bounds__(1024) void scan3_kernel(
    const int* __restrict__ deg, const int* __restrict__ boff,
    int* __restrict__ row_ptr, int* __restrict__ cursor)
{
  const int i = blockIdx.x * 1024 + threadIdx.x;
  const int wid = threadIdx.x >> 6, lane = threadIdx.x & 63;
  const int v = (i < Nn) ? deg[i] : 0;
  int inc = v;
  #pragma unroll
  for (int o = 1; o < 64; o <<= 1) {
    const int u = __shfl_up(inc, o, 64);
    if (lane >= o) inc += u;
  }
  __shared__ int ws[16];
  if (lane == 63) ws[wid] = inc;
  __syncthreads();
  if (wid == 0 && lane < 16) {
    int s = ws[lane];
    #pragma unroll
    for (int o = 1; o < 16; o <<= 1) {
      const int u = __shfl_up(s, o, 64);
      if (lane >= o) s += u;
    }
    ws[lane] = s;
  }
  __syncthreads();
  const int woff = (wid == 0) ? 0 : ws[wid - 1];
  const int excl = boff[blockIdx.x] + woff + inc - v;
  if (i < Nn) { row_ptr[i] = excl; cursor[i] = excl; }
}

__global__ __launch_bounds__(256) void fill_kernel(
    const int* __restrict__ src, const int* __restrict__ dst,
    const float* __restrict__ ea, int* __restrict__ cursor,
    uv4* __restrict__ edges)
{
  const int e = blockIdx.x * 256 + threadIdx.x;
  if (e >= Ee) return;
  const int pos = atomicAdd(&cursor[dst[e]], 1);
  uv4 r;
  r.x = (unsigned)src[e];
  r.y = h22u(__float2half2_rn(ea[3 * e + 0]));
  r.z = h22u(__float2half2_rn(ea[3 * e + 1]));
  r.w = h22u(__float2half2_rn(ea[3 * e + 2]));
  edges[pos] = r;
}

// ---------------------------------------------------------------------------
// Gather aggregation: fp16 packed math, 4 independent chains in flight
// ---------------------------------------------------------------------------
template<int DIN>
__global__ __launch_bounds__(256) void agg_gather(
    const unsigned short* __restrict__ x, const uv4* __restrict__ edges,
    const float* __restrict__ We, const float* __restrict__ be,
    const int* __restrict__ row_ptr, unsigned short* __restrict__ S)
{
  constexpr int FPL = DIN / 64;
  constexpr int H2  = FPL / 2;
  constexpr int SH  = (DIN == 256) ? 8 : 7;
  const int wv   = threadIdx.x >> 6;
  const int lane = threadIdx.x & 63;
  const int n = blockIdx.x * 4 + wv;
  if (n >= Nn) return;
  const int fo = lane * FPL;

  const __half2 zero2 = __float2half2_rn(0.f);
  __half2 w0h[H2], w1h[H2], w2h[H2], bbh[H2], acc[H2];
  #pragma unroll
  for (int j = 0; j < H2; j++) {
    w0h[j] = __halves2half2(__float2half_rn(We[0 * DIN + fo + 2 * j]),
                            __float2half_rn(We[0 * DIN + fo + 2 * j + 1]));
    w1h[j] = __halves2half2(__float2half_rn(We[1 * DIN + fo + 2 * j]),
                            __float2half_rn(We[1 * DIN + fo + 2 * j + 1]));
    w2h[j] = __halves2half2(__float2half_rn(We[2 * DIN + fo + 2 * j]),
                            __float2half_rn(We[2 * DIN + fo + 2 * j + 1]));
    bbh[j] = __halves2half2(__float2half_rn(be[fo + 2 * j]),
                            __float2half_rn(be[fo + 2 * j + 1]));
    acc[j] = zero2;
  }

  const int beg = row_ptr[n], end = row_ptr[n + 1];
  int i = beg;

  for (; i + 4 <= end; i += 4) {
    uv4 e[4];
    #pragma unroll
    for (int q = 0; q < 4; q++) e[q] = __builtin_nontemporal_load(edges + i + q);
    __half2 xv[4][H2];
    #pragma unroll
    for (int q = 0; q < 4; q++) {
      const unsigned o = (e[q].x << SH) + fo;
      if constexpr (H2 == 2) {
        const uv2 r = *reinterpret_cast<const uv2*>(x + o);
        xv[q][0] = u2h2(r.x); xv[q][1] = u2h2(r.y);
      } else {
        xv[q][0] = u2h2(*reinterpret_cast<const unsigned int*>(x + o));
      }
    }
    #pragma unroll
    for (int q = 0; q < 4; q++) {
      const __half2 a0 = u2h2(e[q].y), a1 = u2h2(e[q].z), a2 = u2h2(e[q].w);
      #pragma unroll
      for (int j = 0; j < H2; j++) {
        __half2 m = __hadd2(xv[q][j], bbh[j]);
        m = __hfma2(a2, w2h[j], m);
        m = __hfma2(a1, w1h[j], m);
        m = __hfma2(a0, w0h[j], m);
        acc[j] = __hadd2(acc[j], hmax2(m, zero2));
      }
    }
  }
  for (; i < end; i++) {
    const uv4 e0 = __builtin_nontemporal_load(edges + i);
    const unsigned o0 = (e0.x << SH) + fo;
    __half2 xv0[H2];
    if constexpr (H2 == 2) {
      const uv2 r0 = *reinterpret_cast<const uv2*>(x + o0);
      xv0[0] = u2h2(r0.x); xv0[1] = u2h2(r0.y);
    } else {
      xv0[0] = u2h2(*reinterpret_cast<const unsigned int*>(x + o0));
    }
    const __half2 a00 = u2h2(e0.y), a01 = u2h2(e0.z), a02 = u2h2(e0.w);
    #pragma unroll
    for (int j = 0; j < H2; j++) {
      __half2 m0 = __hadd2(xv0[j], bbh[j]);
      m0 = __hfma2(a02, w2h[j], m0);
      m0 = __hfma2(a01, w1h[j], m0);
      m0 = __hfma2(a00, w0h[j], m0);
      acc[j] = __hadd2(acc[j], hmax2(m0, zero2));
    }
  }

  const unsigned on = ((unsigned)n << SH) + fo;
  if constexpr (H2 == 2) {
    const uv2 rs = *reinterpret_cast<const uv2*>(x + on);
    const float2 s0 = __half22float2(u2h2(rs.x)), s1 = __half22float2(u2h2(rs.y));
    const float2 f0 = __half22float2(acc[0]), f1 = __half22float2(acc[1]);
    uv2 o;
    o.x = (unsigned)f2h(s0.x + f0.x) | ((unsigned)f2h(s0.y + f0.y) << 16);
    o.y = (unsigned)f2h(s1.x + f1.x) | ((unsigned)f2h(s1.y + f1.y) << 16);
    __builtin_nontemporal_store(o, reinterpret_cast<uv2*>(S + on));
  } else {
    const float2 s0 = __half22float2(u2h2(*reinterpret_cast<const unsigned int*>(x + on)));
    const float2 f0 = __half22float2(acc[0]);
    const unsigned o = (unsigned)f2h(s0.x + f0.x) | ((unsigned)f2h(s0.y + f0.y) << 16);
    __builtin_nontemporal_store(o, reinterpret_cast<unsigned int*>(S + on));
  }
}

// ---------------------------------------------------------------------------
// Fused dual GEMM + pooling (fp16)
// ---------------------------------------------------------------------------
template<int K1, bool WRITE_XB>
__global__ __launch_bounds__(512) void gemm12(
    const unsigned short* __restrict__ A,
    const unsigned short* __restrict__ B1t, const float* __restrict__ b1,
    const float* __restrict__ gamma, const float* __restrict__ beta,
    const float* __restrict__ mu, const float* __restrict__ var,
    const unsigned short* __restrict__ B2t, const float* __restrict__ b2,
    unsigned short* __restrict__ XB,
    const int* __restrict__ batch, float* __restrict__ pooled, int layer)
{
  __shared__ __align__(16) unsigned short smem[128 * 256];  // 64 KB
  unsigned short* lA = smem;
  unsigned short* lY = smem;
  float* part = (float*)smem;

  const int t = threadIdx.x;
  const int lane = t & 63, wid = t >> 6;
  const int wrow = wid >> 2, wcol = wid & 3;
  const int l15 = lane & 15, hi = lane >> 4;
  const int n0 = blockIdx.x * 128;

  // ---- stage full A tile [128][K1] ----
  constexpr int SPR = K1 / 8;
  constexpr int NCH = 128 * K1 * 2 / 1024;
  constexpr int CPW = NCH / 8;
  #pragma unroll
  for (int c = 0; c < CPW; c++) {
    const int ch = wid * CPW + c;
    const int row = ch * (512 / K1) + lane / SPR;
    const int slot = lane % SPR;
    const int scol = (slot ^ (row & 7)) * 8;
    const int gr = min(n0 + row, Nn - 1);
    gload_lds16(A + (size_t)gr * K1 + scol, (char*)lA + ch * 1024);
  }
  __syncthreads();

  // ---- phase 1: acc = A @ W1 ----
  f32x4 acc[4][4] = {};
  #pragma unroll
  for (int ks = 0; ks < K1 / 32; ks++) {
    short8 av[4], bv[4];
    #pragma unroll
    for (int rf = 0; rf < 4; rf++) {
      const int ar = wrow * 64 + rf * 16 + l15;
      av[rf] = *reinterpret_cast<const short8*>(
          (const char*)lA + ar * (K1 * 2) + (((ks * 4 + hi) ^ (ar & 7)) << 4));
    }
    #pragma unroll
    for (int cf = 0; cf < 4; cf++) {
      const int c = wcol * 64 + cf * 16 + l15;
      bv[cf] = *reinterpret_cast<const short8*>(B1t + (size_t)c * K1 + ks * 32 + hi * 8);
    }
    #pragma unroll
    for (int rf = 0; rf < 4; rf++)
      #pragma unroll
      for (int cf = 0; cf < 4; cf++)
        acc[rf][cf] = __builtin_amdgcn_mfma_f32_16x16x32_f16(av[rf], bv[cf], acc[rf][cf], 0, 0, 0);
  }
  __syncthreads();

  // ---- epilogue 1: BN + leaky -> lY ----
  #pragma unroll
  for (int cf = 0; cf < 4; cf++) {
    const int c = wcol * 64 + cf * 16 + l15;
    const float bs = b1[c];
    const float gm = gamma[c], bt2 = beta[c], mm = mu[c];
    const float iv = rsqrtf(var[c] + 1e-5f);
    const int slot0 = c >> 3;
    #pragma unroll
    for (int rf = 0; rf < 4; rf++)
      #pragma unroll
      for (int rg = 0; rg < 4; rg++) {
        const int row = wrow * 64 + rf * 16 + hi * 4 + rg;
        float v = acc[rf][cf][rg] + bs;
        v = gm * (v - mm) * iv + bt2;
        v = LRELU(v);
        *reinterpret_cast<unsigned short*>(
            (char*)lY + row * 512 + (((slot0 ^ (row & 7)) << 4)) + (c & 7) * 2) = f2h(v);
      }
  }
  __syncthreads();

  // prefetch pool slots early so the batch[] gathers hide under phase-2 MFMAs
  const int base = batch[min(n0, Nn - 1)];
  int slotArr[4][4];
  #pragma unroll
  for (int rf = 0; rf < 4; rf++)
    #pragma unroll
    for (int rg = 0; rg < 4; rg++) {
      const int row = n0 + wrow * 64 + rf * 16 + hi * 4 + rg;
      slotArr[rf][rg] = (row < Nn) ? (batch[row] - base) : -1;
    }

  // ---- phase 2: acc = Y @ W2 ----
  #pragma unroll
  for (int rf = 0; rf < 4; rf++)
    #pragma unroll
    for (int cf = 0; cf < 4; cf++) acc[rf][cf] = (f32x4){0.f, 0.f, 0.f, 0.f};
  #pragma unroll
  for (int ks = 0; ks < 8; ks++) {
    short8 av[4], bv[4];
    #pragma unroll
    for (int rf = 0; rf < 4; rf++) {
      const int ar = wrow * 64 + rf * 16 + l15;
      av[rf] = *reinterpret_cast<const short8*>(
          (const char*)lY + ar * 512 + (((ks * 4 + hi) ^ (ar & 7)) << 4));
    }
    #pragma unroll
    for (int cf = 0; cf < 4; cf++) {
      const int c = wcol * 64 + cf * 16 + l15;
      bv[cf] = *reinterpret_cast<const short8*>(B2t + (size_t)c * 256 + ks * 32 + hi * 8);
    }
    #pragma unroll
    for (int rf = 0; rf < 4; rf++)
      #pragma unroll
      for (int cf = 0; cf < 4; cf++)
        acc[rf][cf] = __builtin_amdgcn_mfma_f32_16x16x32_f16(av[rf], bv[cf], acc[rf][cf], 0, 0, 0);
  }
  __syncthreads();  // all lY reads done -> reuse smem as pool partial

  for (int z = t; z < 1024; z += 512) part[z] = 0.f;
  __syncthreads();

  // ---- epilogue 2: bias + leaky -> XB (optional) + LDS pool partial ----
  #pragma unroll
  for (int cf = 0; cf < 4; cf++) {
    const int col = wcol * 64 + cf * 16 + l15;
    const float bs = b2[col];
    float psum[4] = {0.f, 0.f, 0.f, 0.f};
    #pragma unroll
    for (int rf = 0; rf < 4; rf++)
      #pragma unroll
      for (int rg = 0; rg < 4; rg++) {
        const int sl = slotArr[rf][rg];
        if (sl < 0) continue;
        const float v = LRELU(acc[rf][cf][rg] + bs);
        if (WRITE_XB) {
          const int row = n0 + wrow * 64 + rf * 16 + hi * 4 + rg;
          XB[(size_t)row * 256 + col] = f2h(v);
        }
        psum[sl] += v;
      }
    #pragma unroll
    for (int k = 0; k < 4; k++)
      if (psum[k] != 0.f) atomicAdd(&part[k * 256 + col], psum[k]);
  }
  __syncthreads();

  for (int z = t; z < 1024; z += 512) {
    const float v = part[z];
    if (v != 0.f) {
      const int g = base + (z >> 8);
      if (g < Gg)
        atomicAdd(&pooled[(size_t)g * 768 + layer * 256 + (z & 255)], v);
    }
  }
}

// ---------------------------------------------------------------------------
// Fused MFMA head (BF16, reads fp32 pooled directly): 4 blocks x 32 graphs
// ---------------------------------------------------------------------------
__global__ __launch_bounds__(256) void head_fused(
    const float* __restrict__ P,
    const unsigned short* __restrict__ B1t,
    const unsigned short* __restrict__ B2t,
    const unsigned short* __restrict__ B3t,
    const unsigned short* __restrict__ B4t,
    const float* __restrict__ b1, const float* __restrict__ b2,
    const float* __restrict__ b3, const float* __restrict__ b4,
    float* __restrict__ out)
{
  __shared__ __align__(16) unsigned short act[32 * 256];
  const int t = threadIdx.x, lane = t & 63, wid = t >> 6;
  const int l15 = lane & 15, hi = lane >> 4;
  const int r0 = blockIdx.x * 32;

  f32x4 acc[2][4];

  #pragma unroll
  for (int rf = 0; rf < 2; rf++)
    #pragma unroll
    for (int cf = 0; cf < 4; cf++) acc[rf][cf] = (f32x4){0.f, 0.f, 0.f, 0.f};
  for (int ks = 0; ks < 24; ks++) {
    short8 bv[4], av[2];
    #pragma unroll
    for (int cf = 0; cf < 4; cf++) {
      const int c = wid * 64 + cf * 16 + l15;
      bv[cf] = *reinterpret_cast<const short8*>(B1t + (size_t)c * 768 + ks * 32 + hi * 8);
    }
    #pragma unroll
    for (int rf = 0; rf < 2; rf++) {
      const float* p = P + (size_t)(r0 + rf * 16 + l15) * 768 + ks * 32 + hi * 8;
      const float4 p0 = *reinterpret_cast<const float4*>(p);
      const float4 p1 = *reinterpret_cast<const float4*>(p + 4);
      short8 a;
      a[0] = (short)f2bf(p0.x); a[1] = (short)f2bf(p0.y);
      a[2] = (short)f2bf(p0.z); a[3] = (short)f2bf(p0.w);
      a[4] = (short)f2bf(p1.x); a[5] = (short)f2bf(p1.y);
      a[6] = (short)f2bf(p1.z); a[7] = (short)f2bf(p1.w);
      av[rf] = a;
    }
    #pragma unroll
    for (int rf = 0; rf < 2; rf++)
      #pragma unroll
      for (int cf = 0; cf < 4; cf++)
        acc[rf][cf] = __builtin_amdgcn_mfma_f32_16x16x32_bf16(av[rf], bv[cf], acc[rf][cf], 0, 0, 0);
  }
  #pragma unroll
  for (int cf = 0; cf < 4; cf++) {
    const int c = wid * 64 + cf * 16 + l15;
    const float bs = (c < 200) ? b1[c] : 0.f;
    const int slot0 = c >> 3;
    #pragma unroll
    for (int rf = 0; rf < 2; rf++)
      #pragma unroll
      for (int rg = 0; rg < 4; rg++) {
        const int row = rf * 16 + hi * 4 + rg;
        const float v = DLRELU(acc[rf][cf][rg] + bs);
        act[row * 256 + ((slot0 ^ (row & 7)) << 3) + (c & 7)] = f2bf(v);
      }
  }
  __syncthreads();

  #pragma unroll
  for (int L = 0; L < 2; L++) {
    const unsigned short* B = (L == 0) ? B2t : B3t;
    const float* bias = (L == 0) ? b2 : b3;
    #pragma unroll
    for (int rf = 0; rf < 2; rf++)
      #pragma unroll
      for (int cf = 0; cf < 4; cf++) acc[rf][cf] = (f32x4){0.f, 0.f, 0.f, 0.f};
    #pragma unroll
    for (int ks = 0; ks < 8; ks++) {
      short8 bv[4], av[2];
      #pragma unroll
      for (int cf = 0; cf < 4; cf++) {
        const int c = wid * 64 + cf * 16 + l15;
        bv[cf] = *reinterpret_cast<const short8*>(B + (size_t)c * 256 + ks * 32 + hi * 8);
      }
      #pragma unroll
      for (int rf = 0; rf < 2; rf++) {
        const int row = rf * 16 + l15;
        const int slot = ks * 4 + hi;
        av[rf] = *reinterpret_cast<const short8*>(
            act + row * 256 + ((slot ^ (row & 7)) << 3));
      }
      #pragma unroll
      for (int rf = 0; rf < 2; rf++)
        #pragma unroll
        for (int cf = 0; cf < 4; cf++)
          acc[rf][cf] = __builtin_amdgcn_mfma_f32_16x16x32_bf16(av[rf], bv[cf], acc[rf][cf], 0, 0, 0);
    }
    __syncthreads();
    #pragma unroll
    for (int cf = 0; cf < 4; cf++) {
      const int c = wid * 64 + cf * 16 + l15;
      const float bs = (c < 200) ? bias[c] : 0.f;
      const int slot0 = c >> 3;
      #pragma unroll
      for (int rf = 0; rf < 2; rf++)
        #pragma unroll
        for (int rg = 0; rg < 4; rg++) {
          const int row = rf * 16 + hi * 4 + rg;
          const float v = DLRELU(acc[rf][cf][rg] + bs);
          act[row * 256 + ((slot0 ^ (row & 7)) << 3) + (c & 7)] = f2bf(v);
        }
    }
    __syncthreads();
  }

  if (wid == 0) {
    f32x4 a4[2] = {};
    #pragma unroll
    for (int ks = 0; ks < 8; ks++) {
      short8 av[2];
      const short8 bv = *reinterpret_cast<const short8*>(
          B4t + (size_t)l15 * 256 + ks * 32 + hi * 8);
      #pragma unroll
      for (int rf = 0; rf < 2; rf++) {
        const int row = rf * 16 + l15;
        const int slot = ks * 4 + hi;
        av[rf] = *reinterpret_cast<const short8*>(
            act + row * 256 + ((slot ^ (row & 7)) << 3));
      }
      #pragma unroll
      for (int rf = 0; rf < 2; rf++)
        a4[rf] = __builtin_amdgcn_mfma_f32_16x16x32_bf16(av[rf], bv, a4[rf], 0, 0, 0);
    }
    if (l15 < Oo) {
      const float bs = b4[l15];
      #pragma unroll
      for (int rf = 0; rf < 2; rf++)
        #pragma unroll
        for (int rg = 0; rg < 4; rg++) {
          const int row = r0 + rf * 16 + hi * 4 + rg;
          out[(size_t)row * Oo + l15] = a4[rf][rg] + bs;
        }
    }
  }
}

// ---------------------------------------------------------------------------
extern "C" void kernel_launch(void* const* d_in, const int* in_sizes, int n_in,
                              void* d_out, int out_size, void* d_ws, size_t ws_size,
                              hipStream_t stream)
{
  const float* x     = (const float*)d_in[0];
  const int*   ei    = (const int*)d_in[1];
  const float* ea    = (const float*)d_in[2];
  const int*   batch = (const int*)d_in[3];
  const int* src = ei;
  const int* dst = ei + Ee;

  const float *We[3], *be_[3], *W1[3], *b1[3], *g_[3], *bt_[3], *mu_[3], *var_[3], *W2[3], *b2[3];
  for (int l = 0; l < 3; l++) {
    const int base = 4 + l * 10;
    We[l]  = (const float*)d_in[base + 0];
    be_[l] = (const float*)d_in[base + 1];
    W1[l]  = (const float*)d_in[base + 2];
    b1[l]  = (const float*)d_in[base + 3];
    g_[l]  = (const float*)d_in[base + 4];
    bt_[l] = (const float*)d_in[base + 5];
    mu_[l] = (const float*)d_in[base + 6];
    var_[l]= (const float*)d_in[base + 7];
    W2[l]  = (const float*)d_in[base + 8];
    b2[l]  = (const float*)d_in[base + 9];
  }
  const float *Wm[4], *bm[4];
  for (int i = 0; i < 4; i++) {
    Wm[i] = (const float*)d_in[34 + 2 * i];
    bm[i] = (const float*)d_in[35 + 2 * i];
  }

  // ---- workspace layout ----
  int* deg     = (int*)d_ws;                        // Nn
  int* cursor  = deg + Nn;                          // Nn
  int* row_ptr = cursor + Nn;                       // Nn+4
  int* bsum    = row_ptr + Nn + 4;                  // 64
  int* boff    = bsum + 64;                         // 64
  uv4* edges   = (uv4*)(boff + 64);                 // 16B aligned
  unsigned short* x0h  = (unsigned short*)(edges + Ee);  // Nn*128
  unsigned short* Wt11 = x0h + (size_t)Nn * 128;    // 256x128
  unsigned short* Wt12 = Wt11 + 32768;              // 256x256 each
  unsigned short* Wt21 = Wt12 + 65536;
  unsigned short* Wt22 = Wt21 + 65536;
  unsigned short* Wt31 = Wt22 + 65536;
  unsigned short* Wt32 = Wt31 + 65536;
  unsigned short* HW1t = Wt32 + 65536;              // 256x768 (bf16)
  unsigned short* HW2t = HW1t + 256 * 768;          // 256x256
  unsigned short* HW3t = HW2t + 65536;
  unsigned short* HW4t = HW3t + 65536;
  unsigned short* S    = HW4t + 65536;              // Nn*256
  unsigned short* XB0  = S  + (size_t)Nn * Hh;      // Nn*256
  unsigned short* XB1  = XB0 + (size_t)Nn * Hh;     // Nn*256
  float* pooled = (float*)(XB1 + (size_t)Nn * Hh);  // Gg*768
  float* outf  = (float*)d_out;

  const int  gemmGrid = (Nn + 127) / 128;
  const int  aggGrid  = (Nn + 3) / 4;
  const int  eGrid    = (Ee + 255) / 256;
  const int  sGrid    = (Nn + 1023) / 1024;

  hipMemsetAsync(deg, 0, Nn * sizeof(int), stream);
  hipMemsetAsync(pooled, 0, (size_t)Gg * 768 * sizeof(float), stream);

  // ---- consolidated prep: f2h + hist + weight transposes ----
  {
    PrepArgs P;
    P.x = x; P.x0h = x0h; P.dst = dst; P.deg = deg;
    const float* s[10] = {W1[0], W2[0], W1[1], W2[1], W1[2], W2[2], Wm[0], Wm[1], Wm[2], Wm[3]};
    unsigned short* d[10] = {Wt11, Wt12, Wt21, Wt22, Wt31, Wt32, HW1t, HW2t, HW3t, HW4t};
    const int Ks[10] = {128, 256, 256, 256, 256, 256, 768, 200, 200, 200};
    const int Ms[10] = {256, 256, 256, 256, 256, 256, 200, 200, 200, 10};
    const int Kp[10] = {128, 256, 256, 256, 256, 256, 768, 256, 256, 256};
    const int bf[10] = {0, 0, 0, 0, 0, 0, 1, 1, 1, 1};
    int blk = PREP_A + PREP_B;
    for (int q = 0; q < 10; q++) {
      P.wsrc[q] = s[q]; P.wdst[q] = d[q];
      P.K[q] = Ks[q]; P.M[q] = Ms[q]; P.Kpad[q] = Kp[q]; P.isbf[q] = bf[q];
      P.blk0[q] = blk;
      blk += Kp[q];
    }
    P.blk0[10] = blk;
    prep_kernel<<<blk, 256, 0, stream>>>(P);
  }

  // CSR scan + fill
  scan1_kernel<<<sGrid, 1024, 0, stream>>>(deg, bsum);
  scan2_kernel<<<1, 64, 0, stream>>>(bsum, boff, row_ptr, sGrid);
  scan3_kernel<<<sGrid, 1024, 0, stream>>>(deg, boff, row_ptr, cursor);
  fill_kernel<<<eGrid, 256, 0, stream>>>(src, dst, ea, cursor, edges);

  // ---- layer 1 (din = 128) ----
  agg_gather<128><<<aggGrid, 256, 0, stream>>>(x0h, edges, We[0], be_[0], row_ptr, S);
  gemm12<128, true><<<gemmGrid, 512, 0, stream>>>(
      S, Wt11, b1[0], g_[0], bt_[0], mu_[0], var_[0], Wt12, b2[0], XB0,
      batch, pooled, 0);

  // ---- layer 2 (din = 256) ----
  agg_gather<256><<<aggGrid, 256, 0, stream>>>(XB0, edges, We[1], be_[1], row_ptr, S);
  gemm12<256, true><<<gemmGrid, 512, 0, stream>>>(
      S, Wt21, b1[1], g_[1], bt_[1], mu_[1], var_[1], Wt22, b2[1], XB1,
      batch, pooled, 1);

  // ---- layer 3 (din = 256) ----
  agg_gather<256><<<aggGrid, 256, 0, stream>>>(XB1, edges, We[2], be_[2], row_ptr, S);
  gemm12<256, false><<<gemmGrid, 512, 0, stream>>>(
      S, Wt31, b1[2], g_[2], bt_[2], mu_[2], var_[2], Wt32, b2[2], nullptr,
      batch, pooled, 2);

  // ---- fused MFMA head ----
  head_fused<<<4, 256, 0, stream>>>(pooled, HW1t, HW2t, HW3t, HW4t,
                                    bm[0], bm[1], bm[2], bm[3], outf);
}